// Round 1
// baseline (18217.413 us; speedup 1.0000x reference)
//
#include <hip/hip_runtime.h>
#include <math.h>

#define NG 2048
#define NC 4096
#define EKNN 61440
#define EPPI 65536

static inline int cdiv(int a, int b) { return (a + b - 1) / b; }

// ---------------- GEMM: C[M,N] = A[M,K] @ B[K,N] (+C)(+bias)(act) ----------------
// ACT: 0=none, 1=leaky(0.01), 2=relu
template<int ACT, bool BIAS, bool ACCUM>
__global__ __launch_bounds__(256)
void gemm_f32(const float* __restrict__ A, const float* __restrict__ B,
              const float* __restrict__ bias, float* __restrict__ C,
              int M, int N, int K) {
    __shared__ float As[16][64];   // [k][m]
    __shared__ float Bs[16][64];   // [k][n]
    const int tid = threadIdx.x;
    const int tx = tid & 15, ty = tid >> 4;
    const int bm = blockIdx.y << 6, bn = blockIdx.x << 6;
    float acc[4][4] = {};
    const int ar = tid >> 2, ac = (tid & 3) << 2;      // A tile: 64 rows x 16 k
    const int brk = tid >> 4, bcn = (tid & 15) << 2;   // B tile: 16 k x 64 cols
    for (int k0 = 0; k0 < K; k0 += 16) {
        const float4 va = *(const float4*)(A + (size_t)(bm + ar) * K + k0 + ac);
        const float4 vb = *(const float4*)(B + (size_t)(k0 + brk) * N + bn + bcn);
        As[ac + 0][ar] = va.x;
        As[ac + 1][ar] = va.y;
        As[ac + 2][ar] = va.z;
        As[ac + 3][ar] = va.w;
        *(float4*)(&Bs[brk][bcn]) = vb;
        __syncthreads();
        #pragma unroll
        for (int k = 0; k < 16; ++k) {
            const float4 a = *(const float4*)(&As[k][ty << 2]);
            const float4 b = *(const float4*)(&Bs[k][tx << 2]);
            acc[0][0] += a.x * b.x; acc[0][1] += a.x * b.y; acc[0][2] += a.x * b.z; acc[0][3] += a.x * b.w;
            acc[1][0] += a.y * b.x; acc[1][1] += a.y * b.y; acc[1][2] += a.y * b.z; acc[1][3] += a.y * b.w;
            acc[2][0] += a.z * b.x; acc[2][1] += a.z * b.y; acc[2][2] += a.z * b.z; acc[2][3] += a.z * b.w;
            acc[3][0] += a.w * b.x; acc[3][1] += a.w * b.y; acc[3][2] += a.w * b.z; acc[3][3] += a.w * b.w;
        }
        __syncthreads();
    }
    float4 bb = make_float4(0.f, 0.f, 0.f, 0.f);
    if (BIAS) bb = *(const float4*)(bias + bn + (tx << 2));
    #pragma unroll
    for (int i = 0; i < 4; ++i) {
        const size_t off = (size_t)(bm + (ty << 2) + i) * N + bn + (tx << 2);
        float4 v = make_float4(acc[i][0], acc[i][1], acc[i][2], acc[i][3]);
        if (ACCUM) {
            const float4 c = *(const float4*)(C + off);
            v.x += c.x; v.y += c.y; v.z += c.z; v.w += c.w;
        }
        if (BIAS) { v.x += bb.x; v.y += bb.y; v.z += bb.z; v.w += bb.w; }
        if (ACT == 1) {
            v.x = v.x > 0.f ? v.x : 0.01f * v.x;
            v.y = v.y > 0.f ? v.y : 0.01f * v.y;
            v.z = v.z > 0.f ? v.z : 0.01f * v.z;
            v.w = v.w > 0.f ? v.w : 0.01f * v.w;
        } else if (ACT == 2) {
            v.x = fmaxf(v.x, 0.f); v.y = fmaxf(v.y, 0.f);
            v.z = fmaxf(v.z, 0.f); v.w = fmaxf(v.w, 0.f);
        }
        *(float4*)(C + off) = v;
    }
}

// ---------------- transpose: out[C,R] = in[R,C]^T ----------------
__global__ __launch_bounds__(256)
void transpose_k(const float* __restrict__ in, float* __restrict__ out, int R, int C) {
    __shared__ float tile[32][33];
    const int bx = blockIdx.x << 5;   // col base in `in`
    const int by = blockIdx.y << 5;   // row base in `in`
    const int tx = threadIdx.x & 31, tg = threadIdx.x >> 5;
    #pragma unroll
    for (int i = tg; i < 32; i += 8)
        tile[i][tx] = in[(size_t)(by + i) * C + bx + tx];
    __syncthreads();
    #pragma unroll
    for (int i = tg; i < 32; i += 8)
        out[(size_t)(bx + i) * R + by + tx] = tile[tx][i];
}

// ---------------- small elementwise / graph kernels ----------------
__global__ void fill_k(float* __restrict__ p, float v, int n) {
    int i = blockIdx.x * blockDim.x + threadIdx.x;
    if (i < n) p[i] = v;
}

__global__ void count_dst(const int* __restrict__ dst, float* __restrict__ cnt, int E) {
    int e = blockIdx.x * blockDim.x + threadIdx.x;
    if (e < E) atomicAdd(&cnt[dst[e]], 1.0f);
}

__global__ void make_dinv(const float* __restrict__ cnt, float* __restrict__ dinv, int n) {
    int i = blockIdx.x * blockDim.x + threadIdx.x;
    if (i < n) dinv[i] = rsqrtf(cnt[i] + 1.0f);   // + self loop; deg >= 1 always
}

// agg[dst] += x[src]  (float4 per thread)
__global__ void sage_agg(const int* __restrict__ src, const int* __restrict__ dst,
                         const float* __restrict__ x, float* __restrict__ agg,
                         int E, int F, int perShift) {
    int gid = blockIdx.x * blockDim.x + threadIdx.x;
    int e = gid >> perShift;
    if (e >= E) return;
    int q4 = (gid & ((1 << perShift) - 1)) << 2;
    const float4 v = *(const float4*)(x + (size_t)src[e] * F + q4);
    float* o = agg + (size_t)dst[e] * F + q4;
    atomicAdd(o + 0, v.x);
    atomicAdd(o + 1, v.y);
    atomicAdd(o + 2, v.z);
    atomicAdd(o + 3, v.w);
}

__global__ void sage_div(float* __restrict__ agg, const float* __restrict__ cnt,
                         int total, int fshift) {
    int i = blockIdx.x * blockDim.x + threadIdx.x;
    if (i >= total) return;
    float c = fmaxf(cnt[i >> fshift], 1.0f);
    agg[i] /= c;
}

__global__ void leaky_inplace(float* __restrict__ x, int n) {
    int i = blockIdx.x * blockDim.x + threadIdx.x;
    if (i >= n) return;
    float v = x[i];
    x[i] = v > 0.f ? v : 0.01f * v;
}

// out[i,f] = h[i,f]*dinv[i]^2 + b[f]   (self-loop term + bias)
__global__ void gcn_self_init(const float* __restrict__ h, const float* __restrict__ dinv,
                              const float* __restrict__ b, float* __restrict__ out,
                              int n, int F) {
    int gid = blockIdx.x * blockDim.x + threadIdx.x;
    if (gid >= n * F) return;
    int i = gid / F, f = gid - i * F;
    float d = dinv[i];
    out[gid] = h[gid] * d * d + b[f];
}

// out[dst,f] += h[src,f] * dinv[src] * dinv[dst]
__global__ void gcn_edge(const int* __restrict__ src, const int* __restrict__ dst,
                         const float* __restrict__ h, const float* __restrict__ dinv,
                         float* __restrict__ out, int E, int fshift) {
    int gid = blockIdx.x * blockDim.x + threadIdx.x;
    int e = gid >> fshift;
    if (e >= E) return;
    int f = gid & ((1 << fshift) - 1);
    int s = src[e], d = dst[e];
    int F = 1 << fshift;
    atomicAdd(&out[(size_t)d * F + f], h[(size_t)s * F + f] * dinv[s] * dinv[d]);
}

// alpha[e] = dot(q[dst[e]], k[src[e]]) / sqrt(128)   — one wave per edge
__global__ __launch_bounds__(256)
void edge_dot(const int* __restrict__ src, const int* __restrict__ dst,
              const float* __restrict__ q, const float* __restrict__ k,
              float* __restrict__ alpha, int E) {
    int wid = (blockIdx.x * blockDim.x + threadIdx.x) >> 6;
    int lane = threadIdx.x & 63;
    if (wid >= E) return;
    const int s = src[wid], d = dst[wid];
    float v = q[(size_t)d * 128 + lane] * k[(size_t)s * 128 + lane]
            + q[(size_t)d * 128 + 64 + lane] * k[(size_t)s * 128 + 64 + lane];
    #pragma unroll
    for (int off = 32; off; off >>= 1) v += __shfl_down(v, off);
    if (lane == 0) alpha[wid] = v * 0.08838834764831845f;  // 1/sqrt(128)
}

__device__ inline void atomicMaxF(float* addr, float v) {
    if (v >= 0.f) atomicMax((int*)addr, __float_as_int(v));
    else          atomicMin((unsigned int*)addr, __float_as_uint(v));
}

__global__ void seg_max(const int* __restrict__ dst, const float* __restrict__ alpha,
                        float* __restrict__ m, int E) {
    int e = blockIdx.x * blockDim.x + threadIdx.x;
    if (e < E) atomicMaxF(&m[dst[e]], alpha[e]);
}

__global__ void seg_expsum(const int* __restrict__ dst, float* __restrict__ alpha,
                           const float* __restrict__ m, float* __restrict__ z, int E) {
    int e = blockIdx.x * blockDim.x + threadIdx.x;
    if (e >= E) return;
    float ex = expf(alpha[e] - m[dst[e]]);
    alpha[e] = ex;
    atomicAdd(&z[dst[e]], ex);
}

__global__ void seg_norm(const int* __restrict__ dst, float* __restrict__ alpha,
                         const float* __restrict__ z, int E) {
    int e = blockIdx.x * blockDim.x + threadIdx.x;
    if (e >= E) return;
    float zz = z[dst[e]];
    alpha[e] /= (zz > 0.f ? zz : 1.f);
}

// out[dst] += a[e] * v[src]   (F=128)
__global__ void tconv_scatter(const int* __restrict__ src, const int* __restrict__ dst,
                              const float* __restrict__ a, const float* __restrict__ v,
                              float* __restrict__ out, int E) {
    int gid = blockIdx.x * blockDim.x + threadIdx.x;
    int e = gid >> 7;
    if (e >= E) return;
    int f = gid & 127;
    atomicAdd(&out[(size_t)dst[e] * 128 + f], a[e] * v[(size_t)src[e] * 128 + f]);
}

__global__ __launch_bounds__(256)
void reduce_stats(const float* __restrict__ a, int E, double* __restrict__ stats) {
    double s = 0.0, s2 = 0.0;
    for (int i = blockIdx.x * blockDim.x + threadIdx.x; i < E; i += gridDim.x * blockDim.x) {
        double x = a[i];
        s += x; s2 += x * x;
    }
    #pragma unroll
    for (int off = 32; off; off >>= 1) {
        s += __shfl_down(s, off);
        s2 += __shfl_down(s2, off);
    }
    __shared__ double sh[4][2];
    int w = threadIdx.x >> 6;
    if ((threadIdx.x & 63) == 0) { sh[w][0] = s; sh[w][1] = s2; }
    __syncthreads();
    if (threadIdx.x == 0) {
        double t = sh[0][0] + sh[1][0] + sh[2][0] + sh[3][0];
        double t2 = sh[0][1] + sh[1][1] + sh[2][1] + sh[3][1];
        atomicAdd(&stats[0], t);
        atomicAdd(&stats[1], t2);
    }
}

__global__ void sigmoid_alpha(float* __restrict__ alpha, int E,
                              const double* __restrict__ stats, float scale_param) {
    int i = blockIdx.x * blockDim.x + threadIdx.x;
    if (i >= E) return;
    double sum = stats[0], sumsq = stats[1];
    double mu = sum / (double)E;
    double var = (sumsq - sum * sum / (double)E) / (double)(E - 1);
    float sd = (float)sqrt(fmax(var, 0.0));
    float t = (alpha[i] - (float)mu) * (scale_param / sd);
    alpha[i] = 1.f / (1.f + expf(-t));
}

// ---------------- workspace layout (floats) ----------------
static constexpr size_t NBIG = (size_t)NG * NC;             // 8388608
static constexpr size_t OFF_P = 0;
static constexpr size_t OFF_Q = NBIG;
static constexpr size_t OFF_R = 2 * NBIG;
static constexpr size_t OFF_H1 = 3 * NBIG;                  // 4096*512
static constexpr size_t OFF_H2 = OFF_H1 + (size_t)4096 * 512;
static constexpr size_t OFF_H3 = OFF_H2 + (size_t)4096 * 512;
static constexpr size_t OFF_QB = OFF_H3 + (size_t)4096 * 512;
static constexpr size_t OFF_KB = OFF_QB + (size_t)4096 * 128;
static constexpr size_t OFF_VB = OFF_KB + (size_t)4096 * 128;
static constexpr size_t OFF_ALPHA = OFF_VB + (size_t)4096 * 128;
static constexpr size_t OFF_CNTK = OFF_ALPHA + 65536;
static constexpr size_t OFF_CNTP = OFF_CNTK + 4096;
static constexpr size_t OFF_DINVK = OFF_CNTP + 4096;
static constexpr size_t OFF_DINVP = OFF_DINVK + 4096;
static constexpr size_t OFF_M = OFF_DINVP + 4096;
static constexpr size_t OFF_Z = OFF_M + 4096;
static constexpr size_t OFF_STATS = OFF_Z + 4096;           // double[2]

extern "C" void kernel_launch(void* const* d_in, const int* in_sizes, int n_in,
                              void* d_out, int out_size, void* d_ws, size_t ws_size,
                              hipStream_t stream) {
    const float* x      = (const float*)d_in[0];
    const int*   knn    = (const int*)d_in[1];
    const int*   ppi    = (const int*)d_in[2];
    const float* c0_wl = (const float*)d_in[3],  *c0_wr = (const float*)d_in[4],  *c0_b = (const float*)d_in[5];
    const float* r0_wl = (const float*)d_in[6],  *r0_wr = (const float*)d_in[7],  *r0_b = (const float*)d_in[8];
    const float* c1_wl = (const float*)d_in[9],  *c1_wr = (const float*)d_in[10], *c1_b = (const float*)d_in[11];
    const float* r1_wl = (const float*)d_in[12], *r1_wr = (const float*)d_in[13], *r1_b = (const float*)d_in[14];
    const float* gr_w  = (const float*)d_in[15], *gr_b  = (const float*)d_in[16];
    const float* tr_wq = (const float*)d_in[17], *tr_bq = (const float*)d_in[18];
    const float* tr_wk = (const float*)d_in[19], *tr_bk = (const float*)d_in[20];
    const float* tr_wv = (const float*)d_in[21], *tr_bv = (const float*)d_in[22];
    const float* tr_ws = (const float*)d_in[23], *tr_bs = (const float*)d_in[24];
    const float* gc_w  = (const float*)d_in[25], *gc_b  = (const float*)d_in[26];
    const float* tc_wq = (const float*)d_in[27], *tc_bq = (const float*)d_in[28];
    const float* tc_wk = (const float*)d_in[29], *tc_bk = (const float*)d_in[30];
    const float* tc_wv = (const float*)d_in[31], *tc_bv = (const float*)d_in[32];
    const float* tc_ws = (const float*)d_in[33], *tc_bs = (const float*)d_in[34];
    const float* d1_w  = (const float*)d_in[35], *d1_b  = (const float*)d_in[36];
    const float* d2_w  = (const float*)d_in[37], *d2_b  = (const float*)d_in[38];
    const float* d3_w  = (const float*)d_in[39], *d3_b  = (const float*)d_in[40];

    const int* knn_src = knn,            *knn_dst = knn + EKNN;
    const int* ppi_src = ppi,            *ppi_dst = ppi + EPPI;

    float* ws = (float*)d_ws;
    float* P = ws + OFF_P;
    float* Q = ws + OFF_Q;
    float* R = ws + OFF_R;
    float* H1 = ws + OFF_H1;
    float* H2 = ws + OFF_H2;
    float* H3 = ws + OFF_H3;
    float* QB = ws + OFF_QB;
    float* KB = ws + OFF_KB;
    float* VB = ws + OFF_VB;
    float* ALPHA = ws + OFF_ALPHA;
    float* CNTK = ws + OFF_CNTK;
    float* CNTP = ws + OFF_CNTP;
    float* DINVK = ws + OFF_DINVK;
    float* DINVP = ws + OFF_DINVP;
    float* MBUF = ws + OFF_M;
    float* ZBUF = ws + OFF_Z;
    double* STATS = (double*)(ws + OFF_STATS);

    float* out_rows = (float*)d_out;                       // [2048,128]
    float* out_cols = out_rows + (size_t)NG * 128;         // [4096,128]
    float* out_feat = out_cols + (size_t)NC * 128;         // [4096,2048]

    auto gemm = [&](const float* A, const float* B, const float* bias, float* C,
                    int M, int N, int K, int act, bool accum) {
        dim3 g(N >> 6, M >> 6), blk(256);
        if (accum)         gemm_f32<1, true,  true ><<<g, blk, 0, stream>>>(A, B, bias, C, M, N, K);
        else if (act == 2) gemm_f32<2, true,  false><<<g, blk, 0, stream>>>(A, B, bias, C, M, N, K);
        else if (bias)     gemm_f32<0, true,  false><<<g, blk, 0, stream>>>(A, B, bias, C, M, N, K);
        else               gemm_f32<0, false, false><<<g, blk, 0, stream>>>(A, B, nullptr, C, M, N, K);
    };
    auto transpose = [&](const float* in, float* out, int Rr, int Cn) {
        transpose_k<<<dim3(Cn >> 5, Rr >> 5), 256, 0, stream>>>(in, out, Rr, Cn);
    };

    // ---- degrees (shared by both SAGE iterations and GCNs) ----
    hipMemsetAsync(CNTK, 0, NC * 4, stream);
    hipMemsetAsync(CNTP, 0, NG * 4, stream);
    count_dst<<<cdiv(EKNN, 256), 256, 0, stream>>>(knn_dst, CNTK, EKNN);
    count_dst<<<cdiv(EPPI, 256), 256, 0, stream>>>(ppi_dst, CNTP, EPPI);
    make_dinv<<<cdiv(NC, 256), 256, 0, stream>>>(CNTK, DINVK, NC);
    make_dinv<<<cdiv(NG, 256), 256, 0, stream>>>(CNTP, DINVP, NG);

    // ================= SAGE block 0 =================
    // cols (cells graph, n=4096, F=2048): xt in Q, agg in R, out in P
    transpose(x, Q, NG, NC);
    hipMemsetAsync(R, 0, NBIG * 4, stream);
    sage_agg<<<cdiv(EKNN * (NG / 4), 256), 256, 0, stream>>>(knn_src, knn_dst, Q, R, EKNN, NG, 9);
    sage_div<<<cdiv(NC * NG, 256), 256, 0, stream>>>(R, CNTK, NC * NG, 11);
    gemm(R, c0_wl, nullptr, P, NC, NG, NG, 0, false);
    gemm(Q, c0_wr, c0_b,    P, NC, NG, NG, 1, true);
    transpose(P, Q, NC, NG);           // emb1 [2048,4096] in Q
    // rows (genes graph, n=2048, F=4096)
    hipMemsetAsync(R, 0, NBIG * 4, stream);
    sage_agg<<<cdiv(EPPI * (NC / 4), 256), 256, 0, stream>>>(ppi_src, ppi_dst, Q, R, EPPI, NC, 10);
    sage_div<<<cdiv(NG * NC, 256), 256, 0, stream>>>(R, CNTP, NG * NC, 12);
    gemm(R, r0_wl, nullptr, P, NG, NC, NC, 0, false);
    gemm(Q, r0_wr, r0_b,    P, NG, NC, NC, 1, true);   // emb2 [2048,4096] in P

    // ================= SAGE block 1 =================
    transpose(P, Q, NG, NC);           // xt [4096,2048] in Q
    hipMemsetAsync(R, 0, NBIG * 4, stream);
    sage_agg<<<cdiv(EKNN * (NG / 4), 256), 256, 0, stream>>>(knn_src, knn_dst, Q, R, EKNN, NG, 9);
    sage_div<<<cdiv(NC * NG, 256), 256, 0, stream>>>(R, CNTK, NC * NG, 11);
    gemm(R, c1_wl, nullptr, P, NC, NG, NG, 0, false);
    gemm(Q, c1_wr, c1_b,    P, NC, NG, NG, 1, true);
    transpose(P, Q, NC, NG);           // emb3 [2048,4096] in Q
    hipMemsetAsync(R, 0, NBIG * 4, stream);
    sage_agg<<<cdiv(EPPI * (NC / 4), 256), 256, 0, stream>>>(ppi_src, ppi_dst, Q, R, EPPI, NC, 10);
    sage_div<<<cdiv(NG * NC, 256), 256, 0, stream>>>(R, CNTP, NG * NC, 12);
    gemm(R, r1_wl, nullptr, P, NG, NC, NC, 0, false);
    gemm(Q, r1_wr, r1_b,    P, NG, NC, NC, 1, true);   // emb4 [2048,4096] in P

    // ================= rows encoder (PPI graph, n=2048) =================
    gemm(P, gr_w, nullptr, H1, NG, 512, NC, 0, false);                 // h [2048,512]
    gcn_self_init<<<cdiv(NG * 512, 256), 256, 0, stream>>>(H1, DINVP, gr_b, H2, NG, 512);
    gcn_edge<<<cdiv(EPPI * 512, 256), 256, 0, stream>>>(ppi_src, ppi_dst, H1, DINVP, H2, EPPI, 9);
    leaky_inplace<<<cdiv(NG * 512, 256), 256, 0, stream>>>(H2, NG * 512);  // hr
    gemm(H2, tr_wq, tr_bq, QB, NG, 128, 512, 0, false);
    gemm(H2, tr_wk, tr_bk, KB, NG, 128, 512, 0, false);
    gemm(H2, tr_wv, tr_bv, VB, NG, 128, 512, 0, false);
    gemm(H2, tr_ws, tr_bs, out_rows, NG, 128, 512, 0, false);          // skip term
    edge_dot<<<cdiv(EPPI * 64, 256), 256, 0, stream>>>(ppi_src, ppi_dst, QB, KB, ALPHA, EPPI);
    fill_k<<<cdiv(NG, 256), 256, 0, stream>>>(MBUF, -INFINITY, NG);
    seg_max<<<cdiv(EPPI, 256), 256, 0, stream>>>(ppi_dst, ALPHA, MBUF, EPPI);
    hipMemsetAsync(ZBUF, 0, NG * 4, stream);
    seg_expsum<<<cdiv(EPPI, 256), 256, 0, stream>>>(ppi_dst, ALPHA, MBUF, ZBUF, EPPI);
    seg_norm<<<cdiv(EPPI, 256), 256, 0, stream>>>(ppi_dst, ALPHA, ZBUF, EPPI);
    tconv_scatter<<<cdiv(EPPI * 128, 256), 256, 0, stream>>>(ppi_src, ppi_dst, ALPHA, VB, out_rows, EPPI);

    // ================= cols encoder (KNN graph, n=4096) =================
    transpose(P, Q, NG, NC);                                           // embT [4096,2048]
    gemm(Q, gc_w, nullptr, H1, NC, 512, NG, 0, false);                 // h [4096,512]
    gcn_self_init<<<cdiv(NC * 512, 256), 256, 0, stream>>>(H1, DINVK, gc_b, H3, NC, 512);
    gcn_edge<<<cdiv(EKNN * 512, 256), 256, 0, stream>>>(knn_src, knn_dst, H1, DINVK, H3, EKNN, 9);
    leaky_inplace<<<cdiv(NC * 512, 256), 256, 0, stream>>>(H3, NC * 512);  // hc
    gemm(H3, tc_wq, tc_bq, QB, NC, 128, 512, 0, false);
    gemm(H3, tc_wk, tc_bk, KB, NC, 128, 512, 0, false);
    gemm(H3, tc_wv, tc_bv, VB, NC, 128, 512, 0, false);
    gemm(H3, tc_ws, tc_bs, out_cols, NC, 128, 512, 0, false);          // skip term
    edge_dot<<<cdiv(EKNN * 64, 256), 256, 0, stream>>>(knn_src, knn_dst, QB, KB, ALPHA, EKNN);
    hipMemsetAsync(STATS, 0, 16, stream);
    reduce_stats<<<256, 256, 0, stream>>>(ALPHA, EKNN, STATS);
    sigmoid_alpha<<<cdiv(EKNN, 256), 256, 0, stream>>>(ALPHA, EKNN, STATS, 3.0f);
    tconv_scatter<<<cdiv(EKNN * 128, 256), 256, 0, stream>>>(knn_src, knn_dst, ALPHA, VB, out_cols, EKNN);

    // ================= decoder =================
    gemm(out_cols, d1_w, d1_b, H1, NC, 512, 128, 2, false);
    gemm(H1, d2_w, d2_b, H2, NC, 512, 512, 2, false);
    gemm(H2, d3_w, d3_b, out_feat, NC, NG, 512, 0, false);

    (void)in_sizes; (void)n_in; (void)out_size; (void)ws_size;
}

// Round 2
// 7839.294 us; speedup vs baseline: 2.3239x; 2.3239x over previous
//
#include <hip/hip_runtime.h>
#include <math.h>

#define NG 2048
#define NC 4096
#define EKNN 61440
#define EPPI 65536

static inline int cdiv(int a, int b) { return (a + b - 1) / b; }

// ---------------- GEMM: C[M,N] = A[M,K] @ B[K,N] (+C)(+bias)(act) ----------------
// ACT: 0=none, 1=leaky(0.01), 2=relu
template<int ACT, bool BIAS, bool ACCUM>
__global__ __launch_bounds__(256)
void gemm_f32(const float* __restrict__ A, const float* __restrict__ B,
              const float* __restrict__ bias, float* __restrict__ C,
              int M, int N, int K) {
    __shared__ float As[16][64];   // [k][m]
    __shared__ float Bs[16][64];   // [k][n]
    const int tid = threadIdx.x;
    const int tx = tid & 15, ty = tid >> 4;
    const int bm = blockIdx.y << 6, bn = blockIdx.x << 6;
    float acc[4][4] = {};
    const int ar = tid >> 2, ac = (tid & 3) << 2;      // A tile: 64 rows x 16 k
    const int brk = tid >> 4, bcn = (tid & 15) << 2;   // B tile: 16 k x 64 cols
    for (int k0 = 0; k0 < K; k0 += 16) {
        const float4 va = *(const float4*)(A + (size_t)(bm + ar) * K + k0 + ac);
        const float4 vb = *(const float4*)(B + (size_t)(k0 + brk) * N + bn + bcn);
        As[ac + 0][ar] = va.x;
        As[ac + 1][ar] = va.y;
        As[ac + 2][ar] = va.z;
        As[ac + 3][ar] = va.w;
        *(float4*)(&Bs[brk][bcn]) = vb;
        __syncthreads();
        #pragma unroll
        for (int k = 0; k < 16; ++k) {
            const float4 a = *(const float4*)(&As[k][ty << 2]);
            const float4 b = *(const float4*)(&Bs[k][tx << 2]);
            acc[0][0] += a.x * b.x; acc[0][1] += a.x * b.y; acc[0][2] += a.x * b.z; acc[0][3] += a.x * b.w;
            acc[1][0] += a.y * b.x; acc[1][1] += a.y * b.y; acc[1][2] += a.y * b.z; acc[1][3] += a.y * b.w;
            acc[2][0] += a.z * b.x; acc[2][1] += a.z * b.y; acc[2][2] += a.z * b.z; acc[2][3] += a.z * b.w;
            acc[3][0] += a.w * b.x; acc[3][1] += a.w * b.y; acc[3][2] += a.w * b.z; acc[3][3] += a.w * b.w;
        }
        __syncthreads();
    }
    float4 bb = make_float4(0.f, 0.f, 0.f, 0.f);
    if (BIAS) bb = *(const float4*)(bias + bn + (tx << 2));
    #pragma unroll
    for (int i = 0; i < 4; ++i) {
        const size_t off = (size_t)(bm + (ty << 2) + i) * N + bn + (tx << 2);
        float4 v = make_float4(acc[i][0], acc[i][1], acc[i][2], acc[i][3]);
        if (ACCUM) {
            const float4 c = *(const float4*)(C + off);
            v.x += c.x; v.y += c.y; v.z += c.z; v.w += c.w;
        }
        if (BIAS) { v.x += bb.x; v.y += bb.y; v.z += bb.z; v.w += bb.w; }
        if (ACT == 1) {
            v.x = v.x > 0.f ? v.x : 0.01f * v.x;
            v.y = v.y > 0.f ? v.y : 0.01f * v.y;
            v.z = v.z > 0.f ? v.z : 0.01f * v.z;
            v.w = v.w > 0.f ? v.w : 0.01f * v.w;
        } else if (ACT == 2) {
            v.x = fmaxf(v.x, 0.f); v.y = fmaxf(v.y, 0.f);
            v.z = fmaxf(v.z, 0.f); v.w = fmaxf(v.w, 0.f);
        }
        *(float4*)(C + off) = v;
    }
}

// ---------------- transpose: out[C,R] = in[R,C]^T ----------------
__global__ __launch_bounds__(256)
void transpose_k(const float* __restrict__ in, float* __restrict__ out, int R, int C) {
    __shared__ float tile[32][33];
    const int bx = blockIdx.x << 5;   // col base in `in`
    const int by = blockIdx.y << 5;   // row base in `in`
    const int tx = threadIdx.x & 31, tg = threadIdx.x >> 5;
    #pragma unroll
    for (int i = tg; i < 32; i += 8)
        tile[i][tx] = in[(size_t)(by + i) * C + bx + tx];
    __syncthreads();
    #pragma unroll
    for (int i = tg; i < 32; i += 8)
        out[(size_t)(bx + i) * R + by + tx] = tile[tx][i];
}

// ---------------- degree / CSR build ----------------
__global__ void fill_k(float* __restrict__ p, float v, int n) {
    int i = blockIdx.x * blockDim.x + threadIdx.x;
    if (i < n) p[i] = v;
}

__global__ void count_dst(const int* __restrict__ dst, float* __restrict__ cnt, int E) {
    int e = blockIdx.x * blockDim.x + threadIdx.x;
    if (e < E) atomicAdd(&cnt[dst[e]], 1.0f);
}

__global__ void make_dinv(const float* __restrict__ cnt, float* __restrict__ dinv, int n) {
    int i = blockIdx.x * blockDim.x + threadIdx.x;
    if (i < n) dinv[i] = rsqrtf(cnt[i] + 1.0f);   // + self loop; deg >= 1 always
}

// exclusive scan of cnt (float, integral values) into rowptr[n+1]; n % 256 == 0
__global__ __launch_bounds__(256)
void scan_rowptr(const float* __restrict__ cnt, int* __restrict__ rowptr, int n) {
    __shared__ int part[257];
    const int tid = threadIdx.x;
    const int per = n >> 8;
    const int base = tid * per;
    int s = 0;
    for (int i = 0; i < per; ++i) s += (int)cnt[base + i];
    part[tid + 1] = s;
    if (tid == 0) part[0] = 0;
    __syncthreads();
    if (tid == 0)
        for (int i = 1; i <= 256; ++i) part[i] += part[i - 1];
    __syncthreads();
    int run = part[tid];
    for (int i = 0; i < per; ++i) {
        rowptr[base + i] = run;
        run += (int)cnt[base + i];
    }
    if (tid == 255) rowptr[n] = run;
}

__global__ void fill_csr(const int* __restrict__ src, const int* __restrict__ dst,
                         const int* __restrict__ rowptr, int* __restrict__ cursor,
                         int* __restrict__ srcs, int* __restrict__ eids, int E) {
    int e = blockIdx.x * blockDim.x + threadIdx.x;
    if (e >= E) return;
    int d = dst[e];
    int p = atomicAdd(&cursor[d], 1);
    int idx = rowptr[d] + p;
    srcs[idx] = src[e];
    eids[idx] = e;
}

// ---------------- CSR gathers ----------------
// mean-aggregate: out[node, :] = mean over neighbors src of x[src, :]. F = NSLOT*1024.
template<int NSLOT>
__global__ __launch_bounds__(256)
void sage_gather(const int* __restrict__ rowptr, const int* __restrict__ srcs,
                 const float* __restrict__ x, float* __restrict__ out) {
    const int F = NSLOT * 1024;
    const int node = blockIdx.x, tid = threadIdx.x;
    const int beg = rowptr[node], end = rowptr[node + 1];
    __shared__ int snb[256];
    float ax[NSLOT], ay[NSLOT], az[NSLOT], aw[NSLOT];
    #pragma unroll
    for (int j = 0; j < NSLOT; ++j) { ax[j] = ay[j] = az[j] = aw[j] = 0.f; }
    for (int c = beg; c < end; c += 256) {
        const int m = min(256, end - c);
        __syncthreads();
        if (tid < m) snb[tid] = srcs[c + tid];
        __syncthreads();
        for (int i = 0; i < m; ++i) {
            const float4* row = (const float4*)(x + (size_t)snb[i] * F);
            #pragma unroll
            for (int j = 0; j < NSLOT; ++j) {
                const float4 v = row[tid + j * 256];
                ax[j] += v.x; ay[j] += v.y; az[j] += v.z; aw[j] += v.w;
            }
        }
    }
    const float inv = 1.f / fmaxf((float)(end - beg), 1.f);
    float4* orow = (float4*)(out + (size_t)node * F);
    #pragma unroll
    for (int j = 0; j < NSLOT; ++j)
        orow[tid + j * 256] = make_float4(ax[j] * inv, ay[j] * inv, az[j] * inv, aw[j] * inv);
}

// GCN (F=512) with self-loop + bias + leaky fused:
// out[d,:] = leaky( dinv[d]*sum_s(h[s,:]*dinv[s]) + h[d,:]*dinv[d]^2 + b )
__global__ __launch_bounds__(128)
void gcn_gather(const int* __restrict__ rowptr, const int* __restrict__ srcs,
                const float* __restrict__ h, const float* __restrict__ dinv,
                const float* __restrict__ b, float* __restrict__ out) {
    const int node = blockIdx.x, tid = threadIdx.x;
    const int beg = rowptr[node], end = rowptr[node + 1];
    __shared__ int snb[128];
    __shared__ float sdi[128];
    float ax = 0.f, ay = 0.f, az = 0.f, aw = 0.f;
    for (int c = beg; c < end; c += 128) {
        const int m = min(128, end - c);
        __syncthreads();
        if (tid < m) { int s = srcs[c + tid]; snb[tid] = s; sdi[tid] = dinv[s]; }
        __syncthreads();
        for (int i = 0; i < m; ++i) {
            const float4 v = ((const float4*)(h + (size_t)snb[i] * 512))[tid];
            const float w = sdi[i];
            ax += v.x * w; ay += v.y * w; az += v.z * w; aw += v.w * w;
        }
    }
    const float dd = dinv[node];
    const float4 hv = ((const float4*)(h + (size_t)node * 512))[tid];
    const float4 bv = ((const float4*)b)[tid];
    float4 o;
    o.x = ax * dd + hv.x * dd * dd + bv.x;
    o.y = ay * dd + hv.y * dd * dd + bv.y;
    o.z = az * dd + hv.z * dd * dd + bv.z;
    o.w = aw * dd + hv.w * dd * dd + bv.w;
    o.x = o.x > 0.f ? o.x : 0.01f * o.x;
    o.y = o.y > 0.f ? o.y : 0.01f * o.y;
    o.z = o.z > 0.f ? o.z : 0.01f * o.z;
    o.w = o.w > 0.f ? o.w : 0.01f * o.w;
    ((float4*)(out + (size_t)node * 512))[tid] = o;
}

// out[d,:] += sum_e a[e] * v[src[e],:]   (F=128)
__global__ __launch_bounds__(128)
void tconv_gather(const int* __restrict__ rowptr, const int* __restrict__ srcs,
                  const int* __restrict__ eids, const float* __restrict__ alpha,
                  const float* __restrict__ v, float* __restrict__ out) {
    const int node = blockIdx.x, tid = threadIdx.x;
    const int beg = rowptr[node], end = rowptr[node + 1];
    __shared__ int snb[128];
    __shared__ float sa[128];
    float acc = 0.f;
    for (int c = beg; c < end; c += 128) {
        const int m = min(128, end - c);
        __syncthreads();
        if (tid < m) { snb[tid] = srcs[c + tid]; sa[tid] = alpha[eids[c + tid]]; }
        __syncthreads();
        for (int i = 0; i < m; ++i)
            acc += sa[i] * v[(size_t)snb[i] * 128 + tid];
    }
    out[(size_t)node * 128 + tid] += acc;
}

// ---------------- attention edge kernels ----------------
__global__ __launch_bounds__(256)
void edge_dot(const int* __restrict__ src, const int* __restrict__ dst,
              const float* __restrict__ q, const float* __restrict__ k,
              float* __restrict__ alpha, int E) {
    int wid = (blockIdx.x * blockDim.x + threadIdx.x) >> 6;
    int lane = threadIdx.x & 63;
    if (wid >= E) return;
    const int s = src[wid], d = dst[wid];
    float v = q[(size_t)d * 128 + lane] * k[(size_t)s * 128 + lane]
            + q[(size_t)d * 128 + 64 + lane] * k[(size_t)s * 128 + 64 + lane];
    #pragma unroll
    for (int off = 32; off; off >>= 1) v += __shfl_down(v, off);
    if (lane == 0) alpha[wid] = v * 0.08838834764831845f;  // 1/sqrt(128)
}

__device__ inline void atomicMaxF(float* addr, float v) {
    if (v >= 0.f) atomicMax((int*)addr, __float_as_int(v));
    else          atomicMin((unsigned int*)addr, __float_as_uint(v));
}

__global__ void seg_max(const int* __restrict__ dst, const float* __restrict__ alpha,
                        float* __restrict__ m, int E) {
    int e = blockIdx.x * blockDim.x + threadIdx.x;
    if (e < E) atomicMaxF(&m[dst[e]], alpha[e]);
}

__global__ void seg_expsum(const int* __restrict__ dst, float* __restrict__ alpha,
                           const float* __restrict__ m, float* __restrict__ z, int E) {
    int e = blockIdx.x * blockDim.x + threadIdx.x;
    if (e >= E) return;
    float ex = expf(alpha[e] - m[dst[e]]);
    alpha[e] = ex;
    atomicAdd(&z[dst[e]], ex);
}

__global__ void seg_norm(const int* __restrict__ dst, float* __restrict__ alpha,
                         const float* __restrict__ z, int E) {
    int e = blockIdx.x * blockDim.x + threadIdx.x;
    if (e >= E) return;
    float zz = z[dst[e]];
    alpha[e] /= (zz > 0.f ? zz : 1.f);
}

__global__ __launch_bounds__(256)
void reduce_stats(const float* __restrict__ a, int E, double* __restrict__ stats) {
    double s = 0.0, s2 = 0.0;
    for (int i = blockIdx.x * blockDim.x + threadIdx.x; i < E; i += gridDim.x * blockDim.x) {
        double x = a[i];
        s += x; s2 += x * x;
    }
    #pragma unroll
    for (int off = 32; off; off >>= 1) {
        s += __shfl_down(s, off);
        s2 += __shfl_down(s2, off);
    }
    __shared__ double sh[4][2];
    int w = threadIdx.x >> 6;
    if ((threadIdx.x & 63) == 0) { sh[w][0] = s; sh[w][1] = s2; }
    __syncthreads();
    if (threadIdx.x == 0) {
        double t = sh[0][0] + sh[1][0] + sh[2][0] + sh[3][0];
        double t2 = sh[0][1] + sh[1][1] + sh[2][1] + sh[3][1];
        atomicAdd(&stats[0], t);
        atomicAdd(&stats[1], t2);
    }
}

__global__ void sigmoid_alpha(float* __restrict__ alpha, int E,
                              const double* __restrict__ stats, float scale_param) {
    int i = blockIdx.x * blockDim.x + threadIdx.x;
    if (i >= E) return;
    double sum = stats[0], sumsq = stats[1];
    double mu = sum / (double)E;
    double var = (sumsq - sum * sum / (double)E) / (double)(E - 1);
    float sd = (float)sqrt(fmax(var, 0.0));
    float t = (alpha[i] - (float)mu) * (scale_param / sd);
    alpha[i] = 1.f / (1.f + expf(-t));
}

// ---------------- workspace layout (float units) ----------------
static constexpr size_t NBIG = (size_t)NG * NC;             // 8388608
static constexpr size_t OFF_P = 0;
static constexpr size_t OFF_Q = NBIG;
static constexpr size_t OFF_R = 2 * NBIG;
static constexpr size_t OFF_H1 = 3 * NBIG;
static constexpr size_t OFF_H2 = OFF_H1 + (size_t)4096 * 512;
static constexpr size_t OFF_H3 = OFF_H2 + (size_t)4096 * 512;
static constexpr size_t OFF_QB = OFF_H3 + (size_t)4096 * 512;
static constexpr size_t OFF_KB = OFF_QB + (size_t)4096 * 128;
static constexpr size_t OFF_VB = OFF_KB + (size_t)4096 * 128;
static constexpr size_t OFF_ALPHA = OFF_VB + (size_t)4096 * 128;
static constexpr size_t OFF_CNTK = OFF_ALPHA + 65536;
static constexpr size_t OFF_CNTP = OFF_CNTK + 4096;
static constexpr size_t OFF_DINVK = OFF_CNTP + 4096;
static constexpr size_t OFF_DINVP = OFF_DINVK + 4096;
static constexpr size_t OFF_M = OFF_DINVP + 4096;
static constexpr size_t OFF_Z = OFF_M + 4096;
static constexpr size_t OFF_STATS = OFF_Z + 4096;           // double[2] = 4 floats
static constexpr size_t OFF_RPK = OFF_STATS + 4;            // int[NC+1] -> 4100
static constexpr size_t OFF_RPP = OFF_RPK + 4100;           // int[NG+1] -> 2052
static constexpr size_t OFF_SRCK = OFF_RPP + 2052;          // int[EKNN]
static constexpr size_t OFF_EIDK = OFF_SRCK + EKNN;
static constexpr size_t OFF_SRCP = OFF_EIDK + EKNN;         // int[EPPI]
static constexpr size_t OFF_EIDP = OFF_SRCP + EPPI;
static constexpr size_t OFF_CUR = OFF_EIDP + EPPI;          // int[NC]

extern "C" void kernel_launch(void* const* d_in, const int* in_sizes, int n_in,
                              void* d_out, int out_size, void* d_ws, size_t ws_size,
                              hipStream_t stream) {
    const float* x      = (const float*)d_in[0];
    const int*   knn    = (const int*)d_in[1];
    const int*   ppi    = (const int*)d_in[2];
    const float* c0_wl = (const float*)d_in[3],  *c0_wr = (const float*)d_in[4],  *c0_b = (const float*)d_in[5];
    const float* r0_wl = (const float*)d_in[6],  *r0_wr = (const float*)d_in[7],  *r0_b = (const float*)d_in[8];
    const float* c1_wl = (const float*)d_in[9],  *c1_wr = (const float*)d_in[10], *c1_b = (const float*)d_in[11];
    const float* r1_wl = (const float*)d_in[12], *r1_wr = (const float*)d_in[13], *r1_b = (const float*)d_in[14];
    const float* gr_w  = (const float*)d_in[15], *gr_b  = (const float*)d_in[16];
    const float* tr_wq = (const float*)d_in[17], *tr_bq = (const float*)d_in[18];
    const float* tr_wk = (const float*)d_in[19], *tr_bk = (const float*)d_in[20];
    const float* tr_wv = (const float*)d_in[21], *tr_bv = (const float*)d_in[22];
    const float* tr_ws = (const float*)d_in[23], *tr_bs = (const float*)d_in[24];
    const float* gc_w  = (const float*)d_in[25], *gc_b  = (const float*)d_in[26];
    const float* tc_wq = (const float*)d_in[27], *tc_bq = (const float*)d_in[28];
    const float* tc_wk = (const float*)d_in[29], *tc_bk = (const float*)d_in[30];
    const float* tc_wv = (const float*)d_in[31], *tc_bv = (const float*)d_in[32];
    const float* tc_ws = (const float*)d_in[33], *tc_bs = (const float*)d_in[34];
    const float* d1_w  = (const float*)d_in[35], *d1_b  = (const float*)d_in[36];
    const float* d2_w  = (const float*)d_in[37], *d2_b  = (const float*)d_in[38];
    const float* d3_w  = (const float*)d_in[39], *d3_b  = (const float*)d_in[40];

    const int* knn_src = knn, *knn_dst = knn + EKNN;
    const int* ppi_src = ppi, *ppi_dst = ppi + EPPI;

    float* ws = (float*)d_ws;
    float* P = ws + OFF_P;
    float* Q = ws + OFF_Q;
    float* R = ws + OFF_R;
    float* H1 = ws + OFF_H1;
    float* H2 = ws + OFF_H2;
    float* H3 = ws + OFF_H3;
    float* QB = ws + OFF_QB;
    float* KB = ws + OFF_KB;
    float* VB = ws + OFF_VB;
    float* ALPHA = ws + OFF_ALPHA;
    float* CNTK = ws + OFF_CNTK;
    float* CNTP = ws + OFF_CNTP;
    float* DINVK = ws + OFF_DINVK;
    float* DINVP = ws + OFF_DINVP;
    float* MBUF = ws + OFF_M;
    float* ZBUF = ws + OFF_Z;
    double* STATS = (double*)(ws + OFF_STATS);
    int* RPK  = (int*)(ws + OFF_RPK);
    int* RPP  = (int*)(ws + OFF_RPP);
    int* SRCK = (int*)(ws + OFF_SRCK);
    int* EIDK = (int*)(ws + OFF_EIDK);
    int* SRCP = (int*)(ws + OFF_SRCP);
    int* EIDP = (int*)(ws + OFF_EIDP);
    int* CUR  = (int*)(ws + OFF_CUR);

    float* out_rows = (float*)d_out;                       // [2048,128]
    float* out_cols = out_rows + (size_t)NG * 128;         // [4096,128]
    float* out_feat = out_cols + (size_t)NC * 128;         // [4096,2048]

    auto gemm = [&](const float* A, const float* B, const float* bias, float* C,
                    int M, int N, int K, int act, bool accum) {
        dim3 g(N >> 6, M >> 6), blk(256);
        if (accum)         gemm_f32<1, true,  true ><<<g, blk, 0, stream>>>(A, B, bias, C, M, N, K);
        else if (act == 2) gemm_f32<2, true,  false><<<g, blk, 0, stream>>>(A, B, bias, C, M, N, K);
        else if (bias)     gemm_f32<0, true,  false><<<g, blk, 0, stream>>>(A, B, bias, C, M, N, K);
        else               gemm_f32<0, false, false><<<g, blk, 0, stream>>>(A, B, nullptr, C, M, N, K);
    };
    auto transpose = [&](const float* in, float* out, int Rr, int Cn) {
        transpose_k<<<dim3(Cn >> 5, Rr >> 5), 256, 0, stream>>>(in, out, Rr, Cn);
    };

    // ---- degrees + CSR build (once per graph) ----
    hipMemsetAsync(CNTK, 0, NC * 4, stream);
    hipMemsetAsync(CNTP, 0, NG * 4, stream);
    count_dst<<<cdiv(EKNN, 256), 256, 0, stream>>>(knn_dst, CNTK, EKNN);
    count_dst<<<cdiv(EPPI, 256), 256, 0, stream>>>(ppi_dst, CNTP, EPPI);
    make_dinv<<<cdiv(NC, 256), 256, 0, stream>>>(CNTK, DINVK, NC);
    make_dinv<<<cdiv(NG, 256), 256, 0, stream>>>(CNTP, DINVP, NG);
    scan_rowptr<<<1, 256, 0, stream>>>(CNTK, RPK, NC);
    scan_rowptr<<<1, 256, 0, stream>>>(CNTP, RPP, NG);
    hipMemsetAsync(CUR, 0, NC * 4, stream);
    fill_csr<<<cdiv(EKNN, 256), 256, 0, stream>>>(knn_src, knn_dst, RPK, CUR, SRCK, EIDK, EKNN);
    hipMemsetAsync(CUR, 0, NG * 4, stream);
    fill_csr<<<cdiv(EPPI, 256), 256, 0, stream>>>(ppi_src, ppi_dst, RPP, CUR, SRCP, EIDP, EPPI);

    // ================= SAGE block 0 =================
    transpose(x, Q, NG, NC);                               // xt [4096,2048]
    sage_gather<2><<<NC, 256, 0, stream>>>(RPK, SRCK, Q, R);
    gemm(R, c0_wl, nullptr, P, NC, NG, NG, 0, false);
    gemm(Q, c0_wr, c0_b,    P, NC, NG, NG, 1, true);
    transpose(P, Q, NC, NG);                               // emb1 [2048,4096]
    sage_gather<4><<<NG, 256, 0, stream>>>(RPP, SRCP, Q, R);
    gemm(R, r0_wl, nullptr, P, NG, NC, NC, 0, false);
    gemm(Q, r0_wr, r0_b,    P, NG, NC, NC, 1, true);       // emb2 [2048,4096] in P

    // ================= SAGE block 1 =================
    transpose(P, Q, NG, NC);
    sage_gather<2><<<NC, 256, 0, stream>>>(RPK, SRCK, Q, R);
    gemm(R, c1_wl, nullptr, P, NC, NG, NG, 0, false);
    gemm(Q, c1_wr, c1_b,    P, NC, NG, NG, 1, true);
    transpose(P, Q, NC, NG);
    sage_gather<4><<<NG, 256, 0, stream>>>(RPP, SRCP, Q, R);
    gemm(R, r1_wl, nullptr, P, NG, NC, NC, 0, false);
    gemm(Q, r1_wr, r1_b,    P, NG, NC, NC, 1, true);       // emb4 [2048,4096] in P

    // ================= rows encoder (PPI graph, n=2048) =================
    gemm(P, gr_w, nullptr, H1, NG, 512, NC, 0, false);                 // h [2048,512]
    gcn_gather<<<NG, 128, 0, stream>>>(RPP, SRCP, H1, DINVP, gr_b, H2);  // hr (leaky fused)
    gemm(H2, tr_wq, tr_bq, QB, NG, 128, 512, 0, false);
    gemm(H2, tr_wk, tr_bk, KB, NG, 128, 512, 0, false);
    gemm(H2, tr_wv, tr_bv, VB, NG, 128, 512, 0, false);
    gemm(H2, tr_ws, tr_bs, out_rows, NG, 128, 512, 0, false);          // skip term
    edge_dot<<<cdiv(EPPI * 64, 256), 256, 0, stream>>>(ppi_src, ppi_dst, QB, KB, ALPHA, EPPI);
    fill_k<<<cdiv(NG, 256), 256, 0, stream>>>(MBUF, -INFINITY, NG);
    seg_max<<<cdiv(EPPI, 256), 256, 0, stream>>>(ppi_dst, ALPHA, MBUF, EPPI);
    hipMemsetAsync(ZBUF, 0, NG * 4, stream);
    seg_expsum<<<cdiv(EPPI, 256), 256, 0, stream>>>(ppi_dst, ALPHA, MBUF, ZBUF, EPPI);
    seg_norm<<<cdiv(EPPI, 256), 256, 0, stream>>>(ppi_dst, ALPHA, ZBUF, EPPI);
    tconv_gather<<<NG, 128, 0, stream>>>(RPP, SRCP, EIDP, ALPHA, VB, out_rows);

    // ================= cols encoder (KNN graph, n=4096) =================
    transpose(P, Q, NG, NC);                                           // embT [4096,2048]
    gemm(Q, gc_w, nullptr, H1, NC, 512, NG, 0, false);                 // h [4096,512]
    gcn_gather<<<NC, 128, 0, stream>>>(RPK, SRCK, H1, DINVK, gc_b, H3);  // hc (leaky fused)
    gemm(H3, tc_wq, tc_bq, QB, NC, 128, 512, 0, false);
    gemm(H3, tc_wk, tc_bk, KB, NC, 128, 512, 0, false);
    gemm(H3, tc_wv, tc_bv, VB, NC, 128, 512, 0, false);
    gemm(H3, tc_ws, tc_bs, out_cols, NC, 128, 512, 0, false);          // skip term
    edge_dot<<<cdiv(EKNN * 64, 256), 256, 0, stream>>>(knn_src, knn_dst, QB, KB, ALPHA, EKNN);
    hipMemsetAsync(STATS, 0, 16, stream);
    reduce_stats<<<256, 256, 0, stream>>>(ALPHA, EKNN, STATS);
    sigmoid_alpha<<<cdiv(EKNN, 256), 256, 0, stream>>>(ALPHA, EKNN, STATS, 3.0f);
    tconv_gather<<<NC, 128, 0, stream>>>(RPK, SRCK, EIDK, ALPHA, VB, out_cols);

    // ================= decoder =================
    gemm(out_cols, d1_w, d1_b, H1, NC, 512, 128, 2, false);
    gemm(H1, d2_w, d2_b, H2, NC, 512, 512, 2, false);
    gemm(H2, d3_w, d3_b, out_feat, NC, NG, 512, 0, false);

    (void)in_sizes; (void)n_in; (void)out_size; (void)ws_size;
}

// Round 3
// 1351.604 us; speedup vs baseline: 13.4784x; 5.8000x over previous
//
#include <hip/hip_runtime.h>
#include <math.h>

#define NG 2048
#define NC 4096
#define EKNN 61440
#define EPPI 65536

typedef __attribute__((ext_vector_type(8))) short short8v;
typedef __attribute__((ext_vector_type(4))) float f32x4;

static inline int cdiv(int a, int b) { return (a + b - 1) / b; }

__device__ __forceinline__ unsigned short f2b(float f) {
    union { float f; unsigned int i; } v; v.f = f;
    unsigned int r = v.i + 0x7FFFu + ((v.i >> 16) & 1u);
    return (unsigned short)(r >> 16);
}
__device__ __forceinline__ float bl(unsigned int u) { union { unsigned int i; float f; } v; v.i = u << 16; return v.f; }
__device__ __forceinline__ float bh(unsigned int u) { union { unsigned int i; float f; } v; v.i = u & 0xFFFF0000u; return v.f; }
__device__ __forceinline__ unsigned int pk2(float a, float b) { return (unsigned int)f2b(a) | ((unsigned int)f2b(b) << 16); }

#define GLOAD_LDS16(gp, lp) __builtin_amdgcn_global_load_lds( \
    (const __attribute__((address_space(1))) void*)(gp),      \
    (__attribute__((address_space(3))) void*)(lp), 16, 0, 0)

// ================= bf16 MFMA GEMM =================
// C[M,N] = A[M,K] @ Bt[N,K]^T (+C)(+bias)(act); A,Bt bf16; C f32 or bf16.
// Tile 128x128, BK=32, 4 waves (2x2), each wave 64x64 = 4x4 fragments of 16x16x32.
// LDS XOR swizzle: chunk position p stores global chunk q = p ^ ((row>>1)&3).
template<int ACT, bool BIAS, bool ACCUM, bool OBF>
__global__ __launch_bounds__(256)
void gemm_bf16(const unsigned short* __restrict__ A,
               const unsigned short* __restrict__ Bt,
               const float* __restrict__ bias,
               float* __restrict__ Cf, unsigned short* __restrict__ Cb,
               int M, int N, int K) {
    __shared__ unsigned short lds[2][2][128 * 32];
    const int tid = threadIdx.x;
    const int lane = tid & 63, wv = tid >> 6;
    const int wm = wv >> 1, wn = wv & 1;
    const int bm = blockIdx.y << 7, bn = blockIdx.x << 7;

    const unsigned short* gA = A + (size_t)bm * K;
    const unsigned short* gB = Bt + (size_t)bn * K;

    const int rsub = lane >> 2;                          // staging: row within 16-row group
    const int qsw  = (lane & 3) ^ ((lane >> 3) & 3);     // staging: pre-swizzled source chunk
    const int KT = K >> 5;

    f32x4 acc[4][4];
    #pragma unroll
    for (int i = 0; i < 4; ++i)
        #pragma unroll
        for (int j = 0; j < 4; ++j) acc[i][j] = (f32x4){0.f, 0.f, 0.f, 0.f};

    auto stage = [&](int buf, int k0) {
        #pragma unroll
        for (int t = 0; t < 2; ++t) {
            const int br = (wv * 2 + t) * 16;            // wave-uniform
            const unsigned short* sa = gA + (size_t)(br + rsub) * K + k0 + qsw * 8;
            const unsigned short* sb = gB + (size_t)(br + rsub) * K + k0 + qsw * 8;
            GLOAD_LDS16(sa, &lds[buf][0][br * 32]);
            GLOAD_LDS16(sb, &lds[buf][1][br * 32]);
        }
    };

    const int rl = lane & 15, kg = lane >> 4;
    const int swr = (kg ^ ((rl >> 1) & 3)) * 8;          // read chunk offset (shorts)

    stage(0, 0);
    int buf = 0;
    for (int kt = 0; kt < KT; ++kt) {
        __syncthreads();                                 // drains vmcnt: buf ready
        if (kt + 1 < KT) stage(buf ^ 1, (kt + 1) << 5);
        short8v a[4], b[4];
        #pragma unroll
        for (int mi = 0; mi < 4; ++mi)
            a[mi] = *(const short8v*)&lds[buf][0][(wm * 64 + mi * 16 + rl) * 32 + swr];
        #pragma unroll
        for (int ni = 0; ni < 4; ++ni)
            b[ni] = *(const short8v*)&lds[buf][1][(wn * 64 + ni * 16 + rl) * 32 + swr];
        #pragma unroll
        for (int mi = 0; mi < 4; ++mi)
            #pragma unroll
            for (int ni = 0; ni < 4; ++ni)
                acc[mi][ni] = __builtin_amdgcn_mfma_f32_16x16x32_bf16(a[mi], b[ni], acc[mi][ni], 0, 0, 0);
        buf ^= 1;
    }

    // epilogue: D[row=(lane>>4)*4+r][col=lane&15]
    const int colL = lane & 15, rq = lane >> 4;
    #pragma unroll
    for (int mi = 0; mi < 4; ++mi) {
        const int row0 = bm + wm * 64 + mi * 16 + rq * 4;
        #pragma unroll
        for (int ni = 0; ni < 4; ++ni) {
            const int col = bn + wn * 64 + ni * 16 + colL;
            float bv = 0.f;
            if (BIAS) bv = bias[col];
            #pragma unroll
            for (int r = 0; r < 4; ++r) {
                const size_t off = (size_t)(row0 + r) * N + col;
                float v = acc[mi][ni][r];
                if (ACCUM) v += Cf[off];
                if (BIAS) v += bv;
                if (ACT == 1) v = v > 0.f ? v : 0.01f * v;
                if (ACT == 2) v = fmaxf(v, 0.f);
                if (OBF) Cb[off] = f2b(v); else Cf[off] = v;
            }
        }
    }
}

// ---------------- transpose f32 -> bf16: out[C][R] = (bf16)in[R][C]^T ----------------
__global__ __launch_bounds__(256)
void transpose_f2b(const float* __restrict__ in, unsigned short* __restrict__ out, int R, int C) {
    __shared__ float tile[32][33];
    const int bx = blockIdx.x << 5;   // col base in `in`
    const int by = blockIdx.y << 5;   // row base in `in`
    const int tx = threadIdx.x & 31, tg = threadIdx.x >> 5;
    #pragma unroll
    for (int i = tg; i < 32; i += 8)
        tile[i][tx] = in[(size_t)(by + i) * C + bx + tx];
    __syncthreads();
    #pragma unroll
    for (int i = tg; i < 32; i += 8)
        out[(size_t)(bx + i) * R + by + tx] = f2b(tile[tx][i]);
}

__global__ void conv_f2b(const float* __restrict__ in, unsigned short* __restrict__ out, int n4) {
    int i = blockIdx.x * blockDim.x + threadIdx.x;
    if (i >= n4) return;
    const float4 v = ((const float4*)in)[i];
    ((uint2*)out)[i] = make_uint2(pk2(v.x, v.y), pk2(v.z, v.w));
}

// ---------------- degree / CSR build ----------------
__global__ void fill_k(float* __restrict__ p, float v, int n) {
    int i = blockIdx.x * blockDim.x + threadIdx.x;
    if (i < n) p[i] = v;
}

__global__ void count_dst(const int* __restrict__ dst, float* __restrict__ cnt, int E) {
    int e = blockIdx.x * blockDim.x + threadIdx.x;
    if (e < E) atomicAdd(&cnt[dst[e]], 1.0f);
}

__global__ void make_dinv(const float* __restrict__ cnt, float* __restrict__ dinv, int n) {
    int i = blockIdx.x * blockDim.x + threadIdx.x;
    if (i < n) dinv[i] = rsqrtf(cnt[i] + 1.0f);
}

__global__ __launch_bounds__(256)
void scan_rowptr(const float* __restrict__ cnt, int* __restrict__ rowptr, int n) {
    __shared__ int part[257];
    const int tid = threadIdx.x;
    const int per = n >> 8;
    const int base = tid * per;
    int s = 0;
    for (int i = 0; i < per; ++i) s += (int)cnt[base + i];
    part[tid + 1] = s;
    if (tid == 0) part[0] = 0;
    __syncthreads();
    if (tid == 0)
        for (int i = 1; i <= 256; ++i) part[i] += part[i - 1];
    __syncthreads();
    int run = part[tid];
    for (int i = 0; i < per; ++i) {
        rowptr[base + i] = run;
        run += (int)cnt[base + i];
    }
    if (tid == 255) rowptr[n] = run;
}

__global__ void fill_csr(const int* __restrict__ src, const int* __restrict__ dst,
                         const int* __restrict__ rowptr, int* __restrict__ cursor,
                         int* __restrict__ srcs, int* __restrict__ eids, int E) {
    int e = blockIdx.x * blockDim.x + threadIdx.x;
    if (e >= E) return;
    int d = dst[e];
    int p = atomicAdd(&cursor[d], 1);
    int idx = rowptr[d] + p;
    srcs[idx] = src[e];
    eids[idx] = e;
}

// ---------------- CSR gathers (bf16 features) ----------------
// mean-aggregate over bf16 features, f32 accumulate, bf16 out. F = NS*2048.
template<int NS>
__global__ __launch_bounds__(256)
void sage_gather_b(const int* __restrict__ rowptr, const int* __restrict__ srcs,
                   const unsigned short* __restrict__ x, unsigned short* __restrict__ out) {
    const int F = NS * 2048;
    const int node = blockIdx.x, tid = threadIdx.x;
    const int beg = rowptr[node], end = rowptr[node + 1];
    __shared__ int snb[256];
    float acc[NS][8];
    #pragma unroll
    for (int s = 0; s < NS; ++s)
        #pragma unroll
        for (int j = 0; j < 8; ++j) acc[s][j] = 0.f;
    for (int c = beg; c < end; c += 256) {
        const int m = min(256, end - c);
        __syncthreads();
        if (tid < m) snb[tid] = srcs[c + tid];
        __syncthreads();
        for (int i = 0; i < m; ++i) {
            const uint4* row = (const uint4*)(x + (size_t)snb[i] * F);
            #pragma unroll
            for (int s = 0; s < NS; ++s) {
                const uint4 v = row[tid + s * 256];
                acc[s][0] += bl(v.x); acc[s][1] += bh(v.x);
                acc[s][2] += bl(v.y); acc[s][3] += bh(v.y);
                acc[s][4] += bl(v.z); acc[s][5] += bh(v.z);
                acc[s][6] += bl(v.w); acc[s][7] += bh(v.w);
            }
        }
    }
    const float inv = 1.f / fmaxf((float)(end - beg), 1.f);
    uint4* orow = (uint4*)(out + (size_t)node * F);
    #pragma unroll
    for (int s = 0; s < NS; ++s) {
        uint4 o;
        o.x = pk2(acc[s][0] * inv, acc[s][1] * inv);
        o.y = pk2(acc[s][2] * inv, acc[s][3] * inv);
        o.z = pk2(acc[s][4] * inv, acc[s][5] * inv);
        o.w = pk2(acc[s][6] * inv, acc[s][7] * inv);
        orow[tid + s * 256] = o;
    }
}

// GCN (F=512): out = leaky(dinv[d]*sum(h[s]*dinv[s]) + h[d]*dinv[d]^2 + b) -> bf16
__global__ __launch_bounds__(128)
void gcn_gather_b(const int* __restrict__ rowptr, const int* __restrict__ srcs,
                  const float* __restrict__ h, const float* __restrict__ dinv,
                  const float* __restrict__ b, unsigned short* __restrict__ out) {
    const int node = blockIdx.x, tid = threadIdx.x;
    const int beg = rowptr[node], end = rowptr[node + 1];
    __shared__ int snb[128];
    __shared__ float sdi[128];
    float ax = 0.f, ay = 0.f, az = 0.f, aw = 0.f;
    for (int c = beg; c < end; c += 128) {
        const int m = min(128, end - c);
        __syncthreads();
        if (tid < m) { int s = srcs[c + tid]; snb[tid] = s; sdi[tid] = dinv[s]; }
        __syncthreads();
        for (int i = 0; i < m; ++i) {
            const float4 v = ((const float4*)(h + (size_t)snb[i] * 512))[tid];
            const float w = sdi[i];
            ax += v.x * w; ay += v.y * w; az += v.z * w; aw += v.w * w;
        }
    }
    const float dd = dinv[node];
    const float4 hv = ((const float4*)(h + (size_t)node * 512))[tid];
    const float4 bv = ((const float4*)b)[tid];
    float4 o;
    o.x = ax * dd + hv.x * dd * dd + bv.x;
    o.y = ay * dd + hv.y * dd * dd + bv.y;
    o.z = az * dd + hv.z * dd * dd + bv.z;
    o.w = aw * dd + hv.w * dd * dd + bv.w;
    o.x = o.x > 0.f ? o.x : 0.01f * o.x;
    o.y = o.y > 0.f ? o.y : 0.01f * o.y;
    o.z = o.z > 0.f ? o.z : 0.01f * o.z;
    o.w = o.w > 0.f ? o.w : 0.01f * o.w;
    ((uint2*)(out + (size_t)node * 512))[tid] = make_uint2(pk2(o.x, o.y), pk2(o.z, o.w));
}

// out[d,:] += sum_e a[e] * v[src[e],:]   (F=128, f32)
__global__ __launch_bounds__(128)
void tconv_gather(const int* __restrict__ rowptr, const int* __restrict__ srcs,
                  const int* __restrict__ eids, const float* __restrict__ alpha,
                  const float* __restrict__ v, float* __restrict__ out) {
    const int node = blockIdx.x, tid = threadIdx.x;
    const int beg = rowptr[node], end = rowptr[node + 1];
    __shared__ int snb[128];
    __shared__ float sa[128];
    float acc = 0.f;
    for (int c = beg; c < end; c += 128) {
        const int m = min(128, end - c);
        __syncthreads();
        if (tid < m) { snb[tid] = srcs[c + tid]; sa[tid] = alpha[eids[c + tid]]; }
        __syncthreads();
        for (int i = 0; i < m; ++i)
            acc += sa[i] * v[(size_t)snb[i] * 128 + tid];
    }
    out[(size_t)node * 128 + tid] += acc;
}

// ---------------- attention edge kernels (f32) ----------------
__global__ __launch_bounds__(256)
void edge_dot(const int* __restrict__ src, const int* __restrict__ dst,
              const float* __restrict__ q, const float* __restrict__ k,
              float* __restrict__ alpha, int E) {
    int wid = (blockIdx.x * blockDim.x + threadIdx.x) >> 6;
    int lane = threadIdx.x & 63;
    if (wid >= E) return;
    const int s = src[wid], d = dst[wid];
    float v = q[(size_t)d * 128 + lane] * k[(size_t)s * 128 + lane]
            + q[(size_t)d * 128 + 64 + lane] * k[(size_t)s * 128 + 64 + lane];
    #pragma unroll
    for (int off = 32; off; off >>= 1) v += __shfl_down(v, off);
    if (lane == 0) alpha[wid] = v * 0.08838834764831845f;  // 1/sqrt(128)
}

__device__ inline void atomicMaxF(float* addr, float v) {
    if (v >= 0.f) atomicMax((int*)addr, __float_as_int(v));
    else          atomicMin((unsigned int*)addr, __float_as_uint(v));
}

__global__ void seg_max(const int* __restrict__ dst, const float* __restrict__ alpha,
                        float* __restrict__ m, int E) {
    int e = blockIdx.x * blockDim.x + threadIdx.x;
    if (e < E) atomicMaxF(&m[dst[e]], alpha[e]);
}

__global__ void seg_expsum(const int* __restrict__ dst, float* __restrict__ alpha,
                           const float* __restrict__ m, float* __restrict__ z, int E) {
    int e = blockIdx.x * blockDim.x + threadIdx.x;
    if (e >= E) return;
    float ex = expf(alpha[e] - m[dst[e]]);
    alpha[e] = ex;
    atomicAdd(&z[dst[e]], ex);
}

__global__ void seg_norm(const int* __restrict__ dst, float* __restrict__ alpha,
                         const float* __restrict__ z, int E) {
    int e = blockIdx.x * blockDim.x + threadIdx.x;
    if (e >= E) return;
    float zz = z[dst[e]];
    alpha[e] /= (zz > 0.f ? zz : 1.f);
}

__global__ __launch_bounds__(256)
void reduce_stats(const float* __restrict__ a, int E, double* __restrict__ stats) {
    double s = 0.0, s2 = 0.0;
    for (int i = blockIdx.x * blockDim.x + threadIdx.x; i < E; i += gridDim.x * blockDim.x) {
        double x = a[i];
        s += x; s2 += x * x;
    }
    #pragma unroll
    for (int off = 32; off; off >>= 1) {
        s += __shfl_down(s, off);
        s2 += __shfl_down(s2, off);
    }
    __shared__ double sh[4][2];
    int w = threadIdx.x >> 6;
    if ((threadIdx.x & 63) == 0) { sh[w][0] = s; sh[w][1] = s2; }
    __syncthreads();
    if (threadIdx.x == 0) {
        double t = sh[0][0] + sh[1][0] + sh[2][0] + sh[3][0];
        double t2 = sh[0][1] + sh[1][1] + sh[2][1] + sh[3][1];
        atomicAdd(&stats[0], t);
        atomicAdd(&stats[1], t2);
    }
}

__global__ void sigmoid_alpha(float* __restrict__ alpha, int E,
                              const double* __restrict__ stats, float scale_param) {
    int i = blockIdx.x * blockDim.x + threadIdx.x;
    if (i >= E) return;
    double sum = stats[0], sumsq = stats[1];
    double mu = sum / (double)E;
    double var = (sumsq - sum * sum / (double)E) / (double)(E - 1);
    float sd = (float)sqrt(fmax(var, 0.0));
    float t = (alpha[i] - (float)mu) * (scale_param / sd);
    alpha[i] = 1.f / (1.f + expf(-t));
}

// ---------------- workspace layout (float units) ----------------
static constexpr size_t NBIG = (size_t)NG * NC;               // 8388608
static constexpr size_t OFF_P    = 0;                         // f32 [8.39M]
static constexpr size_t OFF_QB16 = NBIG;                      // bf16 NBIG elts
static constexpr size_t OFF_RB16 = OFF_QB16 + NBIG / 2;       // bf16 NBIG elts
static constexpr size_t OFF_WBF  = OFF_RB16 + NBIG / 2;       // bf16 up to 2*NBIG elts (4096^2)
static constexpr size_t OFF_H1   = OFF_WBF + NBIG;            // f32 4096*512
static constexpr size_t OFF_H2B  = OFF_H1 + (size_t)4096 * 512;        // bf16 4096*512
static constexpr size_t OFF_H3B  = OFF_H2B + (size_t)4096 * 512 / 2;   // bf16 4096*512
static constexpr size_t OFF_CBF  = OFF_H3B + (size_t)4096 * 512 / 2;   // bf16 4096*128
static constexpr size_t OFF_QBUF = OFF_CBF + (size_t)4096 * 128 / 2;   // f32 4096*128
static constexpr size_t OFF_KBUF = OFF_QBUF + (size_t)4096 * 128;
static constexpr size_t OFF_VBUF = OFF_KBUF + (size_t)4096 * 128;
static constexpr size_t OFF_ALPHA = OFF_VBUF + (size_t)4096 * 128;
static constexpr size_t OFF_CNTK = OFF_ALPHA + 65536;
static constexpr size_t OFF_CNTP = OFF_CNTK + 4096;
static constexpr size_t OFF_DINVK = OFF_CNTP + 4096;
static constexpr size_t OFF_DINVP = OFF_DINVK + 4096;
static constexpr size_t OFF_M = OFF_DINVP + 4096;
static constexpr size_t OFF_Z = OFF_M + 4096;
static constexpr size_t OFF_STATS = OFF_Z + 4096;             // double[2]
static constexpr size_t OFF_RPK = OFF_STATS + 16;
static constexpr size_t OFF_RPP = OFF_RPK + 4112;
static constexpr size_t OFF_SRCK = OFF_RPP + 2064;
static constexpr size_t OFF_EIDK = OFF_SRCK + EKNN;
static constexpr size_t OFF_SRCP = OFF_EIDK + EKNN;
static constexpr size_t OFF_EIDP = OFF_SRCP + EPPI;
static constexpr size_t OFF_CUR = OFF_EIDP + EPPI;

extern "C" void kernel_launch(void* const* d_in, const int* in_sizes, int n_in,
                              void* d_out, int out_size, void* d_ws, size_t ws_size,
                              hipStream_t stream) {
    const float* x      = (const float*)d_in[0];
    const int*   knn    = (const int*)d_in[1];
    const int*   ppi    = (const int*)d_in[2];
    const float* c0_wl = (const float*)d_in[3],  *c0_wr = (const float*)d_in[4],  *c0_b = (const float*)d_in[5];
    const float* r0_wl = (const float*)d_in[6],  *r0_wr = (const float*)d_in[7],  *r0_b = (const float*)d_in[8];
    const float* c1_wl = (const float*)d_in[9],  *c1_wr = (const float*)d_in[10], *c1_b = (const float*)d_in[11];
    const float* r1_wl = (const float*)d_in[12], *r1_wr = (const float*)d_in[13], *r1_b = (const float*)d_in[14];
    const float* gr_w  = (const float*)d_in[15], *gr_b  = (const float*)d_in[16];
    const float* tr_wq = (const float*)d_in[17], *tr_bq = (const float*)d_in[18];
    const float* tr_wk = (const float*)d_in[19], *tr_bk = (const float*)d_in[20];
    const float* tr_wv = (const float*)d_in[21], *tr_bv = (const float*)d_in[22];
    const float* tr_ws = (const float*)d_in[23], *tr_bs = (const float*)d_in[24];
    const float* gc_w  = (const float*)d_in[25], *gc_b  = (const float*)d_in[26];
    const float* tc_wq = (const float*)d_in[27], *tc_bq = (const float*)d_in[28];
    const float* tc_wk = (const float*)d_in[29], *tc_bk = (const float*)d_in[30];
    const float* tc_wv = (const float*)d_in[31], *tc_bv = (const float*)d_in[32];
    const float* tc_ws = (const float*)d_in[33], *tc_bs = (const float*)d_in[34];
    const float* d1_w  = (const float*)d_in[35], *d1_b  = (const float*)d_in[36];
    const float* d2_w  = (const float*)d_in[37], *d2_b  = (const float*)d_in[38];
    const float* d3_w  = (const float*)d_in[39], *d3_b  = (const float*)d_in[40];

    const int* knn_src = knn, *knn_dst = knn + EKNN;
    const int* ppi_src = ppi, *ppi_dst = ppi + EPPI;

    float* ws = (float*)d_ws;
    float* P = ws + OFF_P;
    unsigned short* Qb = (unsigned short*)(ws + OFF_QB16);
    unsigned short* Rb = (unsigned short*)(ws + OFF_RB16);
    unsigned short* WBF = (unsigned short*)(ws + OFF_WBF);
    float* H1 = ws + OFF_H1;
    unsigned short* H2b = (unsigned short*)(ws + OFF_H2B);
    unsigned short* H3b = (unsigned short*)(ws + OFF_H3B);
    unsigned short* CBF = (unsigned short*)(ws + OFF_CBF);
    float* QB = ws + OFF_QBUF;
    float* KB = ws + OFF_KBUF;
    float* VB = ws + OFF_VBUF;
    float* ALPHA = ws + OFF_ALPHA;
    float* CNTK = ws + OFF_CNTK;
    float* CNTP = ws + OFF_CNTP;
    float* DINVK = ws + OFF_DINVK;
    float* DINVP = ws + OFF_DINVP;
    float* MBUF = ws + OFF_M;
    float* ZBUF = ws + OFF_Z;
    double* STATS = (double*)(ws + OFF_STATS);
    int* RPK  = (int*)(ws + OFF_RPK);
    int* RPP  = (int*)(ws + OFF_RPP);
    int* SRCK = (int*)(ws + OFF_SRCK);
    int* EIDK = (int*)(ws + OFF_EIDK);
    int* SRCP = (int*)(ws + OFF_SRCP);
    int* EIDP = (int*)(ws + OFF_EIDP);
    int* CUR  = (int*)(ws + OFF_CUR);

    float* out_rows = (float*)d_out;                       // [2048,128]
    float* out_cols = out_rows + (size_t)NG * 128;         // [4096,128]
    float* out_feat = out_cols + (size_t)NC * 128;         // [4096,2048]

    // W[K][N] -> WBF[N][K] bf16, then C = A @ WBF^T
    auto gemmW = [&](const float* Wsrc, int K, int N, const unsigned short* Abf,
                     const float* bias, float* Cf, unsigned short* Cb, int M, int mode) {
        transpose_f2b<<<dim3(N >> 5, K >> 5), 256, 0, stream>>>(Wsrc, WBF, K, N);
        dim3 g(N >> 7, M >> 7), blk(256);
        switch (mode) {
            case 0: gemm_bf16<0, false, false, false><<<g, blk, 0, stream>>>(Abf, WBF, nullptr, Cf, nullptr, M, N, K); break;
            case 1: gemm_bf16<1, true,  true,  false><<<g, blk, 0, stream>>>(Abf, WBF, bias, Cf, nullptr, M, N, K); break;
            case 2: gemm_bf16<0, true,  false, false><<<g, blk, 0, stream>>>(Abf, WBF, bias, Cf, nullptr, M, N, K); break;
            case 3: gemm_bf16<2, true,  false, true ><<<g, blk, 0, stream>>>(Abf, WBF, bias, nullptr, Cb, M, N, K); break;
        }
    };

    // ---- degrees + CSR ----
    hipMemsetAsync(CNTK, 0, NC * 4, stream);
    hipMemsetAsync(CNTP, 0, NG * 4, stream);
    count_dst<<<cdiv(EKNN, 256), 256, 0, stream>>>(knn_dst, CNTK, EKNN);
    count_dst<<<cdiv(EPPI, 256), 256, 0, stream>>>(ppi_dst, CNTP, EPPI);
    make_dinv<<<cdiv(NC, 256), 256, 0, stream>>>(CNTK, DINVK, NC);
    make_dinv<<<cdiv(NG, 256), 256, 0, stream>>>(CNTP, DINVP, NG);
    scan_rowptr<<<1, 256, 0, stream>>>(CNTK, RPK, NC);
    scan_rowptr<<<1, 256, 0, stream>>>(CNTP, RPP, NG);
    hipMemsetAsync(CUR, 0, NC * 4, stream);
    fill_csr<<<cdiv(EKNN, 256), 256, 0, stream>>>(knn_src, knn_dst, RPK, CUR, SRCK, EIDK, EKNN);
    hipMemsetAsync(CUR, 0, NG * 4, stream);
    fill_csr<<<cdiv(EPPI, 256), 256, 0, stream>>>(ppi_src, ppi_dst, RPP, CUR, SRCP, EIDP, EPPI);

    // ================= SAGE blocks =================
    transpose_f2b<<<dim3(NC >> 5, NG >> 5), 256, 0, stream>>>(x, Qb, NG, NC);   // Qb [NC][NG]
    const float* cwl[2] = {c0_wl, c1_wl}; const float* cwr[2] = {c0_wr, c1_wr}; const float* cbb[2] = {c0_b, c1_b};
    const float* rwl[2] = {r0_wl, r1_wl}; const float* rwr[2] = {r0_wr, r1_wr}; const float* rbb[2] = {r0_b, r1_b};
    for (int l = 0; l < 2; ++l) {
        // cells graph (n=NC, F=NG)
        sage_gather_b<1><<<NC, 256, 0, stream>>>(RPK, SRCK, Qb, Rb);
        gemmW(cwl[l], NG, NG, Rb, nullptr, P, nullptr, NC, 0);
        gemmW(cwr[l], NG, NG, Qb, cbb[l], P, nullptr, NC, 1);
        transpose_f2b<<<dim3(NG >> 5, NC >> 5), 256, 0, stream>>>(P, Qb, NC, NG);  // Qb [NG][NC]
        // genes graph (n=NG, F=NC)
        sage_gather_b<2><<<NG, 256, 0, stream>>>(RPP, SRCP, Qb, Rb);
        gemmW(rwl[l], NC, NC, Rb, nullptr, P, nullptr, NG, 0);
        gemmW(rwr[l], NC, NC, Qb, rbb[l], P, nullptr, NG, 1);                      // P = emb [NG][NC] f32
        if (l == 0)
            transpose_f2b<<<dim3(NC >> 5, NG >> 5), 256, 0, stream>>>(P, Qb, NG, NC);  // Qb [NC][NG]
    }

    // ================= rows encoder (PPI, n=2048) =================
    conv_f2b<<<cdiv((int)(NBIG / 4), 256), 256, 0, stream>>>(P, Rb, (int)(NBIG / 4));  // Rb = emb4 bf16 [NG][NC]
    gemmW(gr_w, NC, 512, Rb, nullptr, H1, nullptr, NG, 0);
    gcn_gather_b<<<NG, 128, 0, stream>>>(RPP, SRCP, H1, DINVP, gr_b, H2b);
    gemmW(tr_wq, 512, 128, H2b, tr_bq, QB, nullptr, NG, 2);
    gemmW(tr_wk, 512, 128, H2b, tr_bk, KB, nullptr, NG, 2);
    gemmW(tr_wv, 512, 128, H2b, tr_bv, VB, nullptr, NG, 2);
    gemmW(tr_ws, 512, 128, H2b, tr_bs, out_rows, nullptr, NG, 2);
    edge_dot<<<cdiv(EPPI * 64, 256), 256, 0, stream>>>(ppi_src, ppi_dst, QB, KB, ALPHA, EPPI);
    fill_k<<<cdiv(NG, 256), 256, 0, stream>>>(MBUF, -INFINITY, NG);
    seg_max<<<cdiv(EPPI, 256), 256, 0, stream>>>(ppi_dst, ALPHA, MBUF, EPPI);
    hipMemsetAsync(ZBUF, 0, NG * 4, stream);
    seg_expsum<<<cdiv(EPPI, 256), 256, 0, stream>>>(ppi_dst, ALPHA, MBUF, ZBUF, EPPI);
    seg_norm<<<cdiv(EPPI, 256), 256, 0, stream>>>(ppi_dst, ALPHA, ZBUF, EPPI);
    tconv_gather<<<NG, 128, 0, stream>>>(RPP, SRCP, EIDP, ALPHA, VB, out_rows);

    // ================= cols encoder (KNN, n=4096) =================
    transpose_f2b<<<dim3(NC >> 5, NG >> 5), 256, 0, stream>>>(P, Qb, NG, NC);  // Qb [NC][NG]
    gemmW(gc_w, NG, 512, Qb, nullptr, H1, nullptr, NC, 0);
    gcn_gather_b<<<NC, 128, 0, stream>>>(RPK, SRCK, H1, DINVK, gc_b, H3b);
    gemmW(tc_wq, 512, 128, H3b, tc_bq, QB, nullptr, NC, 2);
    gemmW(tc_wk, 512, 128, H3b, tc_bk, KB, nullptr, NC, 2);
    gemmW(tc_wv, 512, 128, H3b, tc_bv, VB, nullptr, NC, 2);
    gemmW(tc_ws, 512, 128, H3b, tc_bs, out_cols, nullptr, NC, 2);
    edge_dot<<<cdiv(EKNN * 64, 256), 256, 0, stream>>>(knn_src, knn_dst, QB, KB, ALPHA, EKNN);
    hipMemsetAsync(STATS, 0, 16, stream);
    reduce_stats<<<256, 256, 0, stream>>>(ALPHA, EKNN, STATS);
    sigmoid_alpha<<<cdiv(EKNN, 256), 256, 0, stream>>>(ALPHA, EKNN, STATS, 3.0f);
    tconv_gather<<<NC, 128, 0, stream>>>(RPK, SRCK, EIDK, ALPHA, VB, out_cols);

    // ================= decoder =================
    conv_f2b<<<cdiv(NC * 128 / 4, 256), 256, 0, stream>>>(out_cols, CBF, NC * 128 / 4);
    gemmW(d1_w, 128, 512, CBF, d1_b, nullptr, H2b, NC, 3);
    gemmW(d2_w, 512, 512, H2b, d2_b, nullptr, H3b, NC, 3);
    gemmW(d3_w, 512, NG, H3b, d3_b, out_feat, nullptr, NC, 2);

    (void)in_sizes; (void)n_in; (void)out_size; (void)ws_size;
}

// Round 5
// 1196.858 us; speedup vs baseline: 15.2210x; 1.1293x over previous
//
#include <hip/hip_runtime.h>
#include <math.h>

#define NG 2048
#define NC 4096
#define EKNN 61440
#define EPPI 65536

typedef __attribute__((ext_vector_type(8))) short short8v;
typedef __attribute__((ext_vector_type(4))) float f32x4;
typedef unsigned short ushort_t;

static inline int cdiv(int a, int b) { return (a + b - 1) / b; }

__device__ __forceinline__ unsigned short f2b(float f) {
    union { float f; unsigned int i; } v; v.f = f;
    unsigned int r = v.i + 0x7FFFu + ((v.i >> 16) & 1u);
    return (unsigned short)(r >> 16);
}
__device__ __forceinline__ float bl(unsigned int u) { union { unsigned int i; float f; } v; v.i = u << 16; return v.f; }
__device__ __forceinline__ float bh(unsigned int u) { union { unsigned int i; float f; } v; v.i = u & 0xFFFF0000u; return v.f; }
__device__ __forceinline__ unsigned int pk2(float a, float b) { return (unsigned int)f2b(a) | ((unsigned int)f2b(b) << 16); }

#define GLOAD_LDS16(gp, lp) __builtin_amdgcn_global_load_lds( \
    (const __attribute__((address_space(1))) void*)(gp),      \
    (__attribute__((address_space(3))) void*)(lp), 16, 0, 0)

// ================= bf16 MFMA GEMM (single A/B) =================
// C[M,N] = A[M,K] @ Bt[N,K]^T (+bias)(act); ACT: 0 none, 2 relu. OBF: bf16 out.
template<int ACT, bool BIAS, bool OBF>
__global__ __launch_bounds__(256)
void gemm_bf16(const ushort_t* __restrict__ A,
               const ushort_t* __restrict__ Bt,
               const float* __restrict__ bias,
               float* __restrict__ Cf, ushort_t* __restrict__ Cb,
               int M, int N, int K) {
    __shared__ ushort_t lds[2][2][128 * 32];
    const int tid = threadIdx.x;
    const int lane = tid & 63, wv = tid >> 6;
    const int wm = wv >> 1, wn = wv & 1;
    const int bm = blockIdx.y << 7, bn = blockIdx.x << 7;

    const ushort_t* gA = A + (size_t)bm * K;
    const ushort_t* gB = Bt + (size_t)bn * K;

    const int rsub = lane >> 2;
    const int qsw  = (lane & 3) ^ ((lane >> 3) & 3);
    const int KT = K >> 5;

    f32x4 acc[4][4];
    #pragma unroll
    for (int i = 0; i < 4; ++i)
        #pragma unroll
        for (int j = 0; j < 4; ++j) acc[i][j] = (f32x4){0.f, 0.f, 0.f, 0.f};

    auto stage = [&](int buf, int k0) {
        #pragma unroll
        for (int t = 0; t < 2; ++t) {
            const int br = (wv * 2 + t) * 16;
            GLOAD_LDS16(gA + (size_t)(br + rsub) * K + k0 + qsw * 8, &lds[buf][0][br * 32]);
            GLOAD_LDS16(gB + (size_t)(br + rsub) * K + k0 + qsw * 8, &lds[buf][1][br * 32]);
        }
    };

    const int rl = lane & 15, kg = lane >> 4;
    const int swr = (kg ^ ((rl >> 1) & 3)) * 8;

    stage(0, 0);
    int buf = 0;
    for (int kt = 0; kt < KT; ++kt) {
        __syncthreads();
        if (kt + 1 < KT) stage(buf ^ 1, (kt + 1) << 5);
        short8v a[4], b[4];
        #pragma unroll
        for (int mi = 0; mi < 4; ++mi)
            a[mi] = *(const short8v*)&lds[buf][0][(wm * 64 + mi * 16 + rl) * 32 + swr];
        #pragma unroll
        for (int ni = 0; ni < 4; ++ni)
            b[ni] = *(const short8v*)&lds[buf][1][(wn * 64 + ni * 16 + rl) * 32 + swr];
        #pragma unroll
        for (int mi = 0; mi < 4; ++mi)
            #pragma unroll
            for (int ni = 0; ni < 4; ++ni)
                acc[mi][ni] = __builtin_amdgcn_mfma_f32_16x16x32_bf16(a[mi], b[ni], acc[mi][ni], 0, 0, 0);
        buf ^= 1;
    }

    const int colL = lane & 15, rq = lane >> 4;
    #pragma unroll
    for (int mi = 0; mi < 4; ++mi) {
        const int row0 = bm + wm * 64 + mi * 16 + rq * 4;
        #pragma unroll
        for (int ni = 0; ni < 4; ++ni) {
            const int col = bn + wn * 64 + ni * 16 + colL;
            float bv = 0.f;
            if (BIAS) bv = bias[col];
            #pragma unroll
            for (int r = 0; r < 4; ++r) {
                const size_t off = (size_t)(row0 + r) * N + col;
                float v = acc[mi][ni][r];
                if (BIAS) v += bv;
                if (ACT == 2) v = fmaxf(v, 0.f);
                if (OBF) Cb[off] = f2b(v); else Cf[off] = v;
            }
        }
    }
}

// ================= fused SAGE GEMM =================
// Cb[M,N] = leaky( A0 @ B0t^T + A1 @ B1t^T + bias ), all bf16 in/out, K same for halves.
__global__ __launch_bounds__(256)
void gemm_sage(const ushort_t* __restrict__ A0, const ushort_t* __restrict__ B0t,
               const ushort_t* __restrict__ A1, const ushort_t* __restrict__ B1t,
               const float* __restrict__ bias, ushort_t* __restrict__ Cb,
               int M, int N, int K) {
    __shared__ ushort_t lds[2][2][128 * 32];
    const int tid = threadIdx.x;
    const int lane = tid & 63, wv = tid >> 6;
    const int wm = wv >> 1, wn = wv & 1;
    const int bm = blockIdx.y << 7, bn = blockIdx.x << 7;

    const ushort_t* gA0 = A0 + (size_t)bm * K;
    const ushort_t* gB0 = B0t + (size_t)bn * K;
    const ushort_t* gA1 = A1 + (size_t)bm * K;
    const ushort_t* gB1 = B1t + (size_t)bn * K;

    const int rsub = lane >> 2;
    const int qsw  = (lane & 3) ^ ((lane >> 3) & 3);
    const int KT = K >> 5;

    f32x4 acc[4][4];
    #pragma unroll
    for (int i = 0; i < 4; ++i)
        #pragma unroll
        for (int j = 0; j < 4; ++j) acc[i][j] = (f32x4){0.f, 0.f, 0.f, 0.f};

    auto stage = [&](int buf, int kt) {
        const int half = kt >= KT;
        const int k0 = (half ? (kt - KT) : kt) << 5;
        const ushort_t* sA = half ? gA1 : gA0;
        const ushort_t* sB = half ? gB1 : gB0;
        #pragma unroll
        for (int t = 0; t < 2; ++t) {
            const int br = (wv * 2 + t) * 16;
            GLOAD_LDS16(sA + (size_t)(br + rsub) * K + k0 + qsw * 8, &lds[buf][0][br * 32]);
            GLOAD_LDS16(sB + (size_t)(br + rsub) * K + k0 + qsw * 8, &lds[buf][1][br * 32]);
        }
    };

    const int rl = lane & 15, kg = lane >> 4;
    const int swr = (kg ^ ((rl >> 1) & 3)) * 8;

    stage(0, 0);
    int buf = 0;
    const int KT2 = KT * 2;
    for (int kt = 0; kt < KT2; ++kt) {
        __syncthreads();
        if (kt + 1 < KT2) stage(buf ^ 1, kt + 1);
        short8v a[4], b[4];
        #pragma unroll
        for (int mi = 0; mi < 4; ++mi)
            a[mi] = *(const short8v*)&lds[buf][0][(wm * 64 + mi * 16 + rl) * 32 + swr];
        #pragma unroll
        for (int ni = 0; ni < 4; ++ni)
            b[ni] = *(const short8v*)&lds[buf][1][(wn * 64 + ni * 16 + rl) * 32 + swr];
        #pragma unroll
        for (int mi = 0; mi < 4; ++mi)
            #pragma unroll
            for (int ni = 0; ni < 4; ++ni)
                acc[mi][ni] = __builtin_amdgcn_mfma_f32_16x16x32_bf16(a[mi], b[ni], acc[mi][ni], 0, 0, 0);
        buf ^= 1;
    }

    const int colL = lane & 15, rq = lane >> 4;
    #pragma unroll
    for (int mi = 0; mi < 4; ++mi) {
        const int row0 = bm + wm * 64 + mi * 16 + rq * 4;
        #pragma unroll
        for (int ni = 0; ni < 4; ++ni) {
            const int col = bn + wn * 64 + ni * 16 + colL;
            const float bv = bias[col];
            #pragma unroll
            for (int r = 0; r < 4; ++r) {
                float v = acc[mi][ni][r] + bv;
                v = v > 0.f ? v : 0.01f * v;
                Cb[(size_t)(row0 + r) * N + col] = f2b(v);
            }
        }
    }
}

// ---------------- transposes ----------------
__global__ __launch_bounds__(256)
void transpose_f2b(const float* __restrict__ in, ushort_t* __restrict__ out, int R, int C) {
    __shared__ float tile[32][33];
    const int bx = blockIdx.x << 5, by = blockIdx.y << 5;
    const int tx = threadIdx.x & 31, tg = threadIdx.x >> 5;
    #pragma unroll
    for (int i = tg; i < 32; i += 8)
        tile[i][tx] = in[(size_t)(by + i) * C + bx + tx];
    __syncthreads();
    #pragma unroll
    for (int i = tg; i < 32; i += 8)
        out[(size_t)(bx + i) * R + by + tx] = f2b(tile[tx][i]);
}

__global__ __launch_bounds__(256)
void transpose_b2b(const ushort_t* __restrict__ in, ushort_t* __restrict__ out, int R, int C) {
    __shared__ ushort_t tile[32][33];
    const int bx = blockIdx.x << 5, by = blockIdx.y << 5;
    const int tx = threadIdx.x & 31, tg = threadIdx.x >> 5;
    #pragma unroll
    for (int i = tg; i < 32; i += 8)
        tile[i][tx] = in[(size_t)(by + i) * C + bx + tx];
    __syncthreads();
    #pragma unroll
    for (int i = tg; i < 32; i += 8)
        out[(size_t)(bx + i) * R + by + tx] = tile[tx][i];
}

// ---------------- degree / CSR build ----------------
__global__ void fill_k(float* __restrict__ p, float v, int n) {
    int i = blockIdx.x * blockDim.x + threadIdx.x;
    if (i < n) p[i] = v;
}

__global__ void count_dst(const int* __restrict__ dst, float* __restrict__ cnt, int E) {
    int e = blockIdx.x * blockDim.x + threadIdx.x;
    if (e < E) atomicAdd(&cnt[dst[e]], 1.0f);
}

__global__ void make_dinv(const float* __restrict__ cnt, float* __restrict__ dinv, int n) {
    int i = blockIdx.x * blockDim.x + threadIdx.x;
    if (i < n) dinv[i] = rsqrtf(cnt[i] + 1.0f);
}

__global__ __launch_bounds__(256)
void scan_rowptr(const float* __restrict__ cnt, int* __restrict__ rowptr, int n) {
    __shared__ int part[257];
    const int tid = threadIdx.x;
    const int per = n >> 8;
    const int base = tid * per;
    int s = 0;
    for (int i = 0; i < per; ++i) s += (int)cnt[base + i];
    part[tid + 1] = s;
    if (tid == 0) part[0] = 0;
    __syncthreads();
    if (tid == 0)
        for (int i = 1; i <= 256; ++i) part[i] += part[i - 1];
    __syncthreads();
    int run = part[tid];
    for (int i = 0; i < per; ++i) {
        rowptr[base + i] = run;
        run += (int)cnt[base + i];
    }
    if (tid == 255) rowptr[n] = run;
}

__global__ void fill_csr(const int* __restrict__ src, const int* __restrict__ dst,
                         const int* __restrict__ rowptr, int* __restrict__ cursor,
                         int* __restrict__ srcs, int* __restrict__ eids, int E) {
    int e = blockIdx.x * blockDim.x + threadIdx.x;
    if (e >= E) return;
    int d = dst[e];
    int p = atomicAdd(&cursor[d], 1);
    int idx = rowptr[d] + p;
    srcs[idx] = src[e];
    eids[idx] = e;
}

__global__ void concat4(const float* __restrict__ a, const float* __restrict__ b,
                        const float* __restrict__ c, const float* __restrict__ d,
                        float* __restrict__ o) {
    int i = threadIdx.x + blockIdx.x * blockDim.x;
    if (i >= 512) return;
    float v;
    if (i < 128) v = a[i];
    else if (i < 256) v = b[i - 128];
    else if (i < 384) v = c[i - 256];
    else v = d[i - 384];
    o[i] = v;
}

// ---------------- CSR gathers ----------------
template<int NS>
__global__ __launch_bounds__(256)
void sage_gather_b(const int* __restrict__ rowptr, const int* __restrict__ srcs,
                   const ushort_t* __restrict__ x, ushort_t* __restrict__ out) {
    const int F = NS * 2048;
    const int node = blockIdx.x, tid = threadIdx.x;
    const int beg = rowptr[node], end = rowptr[node + 1];
    __shared__ int snb[256];
    float acc[NS][8];
    #pragma unroll
    for (int s = 0; s < NS; ++s)
        #pragma unroll
        for (int j = 0; j < 8; ++j) acc[s][j] = 0.f;
    for (int c = beg; c < end; c += 256) {
        const int m = min(256, end - c);
        __syncthreads();
        if (tid < m) snb[tid] = srcs[c + tid];
        __syncthreads();
        for (int i = 0; i < m; ++i) {
            const uint4* row = (const uint4*)(x + (size_t)snb[i] * F);
            #pragma unroll
            for (int s = 0; s < NS; ++s) {
                const uint4 v = row[tid + s * 256];
                acc[s][0] += bl(v.x); acc[s][1] += bh(v.x);
                acc[s][2] += bl(v.y); acc[s][3] += bh(v.y);
                acc[s][4] += bl(v.z); acc[s][5] += bh(v.z);
                acc[s][6] += bl(v.w); acc[s][7] += bh(v.w);
            }
        }
    }
    const float inv = 1.f / fmaxf((float)(end - beg), 1.f);
    uint4* orow = (uint4*)(out + (size_t)node * F);
    #pragma unroll
    for (int s = 0; s < NS; ++s) {
        uint4 o;
        o.x = pk2(acc[s][0] * inv, acc[s][1] * inv);
        o.y = pk2(acc[s][2] * inv, acc[s][3] * inv);
        o.z = pk2(acc[s][4] * inv, acc[s][5] * inv);
        o.w = pk2(acc[s][6] * inv, acc[s][7] * inv);
        orow[tid + s * 256] = o;
    }
}

// GCN (F=512): out = leaky(dinv[d]*sum(h[s]*dinv[s]) + h[d]*dinv[d]^2 + b) -> bf16
__global__ __launch_bounds__(128)
void gcn_gather_b(const int* __restrict__ rowptr, const int* __restrict__ srcs,
                  const float* __restrict__ h, const float* __restrict__ dinv,
                  const float* __restrict__ b, ushort_t* __restrict__ out) {
    const int node = blockIdx.x, tid = threadIdx.x;
    const int beg = rowptr[node], end = rowptr[node + 1];
    __shared__ int snb[128];
    __shared__ float sdi[128];
    float ax = 0.f, ay = 0.f, az = 0.f, aw = 0.f;
    for (int c = beg; c < end; c += 128) {
        const int m = min(128, end - c);
        __syncthreads();
        if (tid < m) { int s = srcs[c + tid]; snb[tid] = s; sdi[tid] = dinv[s]; }
        __syncthreads();
        for (int i = 0; i < m; ++i) {
            const float4 v = ((const float4*)(h + (size_t)snb[i] * 512))[tid];
            const float w = sdi[i];
            ax += v.x * w; ay += v.y * w; az += v.z * w; aw += v.w * w;
        }
    }
    const float dd = dinv[node];
    const float4 hv = ((const float4*)(h + (size_t)node * 512))[tid];
    const float4 bv = ((const float4*)b)[tid];
    float4 o;
    o.x = ax * dd + hv.x * dd * dd + bv.x;
    o.y = ay * dd + hv.y * dd * dd + bv.y;
    o.z = az * dd + hv.z * dd * dd + bv.z;
    o.w = aw * dd + hv.w * dd * dd + bv.w;
    o.x = o.x > 0.f ? o.x : 0.01f * o.x;
    o.y = o.y > 0.f ? o.y : 0.01f * o.y;
    o.z = o.z > 0.f ? o.z : 0.01f * o.z;
    o.w = o.w > 0.f ? o.w : 0.01f * o.w;
    ((uint2*)(out + (size_t)node * 512))[tid] = make_uint2(pk2(o.x, o.y), pk2(o.z, o.w));
}

// out[d,:] = QKVS[d, 384+..] + sum_e a[e] * QKVS[src[e], 256+..]; optional bf16 copy
template<bool WB16>
__global__ __launch_bounds__(128)
void tconv_gather_s(const int* __restrict__ rowptr, const int* __restrict__ srcs,
                    const int* __restrict__ eids, const float* __restrict__ alpha,
                    const float* __restrict__ qkvs, float* __restrict__ out,
                    ushort_t* __restrict__ ob) {
    const int node = blockIdx.x, tid = threadIdx.x;
    const int beg = rowptr[node], end = rowptr[node + 1];
    __shared__ int snb[128];
    __shared__ float sa[128];
    float acc = 0.f;
    for (int c = beg; c < end; c += 128) {
        const int m = min(128, end - c);
        __syncthreads();
        if (tid < m) { snb[tid] = srcs[c + tid]; sa[tid] = alpha[eids[c + tid]]; }
        __syncthreads();
        for (int i = 0; i < m; ++i)
            acc += sa[i] * qkvs[(size_t)snb[i] * 512 + 256 + tid];
    }
    const float r = acc + qkvs[(size_t)node * 512 + 384 + tid];
    out[(size_t)node * 128 + tid] = r;
    if (WB16) ob[(size_t)node * 128 + tid] = f2b(r);
}

// ---------------- attention edge kernels (packed QKVS stride 512) ----------------
__global__ __launch_bounds__(256)
void edge_dot_s(const int* __restrict__ src, const int* __restrict__ dst,
                const float* __restrict__ qkvs, float* __restrict__ alpha, int E) {
    int wid = (blockIdx.x * blockDim.x + threadIdx.x) >> 6;
    int lane = threadIdx.x & 63;
    if (wid >= E) return;
    const size_t qb = (size_t)dst[wid] * 512;
    const size_t kb = (size_t)src[wid] * 512 + 128;
    float v = qkvs[qb + lane] * qkvs[kb + lane]
            + qkvs[qb + 64 + lane] * qkvs[kb + 64 + lane];
    #pragma unroll
    for (int off = 32; off; off >>= 1) v += __shfl_down(v, off);
    if (lane == 0) alpha[wid] = v * 0.08838834764831845f;  // 1/sqrt(128)
}

__device__ inline void atomicMaxF(float* addr, float v) {
    if (v >= 0.f) atomicMax((int*)addr, __float_as_int(v));
    else          atomicMin((unsigned int*)addr, __float_as_uint(v));
}

__global__ void seg_max(const int* __restrict__ dst, const float* __restrict__ alpha,
                        float* __restrict__ m, int E) {
    int e = blockIdx.x * blockDim.x + threadIdx.x;
    if (e < E) atomicMaxF(&m[dst[e]], alpha[e]);
}

__global__ void seg_expsum(const int* __restrict__ dst, float* __restrict__ alpha,
                           const float* __restrict__ m, float* __restrict__ z, int E) {
    int e = blockIdx.x * blockDim.x + threadIdx.x;
    if (e >= E) return;
    float ex = expf(alpha[e] - m[dst[e]]);
    alpha[e] = ex;
    atomicAdd(&z[dst[e]], ex);
}

__global__ void seg_norm(const int* __restrict__ dst, float* __restrict__ alpha,
                         const float* __restrict__ z, int E) {
    int e = blockIdx.x * blockDim.x + threadIdx.x;
    if (e >= E) return;
    float zz = z[dst[e]];
    alpha[e] /= (zz > 0.f ? zz : 1.f);
}

__global__ __launch_bounds__(256)
void reduce_stats(const float* __restrict__ a, int E, double* __restrict__ stats) {
    double s = 0.0, s2 = 0.0;
    for (int i = blockIdx.x * blockDim.x + threadIdx.x; i < E; i += gridDim.x * blockDim.x) {
        double x = a[i];
        s += x; s2 += x * x;
    }
    #pragma unroll
    for (int off = 32; off; off >>= 1) {
        s += __shfl_down(s, off);
        s2 += __shfl_down(s2, off);
    }
    __shared__ double sh[4][2];
    int w = threadIdx.x >> 6;
    if ((threadIdx.x & 63) == 0) { sh[w][0] = s; sh[w][1] = s2; }
    __syncthreads();
    if (threadIdx.x == 0) {
        double t = sh[0][0] + sh[1][0] + sh[2][0] + sh[3][0];
        double t2 = sh[0][1] + sh[1][1] + sh[2][1] + sh[3][1];
        atomicAdd(&stats[0], t);
        atomicAdd(&stats[1], t2);
    }
}

__global__ void sigmoid_alpha(float* __restrict__ alpha, int E,
                              const double* __restrict__ stats, float scale_param) {
    int i = blockIdx.x * blockDim.x + threadIdx.x;
    if (i >= E) return;
    double sum = stats[0], sumsq = stats[1];
    double mu = sum / (double)E;
    double var = (sumsq - sum * sum / (double)E) / (double)(E - 1);
    float sd = (float)sqrt(fmax(var, 0.0));
    float t = (alpha[i] - (float)mu) * (scale_param / sd);
    alpha[i] = 1.f / (1.f + expf(-t));
}

// ---------------- workspace layout (float units) ----------------
// WBF region is 2*NBIG floats = 4*NBIG shorts = two 4096x4096 bf16 weights.
// H1/H2B/H3B/QKVS/CBF overlay INSIDE the WBF region at +2M floats: safe because
// the SAGE phase (full WBF use) doesn't touch them, and the encoder/decoder
// phases use at most the first 1M floats of WBF for weights.
static constexpr size_t NBIG = (size_t)NG * NC;               // 8388608
static constexpr size_t NBH = NBIG / 2;                       // floats per bf16 NBIG buffer
static constexpr size_t OFF_B1 = 0;
static constexpr size_t OFF_B2 = NBH;
static constexpr size_t OFF_B3 = 2 * NBH;
static constexpr size_t OFF_WBF = 3 * NBH;
static constexpr size_t OFF_H1   = OFF_WBF + 2097152;                    // f32 4096*512
static constexpr size_t OFF_H2B  = OFF_H1 + (size_t)4096 * 512;          // bf16 4096*512
static constexpr size_t OFF_H3B  = OFF_H2B + (size_t)4096 * 512 / 2;
static constexpr size_t OFF_QKVS = OFF_H3B + (size_t)4096 * 512 / 2;     // f32 4096*512
static constexpr size_t OFF_CBF  = OFF_QKVS + (size_t)4096 * 512;        // bf16 4096*128
static constexpr size_t OFF_B4 = OFF_WBF + 2 * NBIG;                     // after WBF region
static constexpr size_t OFF_ALPHA = OFF_B4 + 512;
static constexpr size_t OFF_CNTK = OFF_ALPHA + 65536;
static constexpr size_t OFF_CNTP = OFF_CNTK + 4096;
static constexpr size_t OFF_DINVK = OFF_CNTP + 4096;
static constexpr size_t OFF_DINVP = OFF_DINVK + 4096;
static constexpr size_t OFF_M = OFF_DINVP + 4096;
static constexpr size_t OFF_Z = OFF_M + 4096;
static constexpr size_t OFF_STATS = OFF_Z + 4096;             // double[2]
static constexpr size_t OFF_RPK = OFF_STATS + 16;
static constexpr size_t OFF_RPP = OFF_RPK + 4112;
static constexpr size_t OFF_SRCK = OFF_RPP + 2064;
static constexpr size_t OFF_EIDK = OFF_SRCK + EKNN;
static constexpr size_t OFF_SRCP = OFF_EIDK + EKNN;
static constexpr size_t OFF_EIDP = OFF_SRCP + EPPI;
static constexpr size_t OFF_CUR = OFF_EIDP + EPPI;
// sanity: OFF_CBF + 262144 = OFF_WBF + 2M + 2M + 1M + 1M + 2M + 0.25M < OFF_WBF + 2*NBIG  OK

extern "C" void kernel_launch(void* const* d_in, const int* in_sizes, int n_in,
                              void* d_out, int out_size, void* d_ws, size_t ws_size,
                              hipStream_t stream) {
    const float* x      = (const float*)d_in[0];
    const int*   knn    = (const int*)d_in[1];
    const int*   ppi    = (const int*)d_in[2];
    const float* c0_wl = (const float*)d_in[3],  *c0_wr = (const float*)d_in[4],  *c0_b = (const float*)d_in[5];
    const float* r0_wl = (const float*)d_in[6],  *r0_wr = (const float*)d_in[7],  *r0_b = (const float*)d_in[8];
    const float* c1_wl = (const float*)d_in[9],  *c1_wr = (const float*)d_in[10], *c1_b = (const float*)d_in[11];
    const float* r1_wl = (const float*)d_in[12], *r1_wr = (const float*)d_in[13], *r1_b = (const float*)d_in[14];
    const float* gr_w  = (const float*)d_in[15], *gr_b  = (const float*)d_in[16];
    const float* tr_wq = (const float*)d_in[17], *tr_bq = (const float*)d_in[18];
    const float* tr_wk = (const float*)d_in[19], *tr_bk = (const float*)d_in[20];
    const float* tr_wv = (const float*)d_in[21], *tr_bv = (const float*)d_in[22];
    const float* tr_ws = (const float*)d_in[23], *tr_bs = (const float*)d_in[24];
    const float* gc_w  = (const float*)d_in[25], *gc_b  = (const float*)d_in[26];
    const float* tc_wq = (const float*)d_in[27], *tc_bq = (const float*)d_in[28];
    const float* tc_wk = (const float*)d_in[29], *tc_bk = (const float*)d_in[30];
    const float* tc_wv = (const float*)d_in[31], *tc_bv = (const float*)d_in[32];
    const float* tc_ws = (const float*)d_in[33], *tc_bs = (const float*)d_in[34];
    const float* d1_w  = (const float*)d_in[35], *d1_b  = (const float*)d_in[36];
    const float* d2_w  = (const float*)d_in[37], *d2_b  = (const float*)d_in[38];
    const float* d3_w  = (const float*)d_in[39], *d3_b  = (const float*)d_in[40];

    const int* knn_src = knn, *knn_dst = knn + EKNN;
    const int* ppi_src = ppi, *ppi_dst = ppi + EPPI;

    float* ws = (float*)d_ws;
    ushort_t* B1 = (ushort_t*)(ws + OFF_B1);
    ushort_t* B2 = (ushort_t*)(ws + OFF_B2);
    ushort_t* B3 = (ushort_t*)(ws + OFF_B3);
    ushort_t* WBF0 = (ushort_t*)(ws + OFF_WBF);
    ushort_t* WBF1 = WBF0 + 2 * NBIG;            // room for one full 4096^2 bf16 weight before it
    float* H1 = ws + OFF_H1;
    ushort_t* H2b = (ushort_t*)(ws + OFF_H2B);
    ushort_t* H3b = (ushort_t*)(ws + OFF_H3B);
    float* QKVS = ws + OFF_QKVS;
    ushort_t* CBF = (ushort_t*)(ws + OFF_CBF);
    float* B4 = ws + OFF_B4;
    float* ALPHA = ws + OFF_ALPHA;
    float* CNTK = ws + OFF_CNTK;
    float* CNTP = ws + OFF_CNTP;
    float* DINVK = ws + OFF_DINVK;
    float* DINVP = ws + OFF_DINVP;
    float* MBUF = ws + OFF_M;
    float* ZBUF = ws + OFF_Z;
    double* STATS = (double*)(ws + OFF_STATS);
    int* RPK  = (int*)(ws + OFF_RPK);
    int* RPP  = (int*)(ws + OFF_RPP);
    int* SRCK = (int*)(ws + OFF_SRCK);
    int* EIDK = (int*)(ws + OFF_EIDK);
    int* SRCP = (int*)(ws + OFF_SRCP);
    int* EIDP = (int*)(ws + OFF_EIDP);
    int* CUR  = (int*)(ws + OFF_CUR);

    float* out_rows = (float*)d_out;                       // [2048,128]
    float* out_cols = out_rows + (size_t)NG * 128;         // [4096,128]
    float* out_feat = out_cols + (size_t)NC * 128;         // [4096,2048]

    auto tW = [&](const float* Wsrc, int K, int N, ushort_t* dst) {
        transpose_f2b<<<dim3(N >> 5, K >> 5), 256, 0, stream>>>(Wsrc, dst, K, N);
    };
    auto tB = [&](const ushort_t* in, ushort_t* out, int R, int C) {
        transpose_b2b<<<dim3(C >> 5, R >> 5), 256, 0, stream>>>(in, out, R, C);
    };
    auto gemm = [&](const ushort_t* Abf, const ushort_t* Wt, const float* bias,
                    float* Cf, ushort_t* Cb, int M, int N, int K, int mode) {
        dim3 g(N >> 7, M >> 7), blk(256);
        switch (mode) {
            case 0: gemm_bf16<0, false, false><<<g, blk, 0, stream>>>(Abf, Wt, nullptr, Cf, nullptr, M, N, K); break;
            case 2: gemm_bf16<0, true,  false><<<g, blk, 0, stream>>>(Abf, Wt, bias, Cf, nullptr, M, N, K); break;
            case 3: gemm_bf16<2, true,  true ><<<g, blk, 0, stream>>>(Abf, Wt, bias, nullptr, Cb, M, N, K); break;
        }
    };

    // ---- degrees + CSR ----
    hipMemsetAsync(CNTK, 0, NC * 4, stream);
    hipMemsetAsync(CNTP, 0, NG * 4, stream);
    count_dst<<<cdiv(EKNN, 256), 256, 0, stream>>>(knn_dst, CNTK, EKNN);
    count_dst<<<cdiv(EPPI, 256), 256, 0, stream>>>(ppi_dst, CNTP, EPPI);
    make_dinv<<<cdiv(NC, 256), 256, 0, stream>>>(CNTK, DINVK, NC);
    make_dinv<<<cdiv(NG, 256), 256, 0, stream>>>(CNTP, DINVP, NG);
    scan_rowptr<<<1, 256, 0, stream>>>(CNTK, RPK, NC);
    scan_rowptr<<<1, 256, 0, stream>>>(CNTP, RPP, NG);
    hipMemsetAsync(CUR, 0, NC * 4, stream);
    fill_csr<<<cdiv(EKNN, 256), 256, 0, stream>>>(knn_src, knn_dst, RPK, CUR, SRCK, EIDK, EKNN);
    hipMemsetAsync(CUR, 0, NG * 4, stream);
    fill_csr<<<cdiv(EPPI, 256), 256, 0, stream>>>(ppi_src, ppi_dst, RPP, CUR, SRCP, EIDP, EPPI);

    // ================= SAGE blocks (all bf16) =================
    transpose_f2b<<<dim3(NC >> 5, NG >> 5), 256, 0, stream>>>(x, B1, NG, NC);   // B1 [NC][NG]
    const float* cwl[2] = {c0_wl, c1_wl}; const float* cwr[2] = {c0_wr, c1_wr}; const float* cbb[2] = {c0_b, c1_b};
    const float* rwl[2] = {r0_wl, r1_wl}; const float* rwr[2] = {r0_wr, r1_wr}; const float* rbb[2] = {r0_b, r1_b};
    for (int l = 0; l < 2; ++l) {
        // cells graph: B3[NC][NG] = leaky(agg@wl + root@wr + b)
        sage_gather_b<1><<<NC, 256, 0, stream>>>(RPK, SRCK, B1, B2);
        tW(cwl[l], NG, NG, WBF0);
        tW(cwr[l], NG, NG, WBF1);
        gemm_sage<<<dim3(NG >> 7, NC >> 7), 256, 0, stream>>>(B2, WBF0, B1, WBF1, cbb[l], B3, NC, NG, NG);
        tB(B3, B1, NC, NG);                                  // B1 [NG][NC]
        // genes graph: B3[NG][NC]
        sage_gather_b<2><<<NG, 256, 0, stream>>>(RPP, SRCP, B1, B2);
        tW(rwl[l], NC, NC, WBF0);
        tW(rwr[l], NC, NC, WBF1);
        gemm_sage<<<dim3(NC >> 7, NG >> 7), 256, 0, stream>>>(B2, WBF0, B1, WBF1, rbb[l], B3, NG, NC, NC);
        if (l == 0) tB(B3, B1, NG, NC);                      // B1 [NC][NG]
    }
    // B3 = emb4 [NG][NC]; B1 gets emb4^T for cols encoder
    tB(B3, B1, NG, NC);                                      // B1 [NC][NG]

    // ================= rows encoder (PPI, n=2048) =================
    tW(gr_w, NC, 512, WBF0);
    gemm(B3, WBF0, nullptr, H1, nullptr, NG, 512, NC, 0);
    gcn_gather_b<<<NG, 128, 0, stream>>>(RPP, SRCP, H1, DINVP, gr_b, H2b);
    tW(tr_wq, 512, 128, WBF0);
    tW(tr_wk, 512, 128, WBF0 + (size_t)128 * 512);
    tW(tr_wv, 512, 128, WBF0 + (size_t)256 * 512);
    tW(tr_ws, 512, 128, WBF0 + (size_t)384 * 512);
    concat4<<<2, 256, 0, stream>>>(tr_bq, tr_bk, tr_bv, tr_bs, B4);
    gemm(H2b, WBF0, B4, QKVS, nullptr, NG, 512, 512, 2);
    edge_dot_s<<<cdiv(EPPI * 64, 256), 256, 0, stream>>>(ppi_src, ppi_dst, QKVS, ALPHA, EPPI);
    fill_k<<<cdiv(NG, 256), 256, 0, stream>>>(MBUF, -INFINITY, NG);
    seg_max<<<cdiv(EPPI, 256), 256, 0, stream>>>(ppi_dst, ALPHA, MBUF, EPPI);
    hipMemsetAsync(ZBUF, 0, NG * 4, stream);
    seg_expsum<<<cdiv(EPPI, 256), 256, 0, stream>>>(ppi_dst, ALPHA, MBUF, ZBUF, EPPI);
    seg_norm<<<cdiv(EPPI, 256), 256, 0, stream>>>(ppi_dst, ALPHA, ZBUF, EPPI);
    tconv_gather_s<false><<<NG, 128, 0, stream>>>(RPP, SRCP, EIDP, ALPHA, QKVS, out_rows, nullptr);

    // ================= cols encoder (KNN, n=4096) =================
    tW(gc_w, NG, 512, WBF0);
    gemm(B1, WBF0, nullptr, H1, nullptr, NC, 512, NG, 0);
    gcn_gather_b<<<NC, 128, 0, stream>>>(RPK, SRCK, H1, DINVK, gc_b, H3b);
    tW(tc_wq, 512, 128, WBF0);
    tW(tc_wk, 512, 128, WBF0 + (size_t)128 * 512);
    tW(tc_wv, 512, 128, WBF0 + (size_t)256 * 512);
    tW(tc_ws, 512, 128, WBF0 + (size_t)384 * 512);
    concat4<<<2, 256, 0, stream>>>(tc_bq, tc_bk, tc_bv, tc_bs, B4);
    gemm(H3b, WBF0, B4, QKVS, nullptr, NC, 512, 512, 2);
    edge_dot_s<<<cdiv(EKNN * 64, 256), 256, 0, stream>>>(knn_src, knn_dst, QKVS, ALPHA, EKNN);
    hipMemsetAsync(STATS, 0, 16, stream);
    reduce_stats<<<256, 256, 0, stream>>>(ALPHA, EKNN, STATS);
    sigmoid_alpha<<<cdiv(EKNN, 256), 256, 0, stream>>>(ALPHA, EKNN, STATS, 3.0f);
    tconv_gather_s<true><<<NC, 128, 0, stream>>>(RPK, SRCK, EIDK, ALPHA, QKVS, out_cols, CBF);

    // ================= decoder =================
    tW(d1_w, 128, 512, WBF0);
    gemm(CBF, WBF0, d1_b, nullptr, H2b, NC, 512, 128, 3);
    tW(d2_w, 512, 512, WBF0);
    gemm(H2b, WBF0, d2_b, nullptr, H3b, NC, 512, 512, 3);
    tW(d3_w, 512, NG, WBF0);
    gemm(H3b, WBF0, d3_b, out_feat, nullptr, NC, NG, 512, 2);

    (void)in_sizes; (void)n_in; (void)out_size; (void)ws_size;
}

// Round 6
// 1140.750 us; speedup vs baseline: 15.9697x; 1.0492x over previous
//
#include <hip/hip_runtime.h>
#include <math.h>

#define NG 2048
#define NC 4096
#define EKNN 61440
#define EPPI 65536

typedef __attribute__((ext_vector_type(8))) short short8v;
typedef __attribute__((ext_vector_type(4))) float f32x4;
typedef unsigned short ushort_t;

static inline int cdiv(int a, int b) { return (a + b - 1) / b; }

__device__ __forceinline__ unsigned short f2b(float f) {
    union { float f; unsigned int i; } v; v.f = f;
    unsigned int r = v.i + 0x7FFFu + ((v.i >> 16) & 1u);
    return (unsigned short)(r >> 16);
}
__device__ __forceinline__ float bl(unsigned int u) { union { unsigned int i; float f; } v; v.i = u << 16; return v.f; }
__device__ __forceinline__ float bh(unsigned int u) { union { unsigned int i; float f; } v; v.i = u & 0xFFFF0000u; return v.f; }
__device__ __forceinline__ unsigned int pk2(float a, float b) { return (unsigned int)f2b(a) | ((unsigned int)f2b(b) << 16); }

#define GLOAD_LDS16(gp, lp) __builtin_amdgcn_global_load_lds( \
    (const __attribute__((address_space(1))) void*)(gp),      \
    (__attribute__((address_space(3))) void*)(lp), 16, 0, 0)

// ================= bf16 MFMA GEMM (single A/B) =================
// C[M,N] = A[M,K] @ Bt[N,K]^T (+bias col)(act); ACT: 0 none, 2 relu. OBF: bf16 out.
template<int ACT, bool BIAS, bool OBF>
__global__ __launch_bounds__(256)
void gemm_bf16(const ushort_t* __restrict__ A,
               const ushort_t* __restrict__ Bt,
               const float* __restrict__ bias,
               float* __restrict__ Cf, ushort_t* __restrict__ Cb,
               int M, int N, int K) {
    __shared__ ushort_t lds[2][2][128 * 32];
    const int tid = threadIdx.x;
    const int lane = tid & 63, wv = tid >> 6;
    const int wm = wv >> 1, wn = wv & 1;
    const int bm = blockIdx.y << 7, bn = blockIdx.x << 7;

    const ushort_t* gA = A + (size_t)bm * K;
    const ushort_t* gB = Bt + (size_t)bn * K;

    const int rsub = lane >> 2;
    const int qsw  = (lane & 3) ^ ((lane >> 3) & 3);
    const int KT = K >> 5;

    f32x4 acc[4][4];
    #pragma unroll
    for (int i = 0; i < 4; ++i)
        #pragma unroll
        for (int j = 0; j < 4; ++j) acc[i][j] = (f32x4){0.f, 0.f, 0.f, 0.f};

    auto stage = [&](int buf, int k0) {
        #pragma unroll
        for (int t = 0; t < 2; ++t) {
            const int br = (wv * 2 + t) * 16;
            GLOAD_LDS16(gA + (size_t)(br + rsub) * K + k0 + qsw * 8, &lds[buf][0][br * 32]);
            GLOAD_LDS16(gB + (size_t)(br + rsub) * K + k0 + qsw * 8, &lds[buf][1][br * 32]);
        }
    };

    const int rl = lane & 15, kg = lane >> 4;
    const int swr = (kg ^ ((rl >> 1) & 3)) * 8;

    stage(0, 0);
    int buf = 0;
    for (int kt = 0; kt < KT; ++kt) {
        __syncthreads();
        if (kt + 1 < KT) stage(buf ^ 1, (kt + 1) << 5);
        short8v a[4], b[4];
        #pragma unroll
        for (int mi = 0; mi < 4; ++mi)
            a[mi] = *(const short8v*)&lds[buf][0][(wm * 64 + mi * 16 + rl) * 32 + swr];
        #pragma unroll
        for (int ni = 0; ni < 4; ++ni)
            b[ni] = *(const short8v*)&lds[buf][1][(wn * 64 + ni * 16 + rl) * 32 + swr];
        #pragma unroll
        for (int mi = 0; mi < 4; ++mi)
            #pragma unroll
            for (int ni = 0; ni < 4; ++ni)
                acc[mi][ni] = __builtin_amdgcn_mfma_f32_16x16x32_bf16(a[mi], b[ni], acc[mi][ni], 0, 0, 0);
        buf ^= 1;
    }

    const int colL = lane & 15, rq = lane >> 4;
    #pragma unroll
    for (int mi = 0; mi < 4; ++mi) {
        const int row0 = bm + wm * 64 + mi * 16 + rq * 4;
        #pragma unroll
        for (int ni = 0; ni < 4; ++ni) {
            const int col = bn + wn * 64 + ni * 16 + colL;
            float bv = 0.f;
            if (BIAS) bv = bias[col];
            #pragma unroll
            for (int r = 0; r < 4; ++r) {
                const size_t off = (size_t)(row0 + r) * N + col;
                float v = acc[mi][ni][r];
                if (BIAS) v += bv;
                if (ACT == 2) v = fmaxf(v, 0.f);
                if (OBF) Cb[off] = f2b(v); else Cf[off] = v;
            }
        }
    }
}

// ================= fused SAGE GEMM (swapped orientation, ROW bias) =================
// Cb[M,N] = leaky( A0 @ B0t^T + A1 @ B1t^T + bias[row] ), all bf16 in/out.
// A0/A1 are transposed weights [M][K]; B0t/B1t activations [N][K].
__global__ __launch_bounds__(256)
void gemm_sage(const ushort_t* __restrict__ A0, const ushort_t* __restrict__ B0t,
               const ushort_t* __restrict__ A1, const ushort_t* __restrict__ B1t,
               const float* __restrict__ bias, ushort_t* __restrict__ Cb,
               int M, int N, int K) {
    __shared__ ushort_t lds[2][2][128 * 32];
    const int tid = threadIdx.x;
    const int lane = tid & 63, wv = tid >> 6;
    const int wm = wv >> 1, wn = wv & 1;
    const int bm = blockIdx.y << 7, bn = blockIdx.x << 7;

    const ushort_t* gA0 = A0 + (size_t)bm * K;
    const ushort_t* gB0 = B0t + (size_t)bn * K;
    const ushort_t* gA1 = A1 + (size_t)bm * K;
    const ushort_t* gB1 = B1t + (size_t)bn * K;

    const int rsub = lane >> 2;
    const int qsw  = (lane & 3) ^ ((lane >> 3) & 3);
    const int KT = K >> 5;

    f32x4 acc[4][4];
    #pragma unroll
    for (int i = 0; i < 4; ++i)
        #pragma unroll
        for (int j = 0; j < 4; ++j) acc[i][j] = (f32x4){0.f, 0.f, 0.f, 0.f};

    auto stage = [&](int buf, int kt) {
        const int half = kt >= KT;
        const int k0 = (half ? (kt - KT) : kt) << 5;
        const ushort_t* sA = half ? gA1 : gA0;
        const ushort_t* sB = half ? gB1 : gB0;
        #pragma unroll
        for (int t = 0; t < 2; ++t) {
            const int br = (wv * 2 + t) * 16;
            GLOAD_LDS16(sA + (size_t)(br + rsub) * K + k0 + qsw * 8, &lds[buf][0][br * 32]);
            GLOAD_LDS16(sB + (size_t)(br + rsub) * K + k0 + qsw * 8, &lds[buf][1][br * 32]);
        }
    };

    const int rl = lane & 15, kg = lane >> 4;
    const int swr = (kg ^ ((rl >> 1) & 3)) * 8;

    stage(0, 0);
    int buf = 0;
    const int KT2 = KT * 2;
    for (int kt = 0; kt < KT2; ++kt) {
        __syncthreads();
        if (kt + 1 < KT2) stage(buf ^ 1, kt + 1);
        short8v a[4], b[4];
        #pragma unroll
        for (int mi = 0; mi < 4; ++mi)
            a[mi] = *(const short8v*)&lds[buf][0][(wm * 64 + mi * 16 + rl) * 32 + swr];
        #pragma unroll
        for (int ni = 0; ni < 4; ++ni)
            b[ni] = *(const short8v*)&lds[buf][1][(wn * 64 + ni * 16 + rl) * 32 + swr];
        #pragma unroll
        for (int mi = 0; mi < 4; ++mi)
            #pragma unroll
            for (int ni = 0; ni < 4; ++ni)
                acc[mi][ni] = __builtin_amdgcn_mfma_f32_16x16x32_bf16(a[mi], b[ni], acc[mi][ni], 0, 0, 0);
        buf ^= 1;
    }

    const int colL = lane & 15, rq = lane >> 4;
    #pragma unroll
    for (int mi = 0; mi < 4; ++mi) {
        const int row0 = bm + wm * 64 + mi * 16 + rq * 4;
        float bz[4];
        #pragma unroll
        for (int r = 0; r < 4; ++r) bz[r] = bias[row0 + r];
        #pragma unroll
        for (int ni = 0; ni < 4; ++ni) {
            const int col = bn + wn * 64 + ni * 16 + colL;
            #pragma unroll
            for (int r = 0; r < 4; ++r) {
                float v = acc[mi][ni][r] + bz[r];
                v = v > 0.f ? v : 0.01f * v;
                Cb[(size_t)(row0 + r) * N + col] = f2b(v);
            }
        }
    }
}

// ---------------- transposes ----------------
__global__ __launch_bounds__(256)
void transpose_f2b(const float* __restrict__ in, ushort_t* __restrict__ out, int R, int C) {
    __shared__ float tile[32][33];
    const int bx = blockIdx.x << 5, by = blockIdx.y << 5;
    const int tx = threadIdx.x & 31, tg = threadIdx.x >> 5;
    #pragma unroll
    for (int i = tg; i < 32; i += 8)
        tile[i][tx] = in[(size_t)(by + i) * C + bx + tx];
    __syncthreads();
    #pragma unroll
    for (int i = tg; i < 32; i += 8)
        out[(size_t)(bx + i) * R + by + tx] = f2b(tile[tx][i]);
}

__global__ __launch_bounds__(256)
void transpose_b2b(const ushort_t* __restrict__ in, ushort_t* __restrict__ out, int R, int C) {
    __shared__ ushort_t tile[32][33];
    const int bx = blockIdx.x << 5, by = blockIdx.y << 5;
    const int tx = threadIdx.x & 31, tg = threadIdx.x >> 5;
    #pragma unroll
    for (int i = tg; i < 32; i += 8)
        tile[i][tx] = in[(size_t)(by + i) * C + bx + tx];
    __syncthreads();
    #pragma unroll
    for (int i = tg; i < 32; i += 8)
        out[(size_t)(bx + i) * R + by + tx] = tile[tx][i];
}

// ---------------- degree / CSR build ----------------
__global__ void count_dst(const int* __restrict__ dst, float* __restrict__ cnt, int E) {
    int e = blockIdx.x * blockDim.x + threadIdx.x;
    if (e < E) atomicAdd(&cnt[dst[e]], 1.0f);
}

__global__ void make_dinv(const float* __restrict__ cnt, float* __restrict__ dinv, int n) {
    int i = blockIdx.x * blockDim.x + threadIdx.x;
    if (i < n) dinv[i] = rsqrtf(cnt[i] + 1.0f);
}

__global__ __launch_bounds__(256)
void scan_rowptr(const float* __restrict__ cnt, int* __restrict__ rowptr, int n) {
    __shared__ int part[257];
    const int tid = threadIdx.x;
    const int per = n >> 8;
    const int base = tid * per;
    int s = 0;
    for (int i = 0; i < per; ++i) s += (int)cnt[base + i];
    part[tid + 1] = s;
    if (tid == 0) part[0] = 0;
    __syncthreads();
    if (tid == 0)
        for (int i = 1; i <= 256; ++i) part[i] += part[i - 1];
    __syncthreads();
    int run = part[tid];
    for (int i = 0; i < per; ++i) {
        rowptr[base + i] = run;
        run += (int)cnt[base + i];
    }
    if (tid == 255) rowptr[n] = run;
}

__global__ void fill_csr(const int* __restrict__ src, const int* __restrict__ dst,
                         const int* __restrict__ rowptr, int* __restrict__ cursor,
                         int* __restrict__ srcs, int* __restrict__ eids, int E) {
    int e = blockIdx.x * blockDim.x + threadIdx.x;
    if (e >= E) return;
    int d = dst[e];
    int p = atomicAdd(&cursor[d], 1);
    int idx = rowptr[d] + p;
    srcs[idx] = src[e];
    eids[idx] = e;
}

__global__ void concat4(const float* __restrict__ a, const float* __restrict__ b,
                        const float* __restrict__ c, const float* __restrict__ d,
                        float* __restrict__ o) {
    int i = threadIdx.x + blockIdx.x * blockDim.x;
    if (i >= 512) return;
    float v;
    if (i < 128) v = a[i];
    else if (i < 256) v = b[i - 128];
    else if (i < 384) v = c[i - 256];
    else v = d[i - 384];
    o[i] = v;
}

// ---------------- CSR gathers ----------------
template<int NS>
__global__ __launch_bounds__(256)
void sage_gather_b(const int* __restrict__ rowptr, const int* __restrict__ srcs,
                   const ushort_t* __restrict__ x, ushort_t* __restrict__ out) {
    const int F = NS * 2048;
    const int node = blockIdx.x, tid = threadIdx.x;
    const int beg = rowptr[node], end = rowptr[node + 1];
    __shared__ int snb[256];
    float acc[NS][8];
    #pragma unroll
    for (int s = 0; s < NS; ++s)
        #pragma unroll
        for (int j = 0; j < 8; ++j) acc[s][j] = 0.f;
    for (int c = beg; c < end; c += 256) {
        const int m = min(256, end - c);
        __syncthreads();
        if (tid < m) snb[tid] = srcs[c + tid];
        __syncthreads();
        #pragma unroll 2
        for (int i = 0; i < m; ++i) {
            const uint4* row = (const uint4*)(x + (size_t)snb[i] * F);
            #pragma unroll
            for (int s = 0; s < NS; ++s) {
                const uint4 v = row[tid + s * 256];
                acc[s][0] += bl(v.x); acc[s][1] += bh(v.x);
                acc[s][2] += bl(v.y); acc[s][3] += bh(v.y);
                acc[s][4] += bl(v.z); acc[s][5] += bh(v.z);
                acc[s][6] += bl(v.w); acc[s][7] += bh(v.w);
            }
        }
    }
    const float inv = 1.f / fmaxf((float)(end - beg), 1.f);
    uint4* orow = (uint4*)(out + (size_t)node * F);
    #pragma unroll
    for (int s = 0; s < NS; ++s) {
        uint4 o;
        o.x = pk2(acc[s][0] * inv, acc[s][1] * inv);
        o.y = pk2(acc[s][2] * inv, acc[s][3] * inv);
        o.z = pk2(acc[s][4] * inv, acc[s][5] * inv);
        o.w = pk2(acc[s][6] * inv, acc[s][7] * inv);
        orow[tid + s * 256] = o;
    }
}

// GCN (F=512): out = leaky(dinv[d]*sum(h[s]*dinv[s]) + h[d]*dinv[d]^2 + b) -> bf16
__global__ __launch_bounds__(128)
void gcn_gather_b(const int* __restrict__ rowptr, const int* __restrict__ srcs,
                  const float* __restrict__ h, const float* __restrict__ dinv,
                  const float* __restrict__ b, ushort_t* __restrict__ out) {
    const int node = blockIdx.x, tid = threadIdx.x;
    const int beg = rowptr[node], end = rowptr[node + 1];
    __shared__ int snb[128];
    __shared__ float sdi[128];
    float ax = 0.f, ay = 0.f, az = 0.f, aw = 0.f;
    for (int c = beg; c < end; c += 128) {
        const int m = min(128, end - c);
        __syncthreads();
        if (tid < m) { int s = srcs[c + tid]; snb[tid] = s; sdi[tid] = dinv[s]; }
        __syncthreads();
        for (int i = 0; i < m; ++i) {
            const float4 v = ((const float4*)(h + (size_t)snb[i] * 512))[tid];
            const float w = sdi[i];
            ax += v.x * w; ay += v.y * w; az += v.z * w; aw += v.w * w;
        }
    }
    const float dd = dinv[node];
    const float4 hv = ((const float4*)(h + (size_t)node * 512))[tid];
    const float4 bv = ((const float4*)b)[tid];
    float4 o;
    o.x = ax * dd + hv.x * dd * dd + bv.x;
    o.y = ay * dd + hv.y * dd * dd + bv.y;
    o.z = az * dd + hv.z * dd * dd + bv.z;
    o.w = aw * dd + hv.w * dd * dd + bv.w;
    o.x = o.x > 0.f ? o.x : 0.01f * o.x;
    o.y = o.y > 0.f ? o.y : 0.01f * o.y;
    o.z = o.z > 0.f ? o.z : 0.01f * o.z;
    o.w = o.w > 0.f ? o.w : 0.01f * o.w;
    ((uint2*)(out + (size_t)node * 512))[tid] = make_uint2(pk2(o.x, o.y), pk2(o.z, o.w));
}

// rows: out[d,:] = skip + softmax-weighted sum over CSR edges of V rows (QKVS packed)
__global__ __launch_bounds__(128)
void tconv_softmax_gather(const int* __restrict__ rowptr, const int* __restrict__ srcs,
                          const int* __restrict__ eids, const float* __restrict__ alpha,
                          const float* __restrict__ qkvs, float* __restrict__ out) {
    const int node = blockIdx.x, tid = threadIdx.x;
    const int beg = rowptr[node], end = rowptr[node + 1];
    __shared__ int snb[128];
    __shared__ float sa[128];
    float mx = -INFINITY;
    for (int c = beg; c < end; c += 128) {
        const int m = min(128, end - c);
        __syncthreads();
        if (tid < m) sa[tid] = alpha[eids[c + tid]];
        __syncthreads();
        for (int i = 0; i < m; ++i) mx = fmaxf(mx, sa[i]);
    }
    float acc = 0.f, z = 0.f;
    for (int c = beg; c < end; c += 128) {
        const int m = min(128, end - c);
        __syncthreads();
        if (tid < m) { snb[tid] = srcs[c + tid]; sa[tid] = __expf(alpha[eids[c + tid]] - mx); }
        __syncthreads();
        for (int i = 0; i < m; ++i) {
            z += sa[i];
            acc += sa[i] * qkvs[(size_t)snb[i] * 512 + 256 + tid];
        }
    }
    const float r = acc * (z > 0.f ? 1.f / z : 0.f) + qkvs[(size_t)node * 512 + 384 + tid];
    out[(size_t)node * 128 + tid] = r;
}

// cols: out[d,:] = skip + sum sigmoid((alpha-mu)*scale/sd) * V rows; optional bf16 copy
template<bool WB16>
__global__ __launch_bounds__(128)
void tconv_sigmoid_gather(const int* __restrict__ rowptr, const int* __restrict__ srcs,
                          const int* __restrict__ eids, const float* __restrict__ alpha,
                          const float* __restrict__ qkvs, const double* __restrict__ stats,
                          float scale_param, int E, float* __restrict__ out,
                          ushort_t* __restrict__ ob) {
    const int node = blockIdx.x, tid = threadIdx.x;
    const int beg = rowptr[node], end = rowptr[node + 1];
    const double sum = stats[0], sumsq = stats[1];
    const double mu = sum / (double)E;
    const double var = (sumsq - sum * sum / (double)E) / (double)(E - 1);
    const float sd = (float)sqrt(fmax(var, 0.0));
    const float kk = scale_param / sd;
    const float fmu = (float)mu;
    __shared__ int snb[128];
    __shared__ float sa[128];
    float acc = 0.f;
    for (int c = beg; c < end; c += 128) {
        const int m = min(128, end - c);
        __syncthreads();
        if (tid < m) {
            snb[tid] = srcs[c + tid];
            const float t = (alpha[eids[c + tid]] - fmu) * kk;
            sa[tid] = 1.f / (1.f + __expf(-t));
        }
        __syncthreads();
        for (int i = 0; i < m; ++i)
            acc += sa[i] * qkvs[(size_t)snb[i] * 512 + 256 + tid];
    }
    const float r = acc + qkvs[(size_t)node * 512 + 384 + tid];
    out[(size_t)node * 128 + tid] = r;
    if (WB16) ob[(size_t)node * 128 + tid] = f2b(r);
}

// ---------------- attention edge kernel (packed QKVS stride 512) ----------------
__global__ __launch_bounds__(256)
void edge_dot_s(const int* __restrict__ src, const int* __restrict__ dst,
                const float* __restrict__ qkvs, float* __restrict__ alpha, int E) {
    int wid = (blockIdx.x * blockDim.x + threadIdx.x) >> 6;
    int lane = threadIdx.x & 63;
    if (wid >= E) return;
    const size_t qb = (size_t)dst[wid] * 512;
    const size_t kb = (size_t)src[wid] * 512 + 128;
    float v = qkvs[qb + lane] * qkvs[kb + lane]
            + qkvs[qb + 64 + lane] * qkvs[kb + 64 + lane];
    #pragma unroll
    for (int off = 32; off; off >>= 1) v += __shfl_down(v, off);
    if (lane == 0) alpha[wid] = v * 0.08838834764831845f;  // 1/sqrt(128)
}

__global__ __launch_bounds__(256)
void reduce_stats(const float* __restrict__ a, int E, double* __restrict__ stats) {
    double s = 0.0, s2 = 0.0;
    for (int i = blockIdx.x * blockDim.x + threadIdx.x; i < E; i += gridDim.x * blockDim.x) {
        double x = a[i];
        s += x; s2 += x * x;
    }
    #pragma unroll
    for (int off = 32; off; off >>= 1) {
        s += __shfl_down(s, off);
        s2 += __shfl_down(s2, off);
    }
    __shared__ double sh[4][2];
    int w = threadIdx.x >> 6;
    if ((threadIdx.x & 63) == 0) { sh[w][0] = s; sh[w][1] = s2; }
    __syncthreads();
    if (threadIdx.x == 0) {
        double t = sh[0][0] + sh[1][0] + sh[2][0] + sh[3][0];
        double t2 = sh[0][1] + sh[1][1] + sh[2][1] + sh[3][1];
        atomicAdd(&stats[0], t);
        atomicAdd(&stats[1], t2);
    }
}

// ---------------- workspace layout (float units) ----------------
static constexpr size_t NBIG = (size_t)NG * NC;               // 8388608
static constexpr size_t NBH = NBIG / 2;
static constexpr size_t OFF_B1 = 0;
static constexpr size_t OFF_B2 = NBH;
static constexpr size_t OFF_B3 = 2 * NBH;
static constexpr size_t OFF_WBF = 3 * NBH;
static constexpr size_t OFF_H1   = OFF_WBF + 2097152;                    // f32 4096*512
static constexpr size_t OFF_H2B  = OFF_H1 + (size_t)4096 * 512;          // bf16 4096*512
static constexpr size_t OFF_H3B  = OFF_H2B + (size_t)4096 * 512 / 2;
static constexpr size_t OFF_QKVS = OFF_H3B + (size_t)4096 * 512 / 2;     // f32 4096*512
static constexpr size_t OFF_CBF  = OFF_QKVS + (size_t)4096 * 512;        // bf16 4096*128
static constexpr size_t OFF_B4 = OFF_WBF + 2 * NBIG;                     // after WBF region
static constexpr size_t OFF_ALPHA = OFF_B4 + 512;
static constexpr size_t OFF_CNTK = OFF_ALPHA + 65536;
static constexpr size_t OFF_CNTP = OFF_CNTK + 4096;
static constexpr size_t OFF_DINVK = OFF_CNTP + 4096;
static constexpr size_t OFF_DINVP = OFF_DINVK + 4096;
static constexpr size_t OFF_STATS = OFF_DINVP + 4096;         // double[2]
static constexpr size_t OFF_RPK = OFF_STATS + 16;
static constexpr size_t OFF_RPP = OFF_RPK + 4112;
static constexpr size_t OFF_SRCK = OFF_RPP + 2064;
static constexpr size_t OFF_EIDK = OFF_SRCK + EKNN;
static constexpr size_t OFF_SRCP = OFF_EIDK + EKNN;
static constexpr size_t OFF_EIDP = OFF_SRCP + EPPI;
static constexpr size_t OFF_CUR = OFF_EIDP + EPPI;

extern "C" void kernel_launch(void* const* d_in, const int* in_sizes, int n_in,
                              void* d_out, int out_size, void* d_ws, size_t ws_size,
                              hipStream_t stream) {
    const float* x      = (const float*)d_in[0];
    const int*   knn    = (const int*)d_in[1];
    const int*   ppi    = (const int*)d_in[2];
    const float* c0_wl = (const float*)d_in[3],  *c0_wr = (const float*)d_in[4],  *c0_b = (const float*)d_in[5];
    const float* r0_wl = (const float*)d_in[6],  *r0_wr = (const float*)d_in[7],  *r0_b = (const float*)d_in[8];
    const float* c1_wl = (const float*)d_in[9],  *c1_wr = (const float*)d_in[10], *c1_b = (const float*)d_in[11];
    const float* r1_wl = (const float*)d_in[12], *r1_wr = (const float*)d_in[13], *r1_b = (const float*)d_in[14];
    const float* gr_w  = (const float*)d_in[15], *gr_b  = (const float*)d_in[16];
    const float* tr_wq = (const float*)d_in[17], *tr_bq = (const float*)d_in[18];
    const float* tr_wk = (const float*)d_in[19], *tr_bk = (const float*)d_in[20];
    const float* tr_wv = (const float*)d_in[21], *tr_bv = (const float*)d_in[22];
    const float* tr_ws = (const float*)d_in[23], *tr_bs = (const float*)d_in[24];
    const float* gc_w  = (const float*)d_in[25], *gc_b  = (const float*)d_in[26];
    const float* tc_wq = (const float*)d_in[27], *tc_bq = (const float*)d_in[28];
    const float* tc_wk = (const float*)d_in[29], *tc_bk = (const float*)d_in[30];
    const float* tc_wv = (const float*)d_in[31], *tc_bv = (const float*)d_in[32];
    const float* tc_ws = (const float*)d_in[33], *tc_bs = (const float*)d_in[34];
    const float* d1_w  = (const float*)d_in[35], *d1_b  = (const float*)d_in[36];
    const float* d2_w  = (const float*)d_in[37], *d2_b  = (const float*)d_in[38];
    const float* d3_w  = (const float*)d_in[39], *d3_b  = (const float*)d_in[40];

    const int* knn_src = knn, *knn_dst = knn + EKNN;
    const int* ppi_src = ppi, *ppi_dst = ppi + EPPI;

    float* ws = (float*)d_ws;
    ushort_t* B1 = (ushort_t*)(ws + OFF_B1);
    ushort_t* B2 = (ushort_t*)(ws + OFF_B2);
    ushort_t* B3 = (ushort_t*)(ws + OFF_B3);
    ushort_t* WBF0 = (ushort_t*)(ws + OFF_WBF);
    ushort_t* WBF1 = WBF0 + 2 * NBIG;
    float* H1 = ws + OFF_H1;
    ushort_t* H2b = (ushort_t*)(ws + OFF_H2B);
    ushort_t* H3b = (ushort_t*)(ws + OFF_H3B);
    float* QKVS = ws + OFF_QKVS;
    ushort_t* CBF = (ushort_t*)(ws + OFF_CBF);
    float* B4 = ws + OFF_B4;
    float* ALPHA = ws + OFF_ALPHA;
    float* CNTK = ws + OFF_CNTK;
    float* CNTP = ws + OFF_CNTP;
    float* DINVK = ws + OFF_DINVK;
    float* DINVP = ws + OFF_DINVP;
    double* STATS = (double*)(ws + OFF_STATS);
    int* RPK  = (int*)(ws + OFF_RPK);
    int* RPP  = (int*)(ws + OFF_RPP);
    int* SRCK = (int*)(ws + OFF_SRCK);
    int* EIDK = (int*)(ws + OFF_EIDK);
    int* SRCP = (int*)(ws + OFF_SRCP);
    int* EIDP = (int*)(ws + OFF_EIDP);
    int* CUR  = (int*)(ws + OFF_CUR);

    float* out_rows = (float*)d_out;                       // [2048,128]
    float* out_cols = out_rows + (size_t)NG * 128;         // [4096,128]
    float* out_feat = out_cols + (size_t)NC * 128;         // [4096,2048]

    auto tW = [&](const float* Wsrc, int K, int N, ushort_t* dst) {
        transpose_f2b<<<dim3(N >> 5, K >> 5), 256, 0, stream>>>(Wsrc, dst, K, N);
    };
    auto gemm = [&](const ushort_t* Abf, const ushort_t* Wt, const float* bias,
                    float* Cf, ushort_t* Cb, int M, int N, int K, int mode) {
        dim3 g(N >> 7, M >> 7), blk(256);
        switch (mode) {
            case 0: gemm_bf16<0, false, false><<<g, blk, 0, stream>>>(Abf, Wt, nullptr, Cf, nullptr, M, N, K); break;
            case 2: gemm_bf16<0, true,  false><<<g, blk, 0, stream>>>(Abf, Wt, bias, Cf, nullptr, M, N, K); break;
            case 3: gemm_bf16<2, true,  true ><<<g, blk, 0, stream>>>(Abf, Wt, bias, nullptr, Cb, M, N, K); break;
        }
    };

    // ---- degrees + CSR ----
    hipMemsetAsync(CNTK, 0, NC * 4, stream);
    hipMemsetAsync(CNTP, 0, NG * 4, stream);
    count_dst<<<cdiv(EKNN, 256), 256, 0, stream>>>(knn_dst, CNTK, EKNN);
    count_dst<<<cdiv(EPPI, 256), 256, 0, stream>>>(ppi_dst, CNTP, EPPI);
    make_dinv<<<cdiv(NC, 256), 256, 0, stream>>>(CNTK, DINVK, NC);
    make_dinv<<<cdiv(NG, 256), 256, 0, stream>>>(CNTP, DINVP, NG);
    scan_rowptr<<<1, 256, 0, stream>>>(CNTK, RPK, NC);
    scan_rowptr<<<1, 256, 0, stream>>>(CNTP, RPP, NG);
    hipMemsetAsync(CUR, 0, NC * 4, stream);
    fill_csr<<<cdiv(EKNN, 256), 256, 0, stream>>>(knn_src, knn_dst, RPK, CUR, SRCK, EIDK, EKNN);
    hipMemsetAsync(CUR, 0, NG * 4, stream);
    fill_csr<<<cdiv(EPPI, 256), 256, 0, stream>>>(ppi_src, ppi_dst, RPP, CUR, SRCP, EIDP, EPPI);

    // ================= SAGE blocks (all bf16, swapped outputs — zero transposes) =================
    transpose_f2b<<<dim3(NC >> 5, NG >> 5), 256, 0, stream>>>(x, B1, NG, NC);   // B1 [NC][NG]
    const float* cwl[2] = {c0_wl, c1_wl}; const float* cwr[2] = {c0_wr, c1_wr}; const float* cbb[2] = {c0_b, c1_b};
    const float* rwl[2] = {r0_wl, r1_wl}; const float* rwr[2] = {r0_wr, r1_wr}; const float* rbb[2] = {r0_b, r1_b};
    for (int l = 0; l < 2; ++l) {
        // cells graph: input B1 [NC][NG]; swapped output B3 [NG][NC]
        sage_gather_b<1><<<NC, 256, 0, stream>>>(RPK, SRCK, B1, B2);
        tW(cwl[l], NG, NG, WBF0);
        tW(cwr[l], NG, NG, WBF1);
        gemm_sage<<<dim3(NC >> 7, NG >> 7), 256, 0, stream>>>(WBF0, B2, WBF1, B1, cbb[l], B3, NG, NC, NG);
        // genes graph: input B3 [NG][NC]; swapped output B1 [NC][NG]
        sage_gather_b<2><<<NG, 256, 0, stream>>>(RPP, SRCP, B3, B2);
        tW(rwl[l], NC, NC, WBF0);
        tW(rwr[l], NC, NC, WBF1);
        gemm_sage<<<dim3(NG >> 7, NC >> 7), 256, 0, stream>>>(WBF0, B2, WBF1, B3, rbb[l], B1, NC, NG, NC);
    }
    // emb4: B1 = [NC][NG] (cols encoder); one transpose for rows encoder -> B3 [NG][NC]
    transpose_b2b<<<dim3(NG >> 5, NC >> 5), 256, 0, stream>>>(B1, B3, NC, NG);

    // ================= rows encoder (PPI, n=2048) =================
    tW(gr_w, NC, 512, WBF0);
    gemm(B3, WBF0, nullptr, H1, nullptr, NG, 512, NC, 0);
    gcn_gather_b<<<NG, 128, 0, stream>>>(RPP, SRCP, H1, DINVP, gr_b, H2b);
    tW(tr_wq, 512, 128, WBF0);
    tW(tr_wk, 512, 128, WBF0 + (size_t)128 * 512);
    tW(tr_wv, 512, 128, WBF0 + (size_t)256 * 512);
    tW(tr_ws, 512, 128, WBF0 + (size_t)384 * 512);
    concat4<<<2, 256, 0, stream>>>(tr_bq, tr_bk, tr_bv, tr_bs, B4);
    gemm(H2b, WBF0, B4, QKVS, nullptr, NG, 512, 512, 2);
    edge_dot_s<<<cdiv(EPPI * 64, 256), 256, 0, stream>>>(ppi_src, ppi_dst, QKVS, ALPHA, EPPI);
    tconv_softmax_gather<<<NG, 128, 0, stream>>>(RPP, SRCP, EIDP, ALPHA, QKVS, out_rows);

    // ================= cols encoder (KNN, n=4096) =================
    tW(gc_w, NG, 512, WBF0);
    gemm(B1, WBF0, nullptr, H1, nullptr, NC, 512, NG, 0);
    gcn_gather_b<<<NC, 128, 0, stream>>>(RPK, SRCK, H1, DINVK, gc_b, H3b);
    tW(tc_wq, 512, 128, WBF0);
    tW(tc_wk, 512, 128, WBF0 + (size_t)128 * 512);
    tW(tc_wv, 512, 128, WBF0 + (size_t)256 * 512);
    tW(tc_ws, 512, 128, WBF0 + (size_t)384 * 512);
    concat4<<<2, 256, 0, stream>>>(tc_bq, tc_bk, tc_bv, tc_bs, B4);
    gemm(H3b, WBF0, B4, QKVS, nullptr, NC, 512, 512, 2);
    edge_dot_s<<<cdiv(EKNN * 64, 256), 256, 0, stream>>>(knn_src, knn_dst, QKVS, ALPHA, EKNN);
    hipMemsetAsync(STATS, 0, 16, stream);
    reduce_stats<<<256, 256, 0, stream>>>(ALPHA, EKNN, STATS);
    tconv_sigmoid_gather<true><<<NC, 128, 0, stream>>>(RPK, SRCK, EIDK, ALPHA, QKVS, STATS, 3.0f, EKNN, out_cols, CBF);

    // ================= decoder =================
    tW(d1_w, 128, 512, WBF0);
    gemm(CBF, WBF0, d1_b, nullptr, H2b, NC, 512, 128, 3);
    tW(d2_w, 512, 512, WBF0);
    gemm(H2b, WBF0, d2_b, nullptr, H3b, NC, 512, 512, 3);
    tW(d3_w, 512, NG, WBF0);
    gemm(H3b, WBF0, d3_b, out_feat, nullptr, NC, NG, 512, 2);

    (void)in_sizes; (void)n_in; (void)out_size; (void)ws_size;
}

// Round 7
// 1070.952 us; speedup vs baseline: 17.0105x; 1.0652x over previous
//
#include <hip/hip_runtime.h>
#include <math.h>

#define NG 2048
#define NC 4096
#define EKNN 61440
#define EPPI 65536

typedef __attribute__((ext_vector_type(8))) short short8v;
typedef __attribute__((ext_vector_type(4))) float f32x4;
typedef unsigned short ushort_t;

static inline int cdiv(int a, int b) { return (a + b - 1) / b; }

__device__ __forceinline__ unsigned short f2b(float f) {
    union { float f; unsigned int i; } v; v.f = f;
    unsigned int r = v.i + 0x7FFFu + ((v.i >> 16) & 1u);
    return (unsigned short)(r >> 16);
}
__device__ __forceinline__ float bl(unsigned int u) { union { unsigned int i; float f; } v; v.i = u << 16; return v.f; }
__device__ __forceinline__ float bh(unsigned int u) { union { unsigned int i; float f; } v; v.i = u & 0xFFFF0000u; return v.f; }
__device__ __forceinline__ unsigned int pk2(float a, float b) { return (unsigned int)f2b(a) | ((unsigned int)f2b(b) << 16); }

// bijective XCD swizzle (m204): returns remapped linear block id
__device__ __forceinline__ int xcd_swz_id() {
    const int nwg = gridDim.x * gridDim.y;
    const int orig = blockIdx.y * gridDim.x + blockIdx.x;
    const int q = nwg >> 3, r = nwg & 7;
    const int xcd = orig & 7, off = orig >> 3;
    return (xcd < r ? xcd * (q + 1) : r * (q + 1) + (xcd - r) * q) + off;
}

#define GLOAD_LDS16(gp, lp) __builtin_amdgcn_global_load_lds( \
    (const __attribute__((address_space(1))) void*)(gp),      \
    (__attribute__((address_space(3))) void*)(lp), 16, 0, 0)

// ================= bf16 MFMA GEMM (single A/B) =================
// C[M,N] = A[M,K] @ Bt[N,K]^T (+bias col)(act); ACT: 0 none, 2 relu. OBF: bf16 out.
template<int ACT, bool BIAS, bool OBF>
__global__ __launch_bounds__(256)
void gemm_bf16(const ushort_t* __restrict__ A,
               const ushort_t* __restrict__ Bt,
               const float* __restrict__ bias,
               float* __restrict__ Cf, ushort_t* __restrict__ Cb,
               int M, int N, int K) {
    __shared__ ushort_t lds[2][2][128 * 32];
    const int tid = threadIdx.x;
    const int lane = tid & 63, wv = tid >> 6;
    const int wm = wv >> 1, wn = wv & 1;
    const int swzid = xcd_swz_id();
    const int bm = (swzid / gridDim.x) << 7, bn = (swzid % gridDim.x) << 7;

    const ushort_t* gA = A + (size_t)bm * K;
    const ushort_t* gB = Bt + (size_t)bn * K;

    const int rsub = lane >> 2;
    const int qsw  = (lane & 3) ^ ((lane >> 3) & 3);
    const int KT = K >> 5;

    f32x4 acc[4][4];
    #pragma unroll
    for (int i = 0; i < 4; ++i)
        #pragma unroll
        for (int j = 0; j < 4; ++j) acc[i][j] = (f32x4){0.f, 0.f, 0.f, 0.f};

    auto stage = [&](int buf, int k0) {
        #pragma unroll
        for (int t = 0; t < 2; ++t) {
            const int br = (wv * 2 + t) * 16;
            GLOAD_LDS16(gA + (size_t)(br + rsub) * K + k0 + qsw * 8, &lds[buf][0][br * 32]);
            GLOAD_LDS16(gB + (size_t)(br + rsub) * K + k0 + qsw * 8, &lds[buf][1][br * 32]);
        }
    };

    const int rl = lane & 15, kg = lane >> 4;
    const int swr = (kg ^ ((rl >> 1) & 3)) * 8;

    stage(0, 0);
    int buf = 0;
    for (int kt = 0; kt < KT; ++kt) {
        __syncthreads();
        if (kt + 1 < KT) stage(buf ^ 1, (kt + 1) << 5);
        short8v a[4], b[4];
        #pragma unroll
        for (int mi = 0; mi < 4; ++mi)
            a[mi] = *(const short8v*)&lds[buf][0][(wm * 64 + mi * 16 + rl) * 32 + swr];
        #pragma unroll
        for (int ni = 0; ni < 4; ++ni)
            b[ni] = *(const short8v*)&lds[buf][1][(wn * 64 + ni * 16 + rl) * 32 + swr];
        #pragma unroll
        for (int mi = 0; mi < 4; ++mi)
            #pragma unroll
            for (int ni = 0; ni < 4; ++ni)
                acc[mi][ni] = __builtin_amdgcn_mfma_f32_16x16x32_bf16(a[mi], b[ni], acc[mi][ni], 0, 0, 0);
        buf ^= 1;
    }

    const int colL = lane & 15, rq = lane >> 4;
    #pragma unroll
    for (int mi = 0; mi < 4; ++mi) {
        const int row0 = bm + wm * 64 + mi * 16 + rq * 4;
        #pragma unroll
        for (int ni = 0; ni < 4; ++ni) {
            const int col = bn + wn * 64 + ni * 16 + colL;
            float bv = 0.f;
            if (BIAS) bv = bias[col];
            #pragma unroll
            for (int r = 0; r < 4; ++r) {
                const size_t off = (size_t)(row0 + r) * N + col;
                float v = acc[mi][ni][r];
                if (BIAS) v += bv;
                if (ACT == 2) v = fmaxf(v, 0.f);
                if (OBF) Cb[off] = f2b(v); else Cf[off] = v;
            }
        }
    }
}

// ================= fused SAGE GEMM (swapped orientation, ROW bias) =================
// Cb[M,N] = leaky( A0 @ B0t^T + A1 @ B1t^T + bias[row] ), all bf16 in/out.
__global__ __launch_bounds__(256)
void gemm_sage(const ushort_t* __restrict__ A0, const ushort_t* __restrict__ B0t,
               const ushort_t* __restrict__ A1, const ushort_t* __restrict__ B1t,
               const float* __restrict__ bias, ushort_t* __restrict__ Cb,
               int M, int N, int K) {
    __shared__ ushort_t lds[2][2][128 * 32];
    const int tid = threadIdx.x;
    const int lane = tid & 63, wv = tid >> 6;
    const int wm = wv >> 1, wn = wv & 1;
    const int swzid = xcd_swz_id();
    const int bm = (swzid / gridDim.x) << 7, bn = (swzid % gridDim.x) << 7;

    const ushort_t* gA0 = A0 + (size_t)bm * K;
    const ushort_t* gB0 = B0t + (size_t)bn * K;
    const ushort_t* gA1 = A1 + (size_t)bm * K;
    const ushort_t* gB1 = B1t + (size_t)bn * K;

    const int rsub = lane >> 2;
    const int qsw  = (lane & 3) ^ ((lane >> 3) & 3);
    const int KT = K >> 5;

    f32x4 acc[4][4];
    #pragma unroll
    for (int i = 0; i < 4; ++i)
        #pragma unroll
        for (int j = 0; j < 4; ++j) acc[i][j] = (f32x4){0.f, 0.f, 0.f, 0.f};

    auto stage = [&](int buf, int kt) {
        const int half = kt >= KT;
        const int k0 = (half ? (kt - KT) : kt) << 5;
        const ushort_t* sA = half ? gA1 : gA0;
        const ushort_t* sB = half ? gB1 : gB0;
        #pragma unroll
        for (int t = 0; t < 2; ++t) {
            const int br = (wv * 2 + t) * 16;
            GLOAD_LDS16(sA + (size_t)(br + rsub) * K + k0 + qsw * 8, &lds[buf][0][br * 32]);
            GLOAD_LDS16(sB + (size_t)(br + rsub) * K + k0 + qsw * 8, &lds[buf][1][br * 32]);
        }
    };

    const int rl = lane & 15, kg = lane >> 4;
    const int swr = (kg ^ ((rl >> 1) & 3)) * 8;

    stage(0, 0);
    int buf = 0;
    const int KT2 = KT * 2;
    for (int kt = 0; kt < KT2; ++kt) {
        __syncthreads();
        if (kt + 1 < KT2) stage(buf ^ 1, kt + 1);
        short8v a[4], b[4];
        #pragma unroll
        for (int mi = 0; mi < 4; ++mi)
            a[mi] = *(const short8v*)&lds[buf][0][(wm * 64 + mi * 16 + rl) * 32 + swr];
        #pragma unroll
        for (int ni = 0; ni < 4; ++ni)
            b[ni] = *(const short8v*)&lds[buf][1][(wn * 64 + ni * 16 + rl) * 32 + swr];
        #pragma unroll
        for (int mi = 0; mi < 4; ++mi)
            #pragma unroll
            for (int ni = 0; ni < 4; ++ni)
                acc[mi][ni] = __builtin_amdgcn_mfma_f32_16x16x32_bf16(a[mi], b[ni], acc[mi][ni], 0, 0, 0);
        buf ^= 1;
    }

    const int colL = lane & 15, rq = lane >> 4;
    #pragma unroll
    for (int mi = 0; mi < 4; ++mi) {
        const int row0 = bm + wm * 64 + mi * 16 + rq * 4;
        float bz[4];
        #pragma unroll
        for (int r = 0; r < 4; ++r) bz[r] = bias[row0 + r];
        #pragma unroll
        for (int ni = 0; ni < 4; ++ni) {
            const int col = bn + wn * 64 + ni * 16 + colL;
            #pragma unroll
            for (int r = 0; r < 4; ++r) {
                float v = acc[mi][ni][r] + bz[r];
                v = v > 0.f ? v : 0.01f * v;
                Cb[(size_t)(row0 + r) * N + col] = f2b(v);
            }
        }
    }
}

// ---------------- transposes (64x64 tiles, vectorized) ----------------
// out[C][R] = (bf16) in[R][C]^T ; R,C multiples of 64
__global__ __launch_bounds__(256)
void transpose_f2b(const float* __restrict__ in, ushort_t* __restrict__ out, int R, int C) {
    __shared__ ushort_t t[64][65];
    const int bx = blockIdx.x << 6, by = blockIdx.y << 6;
    const int tr = threadIdx.x >> 4;
    const int tc = (threadIdx.x & 15) << 2;
    #pragma unroll
    for (int i = 0; i < 4; ++i) {
        const int rr = tr + i * 16;
        const float4 v = *(const float4*)(in + (size_t)(by + rr) * C + bx + tc);
        t[rr][tc + 0] = f2b(v.x); t[rr][tc + 1] = f2b(v.y);
        t[rr][tc + 2] = f2b(v.z); t[rr][tc + 3] = f2b(v.w);
    }
    __syncthreads();
    #pragma unroll
    for (int i = 0; i < 4; ++i) {
        const int cc = tr + i * 16;
        ushort4 o;
        o.x = t[tc + 0][cc]; o.y = t[tc + 1][cc];
        o.z = t[tc + 2][cc]; o.w = t[tc + 3][cc];
        *(ushort4*)(out + (size_t)(bx + cc) * R + by + tc) = o;
    }
}

__global__ __launch_bounds__(256)
void transpose_b2b(const ushort_t* __restrict__ in, ushort_t* __restrict__ out, int R, int C) {
    __shared__ ushort_t t[64][65];
    const int bx = blockIdx.x << 6, by = blockIdx.y << 6;
    const int tr = threadIdx.x >> 4;
    const int tc = (threadIdx.x & 15) << 2;
    #pragma unroll
    for (int i = 0; i < 4; ++i) {
        const int rr = tr + i * 16;
        const ushort4 v = *(const ushort4*)(in + (size_t)(by + rr) * C + bx + tc);
        t[rr][tc + 0] = v.x; t[rr][tc + 1] = v.y;
        t[rr][tc + 2] = v.z; t[rr][tc + 3] = v.w;
    }
    __syncthreads();
    #pragma unroll
    for (int i = 0; i < 4; ++i) {
        const int cc = tr + i * 16;
        ushort4 o;
        o.x = t[tc + 0][cc]; o.y = t[tc + 1][cc];
        o.z = t[tc + 2][cc]; o.w = t[tc + 3][cc];
        *(ushort4*)(out + (size_t)(bx + cc) * R + by + tc) = o;
    }
}

// 4 QKVS weights [512][128] f32 -> packed [512][512] bf16 (slot z rows z*128..)
__global__ __launch_bounds__(256)
void transpose_qkvs(const float* __restrict__ wq, const float* __restrict__ wk,
                    const float* __restrict__ wv, const float* __restrict__ wsk,
                    ushort_t* __restrict__ out) {
    const float* in = blockIdx.z == 0 ? wq : blockIdx.z == 1 ? wk : blockIdx.z == 2 ? wv : wsk;
    ushort_t* o = out + (size_t)blockIdx.z * 128 * 512;
    __shared__ ushort_t t[64][65];
    const int bx = blockIdx.x << 6, by = blockIdx.y << 6;   // bx: col in [0,128), by: row in [0,512)
    const int tr = threadIdx.x >> 4;
    const int tc = (threadIdx.x & 15) << 2;
    #pragma unroll
    for (int i = 0; i < 4; ++i) {
        const int rr = tr + i * 16;
        const float4 v = *(const float4*)(in + (size_t)(by + rr) * 128 + bx + tc);
        t[rr][tc + 0] = f2b(v.x); t[rr][tc + 1] = f2b(v.y);
        t[rr][tc + 2] = f2b(v.z); t[rr][tc + 3] = f2b(v.w);
    }
    __syncthreads();
    #pragma unroll
    for (int i = 0; i < 4; ++i) {
        const int cc = tr + i * 16;
        ushort4 ov;
        ov.x = t[tc + 0][cc]; ov.y = t[tc + 1][cc];
        ov.z = t[tc + 2][cc]; ov.w = t[tc + 3][cc];
        *(ushort4*)(o + (size_t)(bx + cc) * 512 + by + tc) = ov;
    }
}

// ---------------- degree / CSR build ----------------
__global__ void count_dst(const int* __restrict__ dst, float* __restrict__ cnt, int E) {
    int e = blockIdx.x * blockDim.x + threadIdx.x;
    if (e < E) atomicAdd(&cnt[dst[e]], 1.0f);
}

__global__ void make_dinv(const float* __restrict__ cnt, float* __restrict__ dinv, int n) {
    int i = blockIdx.x * blockDim.x + threadIdx.x;
    if (i < n) dinv[i] = rsqrtf(cnt[i] + 1.0f);
}

__global__ __launch_bounds__(256)
void scan_rowptr(const float* __restrict__ cnt, int* __restrict__ rowptr, int n) {
    __shared__ int part[257];
    const int tid = threadIdx.x;
    const int per = n >> 8;
    const int base = tid * per;
    int s = 0;
    for (int i = 0; i < per; ++i) s += (int)cnt[base + i];
    part[tid + 1] = s;
    if (tid == 0) part[0] = 0;
    __syncthreads();
    if (tid == 0)
        for (int i = 1; i <= 256; ++i) part[i] += part[i - 1];
    __syncthreads();
    int run = part[tid];
    for (int i = 0; i < per; ++i) {
        rowptr[base + i] = run;
        run += (int)cnt[base + i];
    }
    if (tid == 255) rowptr[n] = run;
}

__global__ void fill_csr(const int* __restrict__ src, const int* __restrict__ dst,
                         const int* __restrict__ rowptr, int* __restrict__ cursor,
                         int* __restrict__ srcs, int* __restrict__ eids, int E) {
    int e = blockIdx.x * blockDim.x + threadIdx.x;
    if (e >= E) return;
    int d = dst[e];
    int p = atomicAdd(&cursor[d], 1);
    int idx = rowptr[d] + p;
    srcs[idx] = src[e];
    eids[idx] = e;
}

__global__ void concat4(const float* __restrict__ a, const float* __restrict__ b,
                        const float* __restrict__ c, const float* __restrict__ d,
                        float* __restrict__ o) {
    int i = threadIdx.x + blockIdx.x * blockDim.x;
    if (i >= 512) return;
    float v;
    if (i < 128) v = a[i];
    else if (i < 256) v = b[i - 128];
    else if (i < 384) v = c[i - 256];
    else v = d[i - 384];
    o[i] = v;
}

// ---------------- CSR gathers ----------------
template<int NS>
__global__ __launch_bounds__(256)
void sage_gather_b(const int* __restrict__ rowptr, const int* __restrict__ srcs,
                   const ushort_t* __restrict__ x, ushort_t* __restrict__ out) {
    const int F = NS * 2048;
    const int node = blockIdx.x, tid = threadIdx.x;
    const int beg = rowptr[node], end = rowptr[node + 1];
    __shared__ int snb[256];
    float acc[NS][8];
    #pragma unroll
    for (int s = 0; s < NS; ++s)
        #pragma unroll
        for (int j = 0; j < 8; ++j) acc[s][j] = 0.f;
    for (int c = beg; c < end; c += 256) {
        const int m = min(256, end - c);
        __syncthreads();
        if (tid < m) snb[tid] = srcs[c + tid];
        __syncthreads();
        #pragma unroll 2
        for (int i = 0; i < m; ++i) {
            const uint4* row = (const uint4*)(x + (size_t)snb[i] * F);
            #pragma unroll
            for (int s = 0; s < NS; ++s) {
                const uint4 v = row[tid + s * 256];
                acc[s][0] += bl(v.x); acc[s][1] += bh(v.x);
                acc[s][2] += bl(v.y); acc[s][3] += bh(v.y);
                acc[s][4] += bl(v.z); acc[s][5] += bh(v.z);
                acc[s][6] += bl(v.w); acc[s][7] += bh(v.w);
            }
        }
    }
    const float inv = 1.f / fmaxf((float)(end - beg), 1.f);
    uint4* orow = (uint4*)(out + (size_t)node * F);
    #pragma unroll
    for (int s = 0; s < NS; ++s) {
        uint4 o;
        o.x = pk2(acc[s][0] * inv, acc[s][1] * inv);
        o.y = pk2(acc[s][2] * inv, acc[s][3] * inv);
        o.z = pk2(acc[s][4] * inv, acc[s][5] * inv);
        o.w = pk2(acc[s][6] * inv, acc[s][7] * inv);
        orow[tid + s * 256] = o;
    }
}

// GCN (F=512): out = leaky(dinv[d]*sum(h[s]*dinv[s]) + h[d]*dinv[d]^2 + b) -> bf16
__global__ __launch_bounds__(128)
void gcn_gather_b(const int* __restrict__ rowptr, const int* __restrict__ srcs,
                  const float* __restrict__ h, const float* __restrict__ dinv,
                  const float* __restrict__ b, ushort_t* __restrict__ out) {
    const int node = blockIdx.x, tid = threadIdx.x;
    const int beg = rowptr[node], end = rowptr[node + 1];
    __shared__ int snb[128];
    __shared__ float sdi[128];
    float ax = 0.f, ay = 0.f, az = 0.f, aw = 0.f;
    for (int c = beg; c < end; c += 128) {
        const int m = min(128, end - c);
        __syncthreads();
        if (tid < m) { int s = srcs[c + tid]; snb[tid] = s; sdi[tid] = dinv[s]; }
        __syncthreads();
        for (int i = 0; i < m; ++i) {
            const float4 v = ((const float4*)(h + (size_t)snb[i] * 512))[tid];
            const float w = sdi[i];
            ax += v.x * w; ay += v.y * w; az += v.z * w; aw += v.w * w;
        }
    }
    const float dd = dinv[node];
    const float4 hv = ((const float4*)(h + (size_t)node * 512))[tid];
    const float4 bv = ((const float4*)b)[tid];
    float4 o;
    o.x = ax * dd + hv.x * dd * dd + bv.x;
    o.y = ay * dd + hv.y * dd * dd + bv.y;
    o.z = az * dd + hv.z * dd * dd + bv.z;
    o.w = aw * dd + hv.w * dd * dd + bv.w;
    o.x = o.x > 0.f ? o.x : 0.01f * o.x;
    o.y = o.y > 0.f ? o.y : 0.01f * o.y;
    o.z = o.z > 0.f ? o.z : 0.01f * o.z;
    o.w = o.w > 0.f ? o.w : 0.01f * o.w;
    ((uint2*)(out + (size_t)node * 512))[tid] = make_uint2(pk2(o.x, o.y), pk2(o.z, o.w));
}

// rows: out[d,:] = skip + softmax-weighted sum over CSR edges of V rows (QKVS packed)
__global__ __launch_bounds__(128)
void tconv_softmax_gather(const int* __restrict__ rowptr, const int* __restrict__ srcs,
                          const int* __restrict__ eids, const float* __restrict__ alpha,
                          const float* __restrict__ qkvs, float* __restrict__ out) {
    const int node = blockIdx.x, tid = threadIdx.x;
    const int beg = rowptr[node], end = rowptr[node + 1];
    __shared__ int snb[128];
    __shared__ float sa[128];
    float mx = -INFINITY;
    for (int c = beg; c < end; c += 128) {
        const int m = min(128, end - c);
        __syncthreads();
        if (tid < m) sa[tid] = alpha[eids[c + tid]];
        __syncthreads();
        for (int i = 0; i < m; ++i) mx = fmaxf(mx, sa[i]);
    }
    float acc = 0.f, z = 0.f;
    for (int c = beg; c < end; c += 128) {
        const int m = min(128, end - c);
        __syncthreads();
        if (tid < m) { snb[tid] = srcs[c + tid]; sa[tid] = __expf(alpha[eids[c + tid]] - mx); }
        __syncthreads();
        for (int i = 0; i < m; ++i) {
            z += sa[i];
            acc += sa[i] * qkvs[(size_t)snb[i] * 512 + 256 + tid];
        }
    }
    const float r = acc * (z > 0.f ? 1.f / z : 0.f) + qkvs[(size_t)node * 512 + 384 + tid];
    out[(size_t)node * 128 + tid] = r;
}

// cols: out[d,:] = skip + sum sigmoid((alpha-mu)*scale/sd) * V rows; optional bf16 copy
template<bool WB16>
__global__ __launch_bounds__(128)
void tconv_sigmoid_gather(const int* __restrict__ rowptr, const int* __restrict__ srcs,
                          const int* __restrict__ eids, const float* __restrict__ alpha,
                          const float* __restrict__ qkvs, const double* __restrict__ stats,
                          float scale_param, int E, float* __restrict__ out,
                          ushort_t* __restrict__ ob) {
    const int node = blockIdx.x, tid = threadIdx.x;
    const int beg = rowptr[node], end = rowptr[node + 1];
    const double sum = stats[0], sumsq = stats[1];
    const double mu = sum / (double)E;
    const double var = (sumsq - sum * sum / (double)E) / (double)(E - 1);
    const float sd = (float)sqrt(fmax(var, 0.0));
    const float kk = scale_param / sd;
    const float fmu = (float)mu;
    __shared__ int snb[128];
    __shared__ float sa[128];
    float acc = 0.f;
    for (int c = beg; c < end; c += 128) {
        const int m = min(128, end - c);
        __syncthreads();
        if (tid < m) {
            snb[tid] = srcs[c + tid];
            const float t = (alpha[eids[c + tid]] - fmu) * kk;
            sa[tid] = 1.f / (1.f + __expf(-t));
        }
        __syncthreads();
        for (int i = 0; i < m; ++i)
            acc += sa[i] * qkvs[(size_t)snb[i] * 512 + 256 + tid];
    }
    const float r = acc + qkvs[(size_t)node * 512 + 384 + tid];
    out[(size_t)node * 128 + tid] = r;
    if (WB16) ob[(size_t)node * 128 + tid] = f2b(r);
}

// ---------------- attention edge kernel (packed QKVS stride 512) ----------------
__global__ __launch_bounds__(256)
void edge_dot_s(const int* __restrict__ src, const int* __restrict__ dst,
                const float* __restrict__ qkvs, float* __restrict__ alpha, int E) {
    int wid = (blockIdx.x * blockDim.x + threadIdx.x) >> 6;
    int lane = threadIdx.x & 63;
    if (wid >= E) return;
    const size_t qb = (size_t)dst[wid] * 512;
    const size_t kb = (size_t)src[wid] * 512 + 128;
    float v = qkvs[qb + lane] * qkvs[kb + lane]
            + qkvs[qb + 64 + lane] * qkvs[kb + 64 + lane];
    #pragma unroll
    for (int off = 32; off; off >>= 1) v += __shfl_down(v, off);
    if (lane == 0) alpha[wid] = v * 0.08838834764831845f;  // 1/sqrt(128)
}

__global__ __launch_bounds__(256)
void reduce_stats(const float* __restrict__ a, int E, double* __restrict__ stats) {
    double s = 0.0, s2 = 0.0;
    for (int i = blockIdx.x * blockDim.x + threadIdx.x; i < E; i += gridDim.x * blockDim.x) {
        double x = a[i];
        s += x; s2 += x * x;
    }
    #pragma unroll
    for (int off = 32; off; off >>= 1) {
        s += __shfl_down(s, off);
        s2 += __shfl_down(s2, off);
    }
    __shared__ double sh[4][2];
    int w = threadIdx.x >> 6;
    if ((threadIdx.x & 63) == 0) { sh[w][0] = s; sh[w][1] = s2; }
    __syncthreads();
    if (threadIdx.x == 0) {
        double t = sh[0][0] + sh[1][0] + sh[2][0] + sh[3][0];
        double t2 = sh[0][1] + sh[1][1] + sh[2][1] + sh[3][1];
        atomicAdd(&stats[0], t);
        atomicAdd(&stats[1], t2);
    }
}

// ---------------- workspace layout (float units) ----------------
static constexpr size_t NBIG = (size_t)NG * NC;               // 8388608
static constexpr size_t NBH = NBIG / 2;
static constexpr size_t OFF_B1 = 0;
static constexpr size_t OFF_B2 = NBH;
static constexpr size_t OFF_B3 = 2 * NBH;
static constexpr size_t OFF_WBF = 3 * NBH;
static constexpr size_t OFF_H1   = OFF_WBF + 2097152;                    // f32 4096*512
static constexpr size_t OFF_H2B  = OFF_H1 + (size_t)4096 * 512;          // bf16 4096*512
static constexpr size_t OFF_H3B  = OFF_H2B + (size_t)4096 * 512 / 2;
static constexpr size_t OFF_QKVS = OFF_H3B + (size_t)4096 * 512 / 2;     // f32 4096*512
static constexpr size_t OFF_CBF  = OFF_QKVS + (size_t)4096 * 512;        // bf16 4096*128
static constexpr size_t OFF_B4 = OFF_WBF + 2 * NBIG;                     // after WBF region
static constexpr size_t OFF_ALPHA = OFF_B4 + 512;
static constexpr size_t OFF_CNTK = OFF_ALPHA + 65536;
static constexpr size_t OFF_CNTP = OFF_CNTK + 4096;
static constexpr size_t OFF_DINVK = OFF_CNTP + 4096;
static constexpr size_t OFF_DINVP = OFF_DINVK + 4096;
static constexpr size_t OFF_STATS = OFF_DINVP + 4096;         // double[2]
static constexpr size_t OFF_RPK = OFF_STATS + 16;
static constexpr size_t OFF_RPP = OFF_RPK + 4112;
static constexpr size_t OFF_SRCK = OFF_RPP + 2064;
static constexpr size_t OFF_EIDK = OFF_SRCK + EKNN;
static constexpr size_t OFF_SRCP = OFF_EIDK + EKNN;
static constexpr size_t OFF_EIDP = OFF_SRCP + EPPI;
static constexpr size_t OFF_CUR = OFF_EIDP + EPPI;

extern "C" void kernel_launch(void* const* d_in, const int* in_sizes, int n_in,
                              void* d_out, int out_size, void* d_ws, size_t ws_size,
                              hipStream_t stream) {
    const float* x      = (const float*)d_in[0];
    const int*   knn    = (const int*)d_in[1];
    const int*   ppi    = (const int*)d_in[2];
    const float* c0_wl = (const float*)d_in[3],  *c0_wr = (const float*)d_in[4],  *c0_b = (const float*)d_in[5];
    const float* r0_wl = (const float*)d_in[6],  *r0_wr = (const float*)d_in[7],  *r0_b = (const float*)d_in[8];
    const float* c1_wl = (const float*)d_in[9],  *c1_wr = (const float*)d_in[10], *c1_b = (const float*)d_in[11];
    const float* r1_wl = (const float*)d_in[12], *r1_wr = (const float*)d_in[13], *r1_b = (const float*)d_in[14];
    const float* gr_w  = (const float*)d_in[15], *gr_b  = (const float*)d_in[16];
    const float* tr_wq = (const float*)d_in[17], *tr_bq = (const float*)d_in[18];
    const float* tr_wk = (const float*)d_in[19], *tr_bk = (const float*)d_in[20];
    const float* tr_wv = (const float*)d_in[21], *tr_bv = (const float*)d_in[22];
    const float* tr_ws = (const float*)d_in[23], *tr_bs = (const float*)d_in[24];
    const float* gc_w  = (const float*)d_in[25], *gc_b  = (const float*)d_in[26];
    const float* tc_wq = (const float*)d_in[27], *tc_bq = (const float*)d_in[28];
    const float* tc_wk = (const float*)d_in[29], *tc_bk = (const float*)d_in[30];
    const float* tc_wv = (const float*)d_in[31], *tc_bv = (const float*)d_in[32];
    const float* tc_ws = (const float*)d_in[33], *tc_bs = (const float*)d_in[34];
    const float* d1_w  = (const float*)d_in[35], *d1_b  = (const float*)d_in[36];
    const float* d2_w  = (const float*)d_in[37], *d2_b  = (const float*)d_in[38];
    const float* d3_w  = (const float*)d_in[39], *d3_b  = (const float*)d_in[40];

    const int* knn_src = knn, *knn_dst = knn + EKNN;
    const int* ppi_src = ppi, *ppi_dst = ppi + EPPI;

    float* ws = (float*)d_ws;
    ushort_t* B1 = (ushort_t*)(ws + OFF_B1);
    ushort_t* B2 = (ushort_t*)(ws + OFF_B2);
    ushort_t* B3 = (ushort_t*)(ws + OFF_B3);
    ushort_t* WBF0 = (ushort_t*)(ws + OFF_WBF);
    ushort_t* WBF1 = WBF0 + 2 * NBIG;
    float* H1 = ws + OFF_H1;
    ushort_t* H2b = (ushort_t*)(ws + OFF_H2B);
    ushort_t* H3b = (ushort_t*)(ws + OFF_H3B);
    float* QKVS = ws + OFF_QKVS;
    ushort_t* CBF = (ushort_t*)(ws + OFF_CBF);
    float* B4 = ws + OFF_B4;
    float* ALPHA = ws + OFF_ALPHA;
    float* CNTK = ws + OFF_CNTK;
    float* CNTP = ws + OFF_CNTP;
    float* DINVK = ws + OFF_DINVK;
    float* DINVP = ws + OFF_DINVP;
    double* STATS = (double*)(ws + OFF_STATS);
    int* RPK  = (int*)(ws + OFF_RPK);
    int* RPP  = (int*)(ws + OFF_RPP);
    int* SRCK = (int*)(ws + OFF_SRCK);
    int* EIDK = (int*)(ws + OFF_EIDK);
    int* SRCP = (int*)(ws + OFF_SRCP);
    int* EIDP = (int*)(ws + OFF_EIDP);
    int* CUR  = (int*)(ws + OFF_CUR);

    float* out_rows = (float*)d_out;                       // [2048,128]
    float* out_cols = out_rows + (size_t)NG * 128;         // [4096,128]
    float* out_feat = out_cols + (size_t)NC * 128;         // [4096,2048]

    auto tW = [&](const float* Wsrc, int K, int N, ushort_t* dst) {
        transpose_f2b<<<dim3(N >> 6, K >> 6), 256, 0, stream>>>(Wsrc, dst, K, N);
    };
    auto gemm = [&](const ushort_t* Abf, const ushort_t* Wt, const float* bias,
                    float* Cf, ushort_t* Cb, int M, int N, int K, int mode) {
        dim3 g(N >> 7, M >> 7), blk(256);
        switch (mode) {
            case 0: gemm_bf16<0, false, false><<<g, blk, 0, stream>>>(Abf, Wt, nullptr, Cf, nullptr, M, N, K); break;
            case 2: gemm_bf16<0, true,  false><<<g, blk, 0, stream>>>(Abf, Wt, bias, Cf, nullptr, M, N, K); break;
            case 3: gemm_bf16<2, true,  true ><<<g, blk, 0, stream>>>(Abf, Wt, bias, nullptr, Cb, M, N, K); break;
        }
    };

    // ---- degrees + CSR ----
    hipMemsetAsync(CNTK, 0, NC * 4, stream);
    hipMemsetAsync(CNTP, 0, NG * 4, stream);
    count_dst<<<cdiv(EKNN, 256), 256, 0, stream>>>(knn_dst, CNTK, EKNN);
    count_dst<<<cdiv(EPPI, 256), 256, 0, stream>>>(ppi_dst, CNTP, EPPI);
    make_dinv<<<cdiv(NC, 256), 256, 0, stream>>>(CNTK, DINVK, NC);
    make_dinv<<<cdiv(NG, 256), 256, 0, stream>>>(CNTP, DINVP, NG);
    scan_rowptr<<<1, 256, 0, stream>>>(CNTK, RPK, NC);
    scan_rowptr<<<1, 256, 0, stream>>>(CNTP, RPP, NG);
    hipMemsetAsync(CUR, 0, NC * 4, stream);
    fill_csr<<<cdiv(EKNN, 256), 256, 0, stream>>>(knn_src, knn_dst, RPK, CUR, SRCK, EIDK, EKNN);
    hipMemsetAsync(CUR, 0, NG * 4, stream);
    fill_csr<<<cdiv(EPPI, 256), 256, 0, stream>>>(ppi_src, ppi_dst, RPP, CUR, SRCP, EIDP, EPPI);

    // ================= SAGE blocks (all bf16, swapped outputs — zero transposes) =================
    transpose_f2b<<<dim3(NC >> 6, NG >> 6), 256, 0, stream>>>(x, B1, NG, NC);   // B1 [NC][NG]
    const float* cwl[2] = {c0_wl, c1_wl}; const float* cwr[2] = {c0_wr, c1_wr}; const float* cbb[2] = {c0_b, c1_b};
    const float* rwl[2] = {r0_wl, r1_wl}; const float* rwr[2] = {r0_wr, r1_wr}; const float* rbb[2] = {r0_b, r1_b};
    for (int l = 0; l < 2; ++l) {
        // cells graph: input B1 [NC][NG]; swapped output B3 [NG][NC]
        sage_gather_b<1><<<NC, 256, 0, stream>>>(RPK, SRCK, B1, B2);
        tW(cwl[l], NG, NG, WBF0);
        tW(cwr[l], NG, NG, WBF1);
        gemm_sage<<<dim3(NC >> 7, NG >> 7), 256, 0, stream>>>(WBF0, B2, WBF1, B1, cbb[l], B3, NG, NC, NG);
        // genes graph: input B3 [NG][NC]; swapped output B1 [NC][NG]
        sage_gather_b<2><<<NG, 256, 0, stream>>>(RPP, SRCP, B3, B2);
        tW(rwl[l], NC, NC, WBF0);
        tW(rwr[l], NC, NC, WBF1);
        gemm_sage<<<dim3(NG >> 7, NC >> 7), 256, 0, stream>>>(WBF0, B2, WBF1, B3, rbb[l], B1, NC, NG, NC);
    }
    // emb4: B1 = [NC][NG] (cols encoder); one transpose for rows encoder -> B3 [NG][NC]
    transpose_b2b<<<dim3(NG >> 6, NC >> 6), 256, 0, stream>>>(B1, B3, NC, NG);

    // ================= rows encoder (PPI, n=2048) =================
    tW(gr_w, NC, 512, WBF0);
    gemm(B3, WBF0, nullptr, H1, nullptr, NG, 512, NC, 0);
    gcn_gather_b<<<NG, 128, 0, stream>>>(RPP, SRCP, H1, DINVP, gr_b, H2b);
    transpose_qkvs<<<dim3(2, 8, 4), 256, 0, stream>>>(tr_wq, tr_wk, tr_wv, tr_ws, WBF0);
    concat4<<<2, 256, 0, stream>>>(tr_bq, tr_bk, tr_bv, tr_bs, B4);
    gemm(H2b, WBF0, B4, QKVS, nullptr, NG, 512, 512, 2);
    edge_dot_s<<<cdiv(EPPI * 64, 256), 256, 0, stream>>>(ppi_src, ppi_dst, QKVS, ALPHA, EPPI);
    tconv_softmax_gather<<<NG, 128, 0, stream>>>(RPP, SRCP, EIDP, ALPHA, QKVS, out_rows);

    // ================= cols encoder (KNN, n=4096) =================
    tW(gc_w, NG, 512, WBF0);
    gemm(B1, WBF0, nullptr, H1, nullptr, NC, 512, NG, 0);
    gcn_gather_b<<<NC, 128, 0, stream>>>(RPK, SRCK, H1, DINVK, gc_b, H3b);
    transpose_qkvs<<<dim3(2, 8, 4), 256, 0, stream>>>(tc_wq, tc_wk, tc_wv, tc_ws, WBF0);
    concat4<<<2, 256, 0, stream>>>(tc_bq, tc_bk, tc_bv, tc_bs, B4);
    gemm(H3b, WBF0, B4, QKVS, nullptr, NC, 512, 512, 2);
    edge_dot_s<<<cdiv(EKNN * 64, 256), 256, 0, stream>>>(knn_src, knn_dst, QKVS, ALPHA, EKNN);
    hipMemsetAsync(STATS, 0, 16, stream);
    reduce_stats<<<256, 256, 0, stream>>>(ALPHA, EKNN, STATS);
    tconv_sigmoid_gather<true><<<NC, 128, 0, stream>>>(RPK, SRCK, EIDK, ALPHA, QKVS, STATS, 3.0f, EKNN, out_cols, CBF);

    // ================= decoder =================
    tW(d1_w, 128, 512, WBF0);
    gemm(CBF, WBF0, d1_b, nullptr, H2b, NC, 512, 128, 3);
    tW(d2_w, 512, 512, WBF0);
    gemm(H2b, WBF0, d2_b, nullptr, H3b, NC, 512, 512, 3);
    tW(d3_w, 512, NG, WBF0);
    gemm(H3b, WBF0, d3_b, out_feat, nullptr, NC, NG, 512, 2);

    (void)in_sizes; (void)n_in; (void)out_size; (void)ws_size;
}

// Round 8
// 974.778 us; speedup vs baseline: 18.6888x; 1.0987x over previous
//
#include <hip/hip_runtime.h>
#include <math.h>

#define NG 2048
#define NC 4096
#define EKNN 61440
#define EPPI 65536

typedef __attribute__((ext_vector_type(8))) short short8v;
typedef __attribute__((ext_vector_type(4))) float f32x4;
typedef unsigned short ushort_t;

static inline int cdiv(int a, int b) { return (a + b - 1) / b; }

__device__ __forceinline__ unsigned short f2b(float f) {
    union { float f; unsigned int i; } v; v.f = f;
    unsigned int r = v.i + 0x7FFFu + ((v.i >> 16) & 1u);
    return (unsigned short)(r >> 16);
}
__device__ __forceinline__ float bl(unsigned int u) { union { unsigned int i; float f; } v; v.i = u << 16; return v.f; }
__device__ __forceinline__ float bh(unsigned int u) { union { unsigned int i; float f; } v; v.i = u & 0xFFFF0000u; return v.f; }
__device__ __forceinline__ unsigned int pk2(float a, float b) { return (unsigned int)f2b(a) | ((unsigned int)f2b(b) << 16); }

__device__ __forceinline__ int xcd_swz_id() {
    const int nwg = gridDim.x * gridDim.y;
    const int orig = blockIdx.y * gridDim.x + blockIdx.x;
    const int q = nwg >> 3, r = nwg & 7;
    const int xcd = orig & 7, off = orig >> 3;
    return (xcd < r ? xcd * (q + 1) : r * (q + 1) + (xcd - r) * q) + off;
}

#define GLOAD_LDS16(gp, lp) __builtin_amdgcn_global_load_lds( \
    (const __attribute__((address_space(1))) void*)(gp),      \
    (__attribute__((address_space(3))) void*)(lp), 16, 0, 0)

// ================= bf16 MFMA GEMM (single, XCD-swizzled) =================
template<int ACT, bool BIAS, bool OBF>
__global__ __launch_bounds__(256)
void gemm_bf16(const ushort_t* __restrict__ A,
               const ushort_t* __restrict__ Bt,
               const float* __restrict__ bias,
               float* __restrict__ Cf, ushort_t* __restrict__ Cb,
               int M, int N, int K) {
    __shared__ ushort_t lds[2][2][128 * 32];
    const int tid = threadIdx.x;
    const int lane = tid & 63, wv = tid >> 6;
    const int wm = wv >> 1, wn = wv & 1;
    const int swzid = xcd_swz_id();
    const int bm = (swzid / gridDim.x) << 7, bn = (swzid % gridDim.x) << 7;

    const ushort_t* gA = A + (size_t)bm * K;
    const ushort_t* gB = Bt + (size_t)bn * K;
    const int rsub = lane >> 2;
    const int qsw  = (lane & 3) ^ ((lane >> 3) & 3);
    const int KT = K >> 5;

    f32x4 acc[4][4];
    #pragma unroll
    for (int i = 0; i < 4; ++i)
        #pragma unroll
        for (int j = 0; j < 4; ++j) acc[i][j] = (f32x4){0.f, 0.f, 0.f, 0.f};

    auto stage = [&](int buf, int k0) {
        #pragma unroll
        for (int t = 0; t < 2; ++t) {
            const int br = (wv * 2 + t) * 16;
            GLOAD_LDS16(gA + (size_t)(br + rsub) * K + k0 + qsw * 8, &lds[buf][0][br * 32]);
            GLOAD_LDS16(gB + (size_t)(br + rsub) * K + k0 + qsw * 8, &lds[buf][1][br * 32]);
        }
    };
    const int rl = lane & 15, kg = lane >> 4;
    const int swr = (kg ^ ((rl >> 1) & 3)) * 8;

    stage(0, 0);
    int buf = 0;
    for (int kt = 0; kt < KT; ++kt) {
        __syncthreads();
        if (kt + 1 < KT) stage(buf ^ 1, (kt + 1) << 5);
        short8v a[4], b[4];
        #pragma unroll
        for (int mi = 0; mi < 4; ++mi)
            a[mi] = *(const short8v*)&lds[buf][0][(wm * 64 + mi * 16 + rl) * 32 + swr];
        #pragma unroll
        for (int ni = 0; ni < 4; ++ni)
            b[ni] = *(const short8v*)&lds[buf][1][(wn * 64 + ni * 16 + rl) * 32 + swr];
        #pragma unroll
        for (int mi = 0; mi < 4; ++mi)
            #pragma unroll
            for (int ni = 0; ni < 4; ++ni)
                acc[mi][ni] = __builtin_amdgcn_mfma_f32_16x16x32_bf16(a[mi], b[ni], acc[mi][ni], 0, 0, 0);
        buf ^= 1;
    }
    const int colL = lane & 15, rq = lane >> 4;
    #pragma unroll
    for (int mi = 0; mi < 4; ++mi) {
        const int row0 = bm + wm * 64 + mi * 16 + rq * 4;
        #pragma unroll
        for (int ni = 0; ni < 4; ++ni) {
            const int col = bn + wn * 64 + ni * 16 + colL;
            float bv = 0.f;
            if (BIAS) bv = bias[col];
            #pragma unroll
            for (int r = 0; r < 4; ++r) {
                const size_t off = (size_t)(row0 + r) * N + col;
                float v = acc[mi][ni][r];
                if (BIAS) v += bv;
                if (ACT == 2) v = fmaxf(v, 0.f);
                if (OBF) Cb[off] = f2b(v); else Cf[off] = v;
            }
        }
    }
}

// ================= batched dual GEMM (two problems, one dispatch) =================
template<bool BIAS, bool OBF>
__global__ __launch_bounds__(256)
void gemm2_bf16(const ushort_t* __restrict__ A0, const ushort_t* __restrict__ Bt0,
                const float* __restrict__ bias0, float* __restrict__ Cf0, ushort_t* __restrict__ Cb0,
                int N0, int K0, int nx0, int nb0,
                const ushort_t* __restrict__ A1, const ushort_t* __restrict__ Bt1,
                const float* __restrict__ bias1, float* __restrict__ Cf1, ushort_t* __restrict__ Cb1,
                int N1, int K1, int nx1) {
    __shared__ ushort_t lds[2][2][128 * 32];
    const int bid = blockIdx.x;
    const bool p1 = bid >= nb0;
    const int lbid = p1 ? bid - nb0 : bid;
    const ushort_t* A = p1 ? A1 : A0;
    const ushort_t* Bt = p1 ? Bt1 : Bt0;
    const float* bias = p1 ? bias1 : bias0;
    float* Cf = p1 ? Cf1 : Cf0;
    ushort_t* Cb = p1 ? Cb1 : Cb0;
    const int N = p1 ? N1 : N0;
    const int K = p1 ? K1 : K0;
    const int nx = p1 ? nx1 : nx0;
    const int bn = (lbid % nx) << 7, bm = (lbid / nx) << 7;

    const int tid = threadIdx.x;
    const int lane = tid & 63, wv = tid >> 6;
    const int wm = wv >> 1, wn = wv & 1;
    const ushort_t* gA = A + (size_t)bm * K;
    const ushort_t* gB = Bt + (size_t)bn * K;
    const int rsub = lane >> 2;
    const int qsw  = (lane & 3) ^ ((lane >> 3) & 3);
    const int KT = K >> 5;

    f32x4 acc[4][4];
    #pragma unroll
    for (int i = 0; i < 4; ++i)
        #pragma unroll
        for (int j = 0; j < 4; ++j) acc[i][j] = (f32x4){0.f, 0.f, 0.f, 0.f};

    auto stage = [&](int buf, int k0) {
        #pragma unroll
        for (int t = 0; t < 2; ++t) {
            const int br = (wv * 2 + t) * 16;
            GLOAD_LDS16(gA + (size_t)(br + rsub) * K + k0 + qsw * 8, &lds[buf][0][br * 32]);
            GLOAD_LDS16(gB + (size_t)(br + rsub) * K + k0 + qsw * 8, &lds[buf][1][br * 32]);
        }
    };
    const int rl = lane & 15, kg = lane >> 4;
    const int swr = (kg ^ ((rl >> 1) & 3)) * 8;

    stage(0, 0);
    int buf = 0;
    for (int kt = 0; kt < KT; ++kt) {
        __syncthreads();
        if (kt + 1 < KT) stage(buf ^ 1, (kt + 1) << 5);
        short8v a[4], b[4];
        #pragma unroll
        for (int mi = 0; mi < 4; ++mi)
            a[mi] = *(const short8v*)&lds[buf][0][(wm * 64 + mi * 16 + rl) * 32 + swr];
        #pragma unroll
        for (int ni = 0; ni < 4; ++ni)
            b[ni] = *(const short8v*)&lds[buf][1][(wn * 64 + ni * 16 + rl) * 32 + swr];
        #pragma unroll
        for (int mi = 0; mi < 4; ++mi)
            #pragma unroll
            for (int ni = 0; ni < 4; ++ni)
                acc[mi][ni] = __builtin_amdgcn_mfma_f32_16x16x32_bf16(a[mi], b[ni], acc[mi][ni], 0, 0, 0);
        buf ^= 1;
    }
    const int colL = lane & 15, rq = lane >> 4;
    #pragma unroll
    for (int mi = 0; mi < 4; ++mi) {
        const int row0 = bm + wm * 64 + mi * 16 + rq * 4;
        #pragma unroll
        for (int ni = 0; ni < 4; ++ni) {
            const int col = bn + wn * 64 + ni * 16 + colL;
            float bv = 0.f;
            if (BIAS) bv = bias[col];
            #pragma unroll
            for (int r = 0; r < 4; ++r) {
                const size_t off = (size_t)(row0 + r) * N + col;
                float v = acc[mi][ni][r];
                if (BIAS) v += bv;
                if (OBF) Cb[off] = f2b(v); else Cf[off] = v;
            }
        }
    }
}

// ================= fused SAGE GEMM (swapped orientation, ROW bias) =================
__global__ __launch_bounds__(256)
void gemm_sage(const ushort_t* __restrict__ A0, const ushort_t* __restrict__ B0t,
               const ushort_t* __restrict__ A1, const ushort_t* __restrict__ B1t,
               const float* __restrict__ bias, ushort_t* __restrict__ Cb,
               int M, int N, int K) {
    __shared__ ushort_t lds[2][2][128 * 32];
    const int tid = threadIdx.x;
    const int lane = tid & 63, wv = tid >> 6;
    const int wm = wv >> 1, wn = wv & 1;
    const int swzid = xcd_swz_id();
    const int bm = (swzid / gridDim.x) << 7, bn = (swzid % gridDim.x) << 7;

    const ushort_t* gA0 = A0 + (size_t)bm * K;
    const ushort_t* gB0 = B0t + (size_t)bn * K;
    const ushort_t* gA1 = A1 + (size_t)bm * K;
    const ushort_t* gB1 = B1t + (size_t)bn * K;
    const int rsub = lane >> 2;
    const int qsw  = (lane & 3) ^ ((lane >> 3) & 3);
    const int KT = K >> 5;

    f32x4 acc[4][4];
    #pragma unroll
    for (int i = 0; i < 4; ++i)
        #pragma unroll
        for (int j = 0; j < 4; ++j) acc[i][j] = (f32x4){0.f, 0.f, 0.f, 0.f};

    auto stage = [&](int buf, int kt) {
        const int half = kt >= KT;
        const int k0 = (half ? (kt - KT) : kt) << 5;
        const ushort_t* sA = half ? gA1 : gA0;
        const ushort_t* sB = half ? gB1 : gB0;
        #pragma unroll
        for (int t = 0; t < 2; ++t) {
            const int br = (wv * 2 + t) * 16;
            GLOAD_LDS16(sA + (size_t)(br + rsub) * K + k0 + qsw * 8, &lds[buf][0][br * 32]);
            GLOAD_LDS16(sB + (size_t)(br + rsub) * K + k0 + qsw * 8, &lds[buf][1][br * 32]);
        }
    };
    const int rl = lane & 15, kg = lane >> 4;
    const int swr = (kg ^ ((rl >> 1) & 3)) * 8;

    stage(0, 0);
    int buf = 0;
    const int KT2 = KT * 2;
    for (int kt = 0; kt < KT2; ++kt) {
        __syncthreads();
        if (kt + 1 < KT2) stage(buf ^ 1, kt + 1);
        short8v a[4], b[4];
        #pragma unroll
        for (int mi = 0; mi < 4; ++mi)
            a[mi] = *(const short8v*)&lds[buf][0][(wm * 64 + mi * 16 + rl) * 32 + swr];
        #pragma unroll
        for (int ni = 0; ni < 4; ++ni)
            b[ni] = *(const short8v*)&lds[buf][1][(wn * 64 + ni * 16 + rl) * 32 + swr];
        #pragma unroll
        for (int mi = 0; mi < 4; ++mi)
            #pragma unroll
            for (int ni = 0; ni < 4; ++ni)
                acc[mi][ni] = __builtin_amdgcn_mfma_f32_16x16x32_bf16(a[mi], b[ni], acc[mi][ni], 0, 0, 0);
        buf ^= 1;
    }
    const int colL = lane & 15, rq = lane >> 4;
    #pragma unroll
    for (int mi = 0; mi < 4; ++mi) {
        const int row0 = bm + wm * 64 + mi * 16 + rq * 4;
        float bz[4];
        #pragma unroll
        for (int r = 0; r < 4; ++r) bz[r] = bias[row0 + r];
        #pragma unroll
        for (int ni = 0; ni < 4; ++ni) {
            const int col = bn + wn * 64 + ni * 16 + colL;
            #pragma unroll
            for (int r = 0; r < 4; ++r) {
                float v = acc[mi][ni][r] + bz[r];
                v = v > 0.f ? v : 0.01f * v;
                Cb[(size_t)(row0 + r) * N + col] = f2b(v);
            }
        }
    }
}

// ---------------- transposes (64x64 tiles, vectorized) ----------------
__global__ __launch_bounds__(256)
void transpose_f2b(const float* __restrict__ in, ushort_t* __restrict__ out, int R, int C) {
    __shared__ ushort_t t[64][65];
    const int bx = blockIdx.x << 6, by = blockIdx.y << 6;
    const int tr = threadIdx.x >> 4;
    const int tc = (threadIdx.x & 15) << 2;
    #pragma unroll
    for (int i = 0; i < 4; ++i) {
        const int rr = tr + i * 16;
        const float4 v = *(const float4*)(in + (size_t)(by + rr) * C + bx + tc);
        t[rr][tc + 0] = f2b(v.x); t[rr][tc + 1] = f2b(v.y);
        t[rr][tc + 2] = f2b(v.z); t[rr][tc + 3] = f2b(v.w);
    }
    __syncthreads();
    #pragma unroll
    for (int i = 0; i < 4; ++i) {
        const int cc = tr + i * 16;
        ushort4 o;
        o.x = t[tc + 0][cc]; o.y = t[tc + 1][cc];
        o.z = t[tc + 2][cc]; o.w = t[tc + 3][cc];
        *(ushort4*)(out + (size_t)(bx + cc) * R + by + tc) = o;
    }
}

// two same-shape f32->bf16 transposes in one dispatch (z selects)
__global__ __launch_bounds__(256)
void transpose_f2b2(const float* __restrict__ in0, ushort_t* __restrict__ out0,
                    const float* __restrict__ in1, ushort_t* __restrict__ out1, int R, int C) {
    const float* in = blockIdx.z ? in1 : in0;
    ushort_t* out = blockIdx.z ? out1 : out0;
    __shared__ ushort_t t[64][65];
    const int bx = blockIdx.x << 6, by = blockIdx.y << 6;
    const int tr = threadIdx.x >> 4;
    const int tc = (threadIdx.x & 15) << 2;
    #pragma unroll
    for (int i = 0; i < 4; ++i) {
        const int rr = tr + i * 16;
        const float4 v = *(const float4*)(in + (size_t)(by + rr) * C + bx + tc);
        t[rr][tc + 0] = f2b(v.x); t[rr][tc + 1] = f2b(v.y);
        t[rr][tc + 2] = f2b(v.z); t[rr][tc + 3] = f2b(v.w);
    }
    __syncthreads();
    #pragma unroll
    for (int i = 0; i < 4; ++i) {
        const int cc = tr + i * 16;
        ushort4 o;
        o.x = t[tc + 0][cc]; o.y = t[tc + 1][cc];
        o.z = t[tc + 2][cc]; o.w = t[tc + 3][cc];
        *(ushort4*)(out + (size_t)(bx + cc) * R + by + tc) = o;
    }
}

__global__ __launch_bounds__(256)
void transpose_b2b(const ushort_t* __restrict__ in, ushort_t* __restrict__ out, int R, int C) {
    __shared__ ushort_t t[64][65];
    const int bx = blockIdx.x << 6, by = blockIdx.y << 6;
    const int tr = threadIdx.x >> 4;
    const int tc = (threadIdx.x & 15) << 2;
    #pragma unroll
    for (int i = 0; i < 4; ++i) {
        const int rr = tr + i * 16;
        const ushort4 v = *(const ushort4*)(in + (size_t)(by + rr) * C + bx + tc);
        t[rr][tc + 0] = v.x; t[rr][tc + 1] = v.y;
        t[rr][tc + 2] = v.z; t[rr][tc + 3] = v.w;
    }
    __syncthreads();
    #pragma unroll
    for (int i = 0; i < 4; ++i) {
        const int cc = tr + i * 16;
        ushort4 o;
        o.x = t[tc + 0][cc]; o.y = t[tc + 1][cc];
        o.z = t[tc + 2][cc]; o.w = t[tc + 3][cc];
        *(ushort4*)(out + (size_t)(bx + cc) * R + by + tc) = o;
    }
}

// 8 QKVS weights [512][128] f32 -> two packed [512][512] bf16
__global__ __launch_bounds__(256)
void transpose_qkvs8(const float* __restrict__ w0, const float* __restrict__ w1,
                     const float* __restrict__ w2, const float* __restrict__ w3,
                     const float* __restrict__ w4, const float* __restrict__ w5,
                     const float* __restrict__ w6, const float* __restrict__ w7,
                     ushort_t* __restrict__ outR, ushort_t* __restrict__ outC) {
    const int z = blockIdx.z;
    const float* in;
    switch (z) {
        case 0: in = w0; break; case 1: in = w1; break;
        case 2: in = w2; break; case 3: in = w3; break;
        case 4: in = w4; break; case 5: in = w5; break;
        case 6: in = w6; break; default: in = w7; break;
    }
    ushort_t* o = (z < 4 ? outR + (size_t)z * 128 * 512 : outC + (size_t)(z - 4) * 128 * 512);
    __shared__ ushort_t t[64][65];
    const int bx = blockIdx.x << 6, by = blockIdx.y << 6;
    const int tr = threadIdx.x >> 4;
    const int tc = (threadIdx.x & 15) << 2;
    #pragma unroll
    for (int i = 0; i < 4; ++i) {
        const int rr = tr + i * 16;
        const float4 v = *(const float4*)(in + (size_t)(by + rr) * 128 + bx + tc);
        t[rr][tc + 0] = f2b(v.x); t[rr][tc + 1] = f2b(v.y);
        t[rr][tc + 2] = f2b(v.z); t[rr][tc + 3] = f2b(v.w);
    }
    __syncthreads();
    #pragma unroll
    for (int i = 0; i < 4; ++i) {
        const int cc = tr + i * 16;
        ushort4 ov;
        ov.x = t[tc + 0][cc]; ov.y = t[tc + 1][cc];
        ov.z = t[tc + 2][cc]; ov.w = t[tc + 3][cc];
        *(ushort4*)(o + (size_t)(bx + cc) * 512 + by + tc) = ov;
    }
}

// ---------------- CSR build (both graphs batched) ----------------
__global__ void count_dst2(const int* __restrict__ pdst, float* __restrict__ cntp,
                           const int* __restrict__ kdst, float* __restrict__ cntk) {
    int e = blockIdx.x * blockDim.x + threadIdx.x;
    if (e < EPPI) atomicAdd(&cntp[pdst[e]], 1.0f);
    else if (e < EPPI + EKNN) atomicAdd(&cntk[kdst[e - EPPI]], 1.0f);
}

__global__ void make_dinv2(const float* __restrict__ cntp, float* __restrict__ dinvp,
                           const float* __restrict__ cntk, float* __restrict__ dinvk) {
    int i = blockIdx.x * blockDim.x + threadIdx.x;
    if (i < NG) dinvp[i] = rsqrtf(cntp[i] + 1.0f);
    else if (i < NG + NC) dinvk[i - NG] = rsqrtf(cntk[i - NG] + 1.0f);
}

__global__ __launch_bounds__(256)
void scan_rowptr2(const float* __restrict__ cntp, int* __restrict__ rpp,
                  const float* __restrict__ cntk, int* __restrict__ rpk) {
    const float* cnt = blockIdx.x ? cntk : cntp;
    int* rowptr = blockIdx.x ? rpk : rpp;
    const int n = blockIdx.x ? NC : NG;
    __shared__ int part[257];
    const int tid = threadIdx.x;
    const int per = n >> 8;
    const int base = tid * per;
    int s = 0;
    for (int i = 0; i < per; ++i) s += (int)cnt[base + i];
    part[tid + 1] = s;
    if (tid == 0) part[0] = 0;
    __syncthreads();
    if (tid == 0)
        for (int i = 1; i <= 256; ++i) part[i] += part[i - 1];
    __syncthreads();
    int run = part[tid];
    for (int i = 0; i < per; ++i) {
        rowptr[base + i] = run;
        run += (int)cnt[base + i];
    }
    if (tid == 255) rowptr[n] = run;
}

__global__ void fill_csr2(const int* __restrict__ psrc, const int* __restrict__ pdst,
                          const int* __restrict__ rpp, int* __restrict__ curp,
                          int* __restrict__ srcp, int* __restrict__ eidp,
                          const int* __restrict__ ksrc, const int* __restrict__ kdst,
                          const int* __restrict__ rpk, int* __restrict__ curk,
                          int* __restrict__ srck, int* __restrict__ eidk) {
    int e = blockIdx.x * blockDim.x + threadIdx.x;
    if (e < EPPI) {
        int d = pdst[e];
        int p = atomicAdd(&curp[d], 1);
        srcp[rpp[d] + p] = psrc[e];
        eidp[rpp[d] + p] = e;
    } else if (e < EPPI + EKNN) {
        int e2 = e - EPPI;
        int d = kdst[e2];
        int p = atomicAdd(&curk[d], 1);
        srck[rpk[d] + p] = ksrc[e2];
        eidk[rpk[d] + p] = e2;
    }
}

__global__ void concat8(const float* __restrict__ a, const float* __restrict__ b,
                        const float* __restrict__ c, const float* __restrict__ d,
                        const float* __restrict__ e, const float* __restrict__ f,
                        const float* __restrict__ g, const float* __restrict__ h,
                        float* __restrict__ o) {
    int i = threadIdx.x + blockIdx.x * blockDim.x;
    if (i >= 1024) return;
    const float* s;
    int j = i & 127;
    switch (i >> 7) {
        case 0: s = a; break; case 1: s = b; break; case 2: s = c; break; case 3: s = d; break;
        case 4: s = e; break; case 5: s = f; break; case 6: s = g; break; default: s = h; break;
    }
    o[i] = s[j];
}

// ---------------- CSR gathers ----------------
template<int NS>
__global__ __launch_bounds__(256)
void sage_gather_b(const int* __restrict__ rowptr, const int* __restrict__ srcs,
                   const ushort_t* __restrict__ x, ushort_t* __restrict__ out) {
    const int F = NS * 2048;
    const int node = blockIdx.x, tid = threadIdx.x;
    const int beg = rowptr[node], end = rowptr[node + 1];
    __shared__ int snb[256];
    float acc[NS][8];
    #pragma unroll
    for (int s = 0; s < NS; ++s)
        #pragma unroll
        for (int j = 0; j < 8; ++j) acc[s][j] = 0.f;
    for (int c = beg; c < end; c += 256) {
        const int m = min(256, end - c);
        __syncthreads();
        if (tid < m) snb[tid] = srcs[c + tid];
        __syncthreads();
        #pragma unroll 2
        for (int i = 0; i < m; ++i) {
            const uint4* row = (const uint4*)(x + (size_t)snb[i] * F);
            #pragma unroll
            for (int s = 0; s < NS; ++s) {
                const uint4 v = row[tid + s * 256];
                acc[s][0] += bl(v.x); acc[s][1] += bh(v.x);
                acc[s][2] += bl(v.y); acc[s][3] += bh(v.y);
                acc[s][4] += bl(v.z); acc[s][5] += bh(v.z);
                acc[s][6] += bl(v.w); acc[s][7] += bh(v.w);
            }
        }
    }
    const float inv = 1.f / fmaxf((float)(end - beg), 1.f);
    uint4* orow = (uint4*)(out + (size_t)node * F);
    #pragma unroll
    for (int s = 0; s < NS; ++s) {
        uint4 o;
        o.x = pk2(acc[s][0] * inv, acc[s][1] * inv);
        o.y = pk2(acc[s][2] * inv, acc[s][3] * inv);
        o.z = pk2(acc[s][4] * inv, acc[s][5] * inv);
        o.w = pk2(acc[s][6] * inv, acc[s][7] * inv);
        orow[tid + s * 256] = o;
    }
}

// batched GCN (rows graph then cols graph), bf16 h input, bf16 out
__global__ __launch_bounds__(128)
void gcn_gather2(const int* __restrict__ rpp, const int* __restrict__ srcp,
                 const ushort_t* __restrict__ hr, const float* __restrict__ dinvp,
                 const float* __restrict__ br, ushort_t* __restrict__ outr,
                 const int* __restrict__ rpk, const int* __restrict__ srck,
                 const ushort_t* __restrict__ hc, const float* __restrict__ dinvk,
                 const float* __restrict__ bc, ushort_t* __restrict__ outc) {
    const bool cols = blockIdx.x >= NG;
    const int node = cols ? blockIdx.x - NG : blockIdx.x;
    const int tid = threadIdx.x;
    const int* rowptr = cols ? rpk : rpp;
    const int* srcs = cols ? srck : srcp;
    const ushort_t* h = cols ? hc : hr;
    const float* dinv = cols ? dinvk : dinvp;
    const float* b = cols ? bc : br;
    ushort_t* out = cols ? outc : outr;

    const int beg = rowptr[node], end = rowptr[node + 1];
    __shared__ int snb[128];
    __shared__ float sdi[128];
    float ax = 0.f, ay = 0.f, az = 0.f, aw = 0.f;
    for (int c = beg; c < end; c += 128) {
        const int m = min(128, end - c);
        __syncthreads();
        if (tid < m) { int s = srcs[c + tid]; snb[tid] = s; sdi[tid] = dinv[s]; }
        __syncthreads();
        for (int i = 0; i < m; ++i) {
            const uint2 v = ((const uint2*)(h + (size_t)snb[i] * 512))[tid];
            const float w = sdi[i];
            ax += bl(v.x) * w; ay += bh(v.x) * w;
            az += bl(v.y) * w; aw += bh(v.y) * w;
        }
    }
    const float dd = dinv[node];
    const uint2 hv = ((const uint2*)(h + (size_t)node * 512))[tid];
    const float4 bv = ((const float4*)b)[tid];
    float4 o;
    o.x = ax * dd + bl(hv.x) * dd * dd + bv.x;
    o.y = ay * dd + bh(hv.x) * dd * dd + bv.y;
    o.z = az * dd + bl(hv.y) * dd * dd + bv.z;
    o.w = aw * dd + bh(hv.y) * dd * dd + bv.w;
    o.x = o.x > 0.f ? o.x : 0.01f * o.x;
    o.y = o.y > 0.f ? o.y : 0.01f * o.y;
    o.z = o.z > 0.f ? o.z : 0.01f * o.z;
    o.w = o.w > 0.f ? o.w : 0.01f * o.w;
    ((uint2*)(out + (size_t)node * 512))[tid] = make_uint2(pk2(o.x, o.y), pk2(o.z, o.w));
}

// batched edge dot (PPI on QKVSr, KNN on QKVSc)
__global__ __launch_bounds__(256)
void edge_dot2(const int* __restrict__ psrc, const int* __restrict__ pdst,
               const float* __restrict__ qr, float* __restrict__ alphap,
               const int* __restrict__ ksrc, const int* __restrict__ kdst,
               const float* __restrict__ qc, float* __restrict__ alphak) {
    int wid = (blockIdx.x * blockDim.x + threadIdx.x) >> 6;
    int lane = threadIdx.x & 63;
    const float* q;
    float* out;
    int s, d, w;
    if (wid < EPPI) {
        w = wid; s = psrc[w]; d = pdst[w]; q = qr; out = alphap;
    } else if (wid < EPPI + EKNN) {
        w = wid - EPPI; s = ksrc[w]; d = kdst[w]; q = qc; out = alphak;
    } else return;
    const size_t qb = (size_t)d * 512;
    const size_t kb = (size_t)s * 512 + 128;
    float v = q[qb + lane] * q[kb + lane] + q[qb + 64 + lane] * q[kb + 64 + lane];
    #pragma unroll
    for (int off = 32; off; off >>= 1) v += __shfl_down(v, off);
    if (lane == 0) out[w] = v * 0.08838834764831845f;  // 1/sqrt(128)
}

__global__ __launch_bounds__(256)
void reduce_stats(const float* __restrict__ a, int E, double* __restrict__ stats) {
    double s = 0.0, s2 = 0.0;
    for (int i = blockIdx.x * blockDim.x + threadIdx.x; i < E; i += gridDim.x * blockDim.x) {
        double x = a[i];
        s += x; s2 += x * x;
    }
    #pragma unroll
    for (int off = 32; off; off >>= 1) {
        s += __shfl_down(s, off);
        s2 += __shfl_down(s2, off);
    }
    __shared__ double sh[4][2];
    int w = threadIdx.x >> 6;
    if ((threadIdx.x & 63) == 0) { sh[w][0] = s; sh[w][1] = s2; }
    __syncthreads();
    if (threadIdx.x == 0) {
        double t = sh[0][0] + sh[1][0] + sh[2][0] + sh[3][0];
        double t2 = sh[0][1] + sh[1][1] + sh[2][1] + sh[3][1];
        atomicAdd(&stats[0], t);
        atomicAdd(&stats[1], t2);
    }
}

// batched tconv: rows softmax path, cols sigmoid path (+bf16 copy)
__global__ __launch_bounds__(128)
void tconv2(const int* __restrict__ rpp, const int* __restrict__ srcp,
            const int* __restrict__ eidp, const float* __restrict__ alphap,
            const float* __restrict__ qr, float* __restrict__ outr,
            const int* __restrict__ rpk, const int* __restrict__ srck,
            const int* __restrict__ eidk, const float* __restrict__ alphak,
            const float* __restrict__ qc, const double* __restrict__ stats,
            float* __restrict__ outc, ushort_t* __restrict__ ob) {
    const int tid = threadIdx.x;
    __shared__ int snb[128];
    __shared__ float sa[128];
    if (blockIdx.x < NG) {
        const int node = blockIdx.x;
        const int beg = rpp[node], end = rpp[node + 1];
        float mx = -INFINITY;
        for (int c = beg; c < end; c += 128) {
            const int m = min(128, end - c);
            __syncthreads();
            if (tid < m) sa[tid] = alphap[eidp[c + tid]];
            __syncthreads();
            for (int i = 0; i < m; ++i) mx = fmaxf(mx, sa[i]);
        }
        float acc = 0.f, z = 0.f;
        for (int c = beg; c < end; c += 128) {
            const int m = min(128, end - c);
            __syncthreads();
            if (tid < m) { snb[tid] = srcp[c + tid]; sa[tid] = __expf(alphap[eidp[c + tid]] - mx); }
            __syncthreads();
            for (int i = 0; i < m; ++i) {
                z += sa[i];
                acc += sa[i] * qr[(size_t)snb[i] * 512 + 256 + tid];
            }
        }
        const float r = acc * (z > 0.f ? 1.f / z : 0.f) + qr[(size_t)node * 512 + 384 + tid];
        outr[(size_t)node * 128 + tid] = r;
    } else {
        const int node = blockIdx.x - NG;
        const int beg = rpk[node], end = rpk[node + 1];
        const double sum = stats[0], sumsq = stats[1];
        const double mu = sum / (double)EKNN;
        const double var = (sumsq - sum * sum / (double)EKNN) / (double)(EKNN - 1);
        const float sd = (float)sqrt(fmax(var, 0.0));
        const float kk = 3.0f / sd;
        const float fmu = (float)mu;
        float acc = 0.f;
        for (int c = beg; c < end; c += 128) {
            const int m = min(128, end - c);
            __syncthreads();
            if (tid < m) {
                snb[tid] = srck[c + tid];
                const float t = (alphak[eidk[c + tid]] - fmu) * kk;
                sa[tid] = 1.f / (1.f + __expf(-t));
            }
            __syncthreads();
            for (int i = 0; i < m; ++i)
                acc += sa[i] * qc[(size_t)snb[i] * 512 + 256 + tid];
        }
        const float r = acc + qc[(size_t)node * 512 + 384 + tid];
        outc[(size_t)node * 128 + tid] = r;
        ob[(size_t)node * 128 + tid] = f2b(r);
    }
}

// ---------------- workspace layout (float units) ----------------
static constexpr size_t NBIG = (size_t)NG * NC;
static constexpr size_t NBH = NBIG / 2;
static constexpr size_t OFF_B1 = 0;
static constexpr size_t OFF_B2 = NBH;
static constexpr size_t OFF_B3 = 2 * NBH;
static constexpr size_t OFF_WBF = 3 * NBH;                      // 2*NBIG floats (2 r-weights bf16)
// overlay inside WBF region at +2M floats (safe: encoder/decoder WBF0 use < 2M floats)
static constexpr size_t OFF_OV   = OFF_WBF + 2097152;
static constexpr size_t OFF_HRB  = OFF_OV;                       // bf16 2048*512
static constexpr size_t OFF_HCB  = OFF_HRB + 524288;             // bf16 4096*512
static constexpr size_t OFF_H2B  = OFF_HCB + 1048576;            // bf16 2048*512
static constexpr size_t OFF_H3B  = OFF_H2B + 524288;             // bf16 4096*512
static constexpr size_t OFF_QKVSR = OFF_H3B + 1048576;           // f32 2048*512
static constexpr size_t OFF_QKVSC = OFF_QKVSR + 1048576;         // f32 4096*512
static constexpr size_t OFF_CBF  = OFF_QKVSC + 2097152;          // bf16 4096*128
static constexpr size_t OFF_WQR  = OFF_CBF + 262144;             // bf16 512*512
static constexpr size_t OFF_WQC  = OFF_WQR + 131072;
static constexpr size_t OFF_D1T  = OFF_WQC + 131072;             // bf16 512*128
static constexpr size_t OFF_D2T  = OFF_D1T + 32768;              // bf16 512*512
static constexpr size_t OFF_D3T  = OFF_D2T + 131072;             // bf16 2048*512
// tail after WBF region
static constexpr size_t OFF_TAIL = OFF_WBF + 2 * NBIG;
static constexpr size_t OFF_B4   = OFF_TAIL;                     // f32 1024
static constexpr size_t OFF_ALPHAP = OFF_B4 + 1024;
static constexpr size_t OFF_ALPHAK = OFF_ALPHAP + EPPI;
static constexpr size_t OFF_CNT  = OFF_ALPHAK + EKNN;            // CNTP NG | CNTK NC | CURP NG | CURK NC
static constexpr size_t OFF_DINVP = OFF_CNT + 12288;
static constexpr size_t OFF_DINVK = OFF_DINVP + NG;
static constexpr size_t OFF_STATS = OFF_DINVK + NC;              // double[2]
static constexpr size_t OFF_RPP  = OFF_STATS + 16;
static constexpr size_t OFF_RPK  = OFF_RPP + 2064;
static constexpr size_t OFF_SRCP = OFF_RPK + 4112;
static constexpr size_t OFF_EIDP = OFF_SRCP + EPPI;
static constexpr size_t OFF_SRCK = OFF_EIDP + EPPI;
static constexpr size_t OFF_EIDK = OFF_SRCK + EKNN;

extern "C" void kernel_launch(void* const* d_in, const int* in_sizes, int n_in,
                              void* d_out, int out_size, void* d_ws, size_t ws_size,
                              hipStream_t stream) {
    const float* x      = (const float*)d_in[0];
    const int*   knn    = (const int*)d_in[1];
    const int*   ppi    = (const int*)d_in[2];
    const float* c0_wl = (const float*)d_in[3],  *c0_wr = (const float*)d_in[4],  *c0_b = (const float*)d_in[5];
    const float* r0_wl = (const float*)d_in[6],  *r0_wr = (const float*)d_in[7],  *r0_b = (const float*)d_in[8];
    const float* c1_wl = (const float*)d_in[9],  *c1_wr = (const float*)d_in[10], *c1_b = (const float*)d_in[11];
    const float* r1_wl = (const float*)d_in[12], *r1_wr = (const float*)d_in[13], *r1_b = (const float*)d_in[14];
    const float* gr_w  = (const float*)d_in[15], *gr_b  = (const float*)d_in[16];
    const float* tr_wq = (const float*)d_in[17], *tr_bq = (const float*)d_in[18];
    const float* tr_wk = (const float*)d_in[19], *tr_bk = (const float*)d_in[20];
    const float* tr_wv = (const float*)d_in[21], *tr_bv = (const float*)d_in[22];
    const float* tr_ws = (const float*)d_in[23], *tr_bs = (const float*)d_in[24];
    const float* gc_w  = (const float*)d_in[25], *gc_b  = (const float*)d_in[26];
    const float* tc_wq = (const float*)d_in[27], *tc_bq = (const float*)d_in[28];
    const float* tc_wk = (const float*)d_in[29], *tc_bk = (const float*)d_in[30];
    const float* tc_wv = (const float*)d_in[31], *tc_bv = (const float*)d_in[32];
    const float* tc_ws = (const float*)d_in[33], *tc_bs = (const float*)d_in[34];
    const float* d1_w  = (const float*)d_in[35], *d1_b  = (const float*)d_in[36];
    const float* d2_w  = (const float*)d_in[37], *d2_b  = (const float*)d_in[38];
    const float* d3_w  = (const float*)d_in[39], *d3_b  = (const float*)d_in[40];

    const int* knn_src = knn, *knn_dst = knn + EKNN;
    const int* ppi_src = ppi, *ppi_dst = ppi + EPPI;

    float* ws = (float*)d_ws;
    ushort_t* B1 = (ushort_t*)(ws + OFF_B1);
    ushort_t* B2 = (ushort_t*)(ws + OFF_B2);
    ushort_t* B3 = (ushort_t*)(ws + OFF_B3);
    ushort_t* WBF0 = (ushort_t*)(ws + OFF_WBF);
    ushort_t* WBF1 = WBF0 + 2 * NBIG;
    ushort_t* GRT = WBF0;                        // 512x4096 bf16 (2M shorts < 4M-short overlay gap)
    ushort_t* GCT = WBF0 + 2097152;              // 512x2048 bf16
    ushort_t* HRB = (ushort_t*)(ws + OFF_HRB);
    ushort_t* HCB = (ushort_t*)(ws + OFF_HCB);
    ushort_t* H2B = (ushort_t*)(ws + OFF_H2B);
    ushort_t* H3B = (ushort_t*)(ws + OFF_H3B);
    float* QKVSR = ws + OFF_QKVSR;
    float* QKVSC = ws + OFF_QKVSC;
    ushort_t* CBF = (ushort_t*)(ws + OFF_CBF);
    ushort_t* WQR = (ushort_t*)(ws + OFF_WQR);
    ushort_t* WQC = (ushort_t*)(ws + OFF_WQC);
    ushort_t* D1T = (ushort_t*)(ws + OFF_D1T);
    ushort_t* D2T = (ushort_t*)(ws + OFF_D2T);
    ushort_t* D3T = (ushort_t*)(ws + OFF_D3T);
    float* B4 = ws + OFF_B4;
    float* ALPHAP = ws + OFF_ALPHAP;
    float* ALPHAK = ws + OFF_ALPHAK;
    float* CNTP = ws + OFF_CNT;
    float* CNTK = CNTP + NG;
    int* CURP = (int*)(CNTK + NC);
    int* CURK = CURP + NG;
    float* DINVP = ws + OFF_DINVP;
    float* DINVK = ws + OFF_DINVK;
    double* STATS = (double*)(ws + OFF_STATS);
    int* RPP  = (int*)(ws + OFF_RPP);
    int* RPK  = (int*)(ws + OFF_RPK);
    int* SRCP = (int*)(ws + OFF_SRCP);
    int* EIDP = (int*)(ws + OFF_EIDP);
    int* SRCK = (int*)(ws + OFF_SRCK);
    int* EIDK = (int*)(ws + OFF_EIDK);

    float* out_rows = (float*)d_out;
    float* out_cols = out_rows + (size_t)NG * 128;
    float* out_feat = out_cols + (size_t)NC * 128;

    auto tW = [&](const float* Wsrc, int K, int N, ushort_t* dst) {
        transpose_f2b<<<dim3(N >> 6, K >> 6), 256, 0, stream>>>(Wsrc, dst, K, N);
    };
    auto gemm = [&](const ushort_t* Abf, const ushort_t* Wt, const float* bias,
                    float* Cf, ushort_t* Cb, int M, int N, int K, int mode) {
        dim3 g(N >> 7, M >> 7), blk(256);
        switch (mode) {
            case 2: gemm_bf16<0, true,  false><<<g, blk, 0, stream>>>(Abf, Wt, bias, Cf, nullptr, M, N, K); break;
            case 3: gemm_bf16<2, true,  true ><<<g, blk, 0, stream>>>(Abf, Wt, bias, nullptr, Cb, M, N, K); break;
        }
    };

    // ---- CSR build (batched) ----
    hipMemsetAsync(CNTP, 0, 12288 * 4, stream);
    count_dst2<<<cdiv(EPPI + EKNN, 256), 256, 0, stream>>>(ppi_dst, CNTP, knn_dst, CNTK);
    make_dinv2<<<cdiv(NG + NC, 256), 256, 0, stream>>>(CNTP, DINVP, CNTK, DINVK);
    scan_rowptr2<<<2, 256, 0, stream>>>(CNTP, RPP, CNTK, RPK);
    fill_csr2<<<cdiv(EPPI + EKNN, 256), 256, 0, stream>>>(ppi_src, ppi_dst, RPP, CURP, SRCP, EIDP,
                                                          knn_src, knn_dst, RPK, CURK, SRCK, EIDK);

    // ---- SAGE blocks ----
    transpose_f2b<<<dim3(NC >> 6, NG >> 6), 256, 0, stream>>>(x, B1, NG, NC);   // B1 [NC][NG]
    const float* cwl[2] = {c0_wl, c1_wl}; const float* cwr[2] = {c0_wr, c1_wr}; const float* cbb[2] = {c0_b, c1_b};
    const float* rwl[2] = {r0_wl, r1_wl}; const float* rwr[2] = {r0_wr, r1_wr}; const float* rbb[2] = {r0_b, r1_b};
    for (int l = 0; l < 2; ++l) {
        sage_gather_b<1><<<NC, 256, 0, stream>>>(RPK, SRCK, B1, B2);
        transpose_f2b2<<<dim3(NG >> 6, NG >> 6, 2), 256, 0, stream>>>(cwl[l], WBF0, cwr[l], WBF1, NG, NG);
        gemm_sage<<<dim3(NC >> 7, NG >> 7), 256, 0, stream>>>(WBF0, B2, WBF1, B1, cbb[l], B3, NG, NC, NG);
        sage_gather_b<2><<<NG, 256, 0, stream>>>(RPP, SRCP, B3, B2);
        transpose_f2b2<<<dim3(NC >> 6, NC >> 6, 2), 256, 0, stream>>>(rwl[l], WBF0, rwr[l], WBF1, NC, NC);
        gemm_sage<<<dim3(NG >> 7, NC >> 7), 256, 0, stream>>>(WBF0, B2, WBF1, B3, rbb[l], B1, NC, NG, NC);
    }
    transpose_b2b<<<dim3(NG >> 6, NC >> 6), 256, 0, stream>>>(B1, B3, NC, NG);   // B3 [NG][NC]

    // ---- encoders (batched pairwise) ----
    tW(gr_w, NC, 512, GRT);
    tW(gc_w, NG, 512, GCT);
    // enc-in: Hr = B3 @ gr_w (bf16 out), Hc = B1 @ gc_w (bf16 out)
    gemm2_bf16<false, true><<<64 + 128, 256, 0, stream>>>(
        B3, GRT, nullptr, nullptr, HRB, 512, NC, 4, 64,
        B1, GCT, nullptr, nullptr, HCB, 512, NG, 4);
    gcn_gather2<<<NG + NC, 128, 0, stream>>>(RPP, SRCP, HRB, DINVP, gr_b, H2B,
                                             RPK, SRCK, HCB, DINVK, gc_b, H3B);
    transpose_qkvs8<<<dim3(2, 8, 8), 256, 0, stream>>>(tr_wq, tr_wk, tr_wv, tr_ws,
                                                       tc_wq, tc_wk, tc_wv, tc_ws, WQR, WQC);
    concat8<<<4, 256, 0, stream>>>(tr_bq, tr_bk, tr_bv, tr_bs, tc_bq, tc_bk, tc_bv, tc_bs, B4);
    gemm2_bf16<true, false><<<64 + 128, 256, 0, stream>>>(
        H2B, WQR, B4, QKVSR, nullptr, 512, 512, 4, 64,
        H3B, WQC, B4 + 512, QKVSC, nullptr, 512, 512, 4);
    edge_dot2<<<cdiv((EPPI + EKNN) * 64, 256), 256, 0, stream>>>(
        ppi_src, ppi_dst, QKVSR, ALPHAP, knn_src, knn_dst, QKVSC, ALPHAK);
    hipMemsetAsync(STATS, 0, 16, stream);
    reduce_stats<<<256, 256, 0, stream>>>(ALPHAK, EKNN, STATS);
    tconv2<<<NG + NC, 128, 0, stream>>>(RPP, SRCP, EIDP, ALPHAP, QKVSR, out_rows,
                                        RPK, SRCK, EIDK, ALPHAK, QKVSC, STATS, out_cols, CBF);

    // ---- decoder ----
    tW(d1_w, 128, 512, D1T);
    gemm(CBF, D1T, d1_b, nullptr, H2B, NC, 512, 128, 3);
    tW(d2_w, 512, 512, D2T);
    gemm(H2B, D2T, d2_b, nullptr, H3B, NC, 512, 512, 3);
    tW(d3_w, 512, NG, D3T);
    gemm(H3B, D3T, d3_b, out_feat, nullptr, NC, NG, 512, 2);

    (void)in_sizes; (void)n_in; (void)out_size; (void)ws_size;
}

// Round 9
// 943.686 us; speedup vs baseline: 19.3045x; 1.0329x over previous
//
#include <hip/hip_runtime.h>
#include <math.h>

#define NG 2048
#define NC 4096
#define EKNN 61440
#define EPPI 65536
#define NJMAX 14

typedef __attribute__((ext_vector_type(8))) short short8v;
typedef __attribute__((ext_vector_type(4))) float f32x4;
typedef unsigned short ushort_t;

static inline int cdiv(int a, int b) { return (a + b - 1) / b; }

__device__ __forceinline__ unsigned short f2b(float f) {
    union { float f; unsigned int i; } v; v.f = f;
    unsigned int r = v.i + 0x7FFFu + ((v.i >> 16) & 1u);
    return (unsigned short)(r >> 16);
}
__device__ __forceinline__ float bl(unsigned int u) { union { unsigned int i; float f; } v; v.i = u << 16; return v.f; }
__device__ __forceinline__ float bh(unsigned int u) { union { unsigned int i; float f; } v; v.i = u & 0xFFFF0000u; return v.f; }
__device__ __forceinline__ unsigned int pk2(float a, float b) { return (unsigned int)f2b(a) | ((unsigned int)f2b(b) << 16); }

__device__ __forceinline__ int xcd_swz_id() {
    const int nwg = gridDim.x * gridDim.y;
    const int orig = blockIdx.y * gridDim.x + blockIdx.x;
    const int q = nwg >> 3, r = nwg & 7;
    const int xcd = orig & 7, off = orig >> 3;
    return (xcd < r ? xcd * (q + 1) : r * (q + 1) + (xcd - r) * q) + off;
}

#define GLOAD_LDS16(gp, lp) __builtin_amdgcn_global_load_lds( \
    (const __attribute__((address_space(1))) void*)(gp),      \
    (__attribute__((address_space(3))) void*)(lp), 16, 0, 0)

// transpose job list (by-value kernel arg)
struct TJobs {
    const void* in[NJMAX];
    ushort_t* out[NJMAX];
    int R[NJMAX], C[NJMAX], start[NJMAX], type[NJMAX];  // type 0=f32->bf16, 1=bf16->bf16
    int n;
    int nGather;
};

// ================= bf16 MFMA GEMM (single, XCD-swizzled) =================
template<int ACT, bool BIAS, bool OBF>
__global__ __launch_bounds__(256)
void gemm_bf16(const ushort_t* __restrict__ A,
               const ushort_t* __restrict__ Bt,
               const float* __restrict__ bias,
               float* __restrict__ Cf, ushort_t* __restrict__ Cb,
               int M, int N, int K) {
    __shared__ ushort_t lds[2][2][128 * 32];
    const int tid = threadIdx.x;
    const int lane = tid & 63, wv = tid >> 6;
    const int wm = wv >> 1, wn = wv & 1;
    const int swzid = xcd_swz_id();
    const int bm = (swzid / gridDim.x) << 7, bn = (swzid % gridDim.x) << 7;

    const ushort_t* gA = A + (size_t)bm * K;
    const ushort_t* gB = Bt + (size_t)bn * K;
    const int rsub = lane >> 2;
    const int qsw  = (lane & 3) ^ ((lane >> 3) & 3);
    const int KT = K >> 5;

    f32x4 acc[4][4];
    #pragma unroll
    for (int i = 0; i < 4; ++i)
        #pragma unroll
        for (int j = 0; j < 4; ++j) acc[i][j] = (f32x4){0.f, 0.f, 0.f, 0.f};

    auto stage = [&](int buf, int k0) {
        #pragma unroll
        for (int t = 0; t < 2; ++t) {
            const int br = (wv * 2 + t) * 16;
            GLOAD_LDS16(gA + (size_t)(br + rsub) * K + k0 + qsw * 8, &lds[buf][0][br * 32]);
            GLOAD_LDS16(gB + (size_t)(br + rsub) * K + k0 + qsw * 8, &lds[buf][1][br * 32]);
        }
    };
    const int rl = lane & 15, kg = lane >> 4;
    const int swr = (kg ^ ((rl >> 1) & 3)) * 8;

    stage(0, 0);
    int buf = 0;
    for (int kt = 0; kt < KT; ++kt) {
        __syncthreads();
        if (kt + 1 < KT) stage(buf ^ 1, (kt + 1) << 5);
        short8v a[4], b[4];
        #pragma unroll
        for (int mi = 0; mi < 4; ++mi)
            a[mi] = *(const short8v*)&lds[buf][0][(wm * 64 + mi * 16 + rl) * 32 + swr];
        #pragma unroll
        for (int ni = 0; ni < 4; ++ni)
            b[ni] = *(const short8v*)&lds[buf][1][(wn * 64 + ni * 16 + rl) * 32 + swr];
        #pragma unroll
        for (int mi = 0; mi < 4; ++mi)
            #pragma unroll
            for (int ni = 0; ni < 4; ++ni)
                acc[mi][ni] = __builtin_amdgcn_mfma_f32_16x16x32_bf16(a[mi], b[ni], acc[mi][ni], 0, 0, 0);
        buf ^= 1;
    }
    const int colL = lane & 15, rq = lane >> 4;
    #pragma unroll
    for (int mi = 0; mi < 4; ++mi) {
        const int row0 = bm + wm * 64 + mi * 16 + rq * 4;
        #pragma unroll
        for (int ni = 0; ni < 4; ++ni) {
            const int col = bn + wn * 64 + ni * 16 + colL;
            float bv = 0.f;
            if (BIAS) bv = bias[col];
            #pragma unroll
            for (int r = 0; r < 4; ++r) {
                const size_t off = (size_t)(row0 + r) * N + col;
                float v = acc[mi][ni][r];
                if (BIAS) v += bv;
                if (ACT == 2) v = fmaxf(v, 0.f);
                if (OBF) Cb[off] = f2b(v); else Cf[off] = v;
            }
        }
    }
}

// ================= batched dual GEMM =================
template<bool BIAS, bool OBF>
__global__ __launch_bounds__(256)
void gemm2_bf16(const ushort_t* __restrict__ A0, const ushort_t* __restrict__ Bt0,
                const float* __restrict__ bias0, float* __restrict__ Cf0, ushort_t* __restrict__ Cb0,
                int N0, int K0, int nx0, int nb0,
                const ushort_t* __restrict__ A1, const ushort_t* __restrict__ Bt1,
                const float* __restrict__ bias1, float* __restrict__ Cf1, ushort_t* __restrict__ Cb1,
                int N1, int K1, int nx1) {
    __shared__ ushort_t lds[2][2][128 * 32];
    const int bid = blockIdx.x;
    const bool p1 = bid >= nb0;
    const int lbid = p1 ? bid - nb0 : bid;
    const ushort_t* A = p1 ? A1 : A0;
    const ushort_t* Bt = p1 ? Bt1 : Bt0;
    const float* bias = p1 ? bias1 : bias0;
    float* Cf = p1 ? Cf1 : Cf0;
    ushort_t* Cb = p1 ? Cb1 : Cb0;
    const int N = p1 ? N1 : N0;
    const int K = p1 ? K1 : K0;
    const int nx = p1 ? nx1 : nx0;
    const int bn = (lbid % nx) << 7, bm = (lbid / nx) << 7;

    const int tid = threadIdx.x;
    const int lane = tid & 63, wv = tid >> 6;
    const int wm = wv >> 1, wn = wv & 1;
    const ushort_t* gA = A + (size_t)bm * K;
    const ushort_t* gB = Bt + (size_t)bn * K;
    const int rsub = lane >> 2;
    const int qsw  = (lane & 3) ^ ((lane >> 3) & 3);
    const int KT = K >> 5;

    f32x4 acc[4][4];
    #pragma unroll
    for (int i = 0; i < 4; ++i)
        #pragma unroll
        for (int j = 0; j < 4; ++j) acc[i][j] = (f32x4){0.f, 0.f, 0.f, 0.f};

    auto stage = [&](int buf, int k0) {
        #pragma unroll
        for (int t = 0; t < 2; ++t) {
            const int br = (wv * 2 + t) * 16;
            GLOAD_LDS16(gA + (size_t)(br + rsub) * K + k0 + qsw * 8, &lds[buf][0][br * 32]);
            GLOAD_LDS16(gB + (size_t)(br + rsub) * K + k0 + qsw * 8, &lds[buf][1][br * 32]);
        }
    };
    const int rl = lane & 15, kg = lane >> 4;
    const int swr = (kg ^ ((rl >> 1) & 3)) * 8;

    stage(0, 0);
    int buf = 0;
    for (int kt = 0; kt < KT; ++kt) {
        __syncthreads();
        if (kt + 1 < KT) stage(buf ^ 1, (kt + 1) << 5);
        short8v a[4], b[4];
        #pragma unroll
        for (int mi = 0; mi < 4; ++mi)
            a[mi] = *(const short8v*)&lds[buf][0][(wm * 64 + mi * 16 + rl) * 32 + swr];
        #pragma unroll
        for (int ni = 0; ni < 4; ++ni)
            b[ni] = *(const short8v*)&lds[buf][1][(wn * 64 + ni * 16 + rl) * 32 + swr];
        #pragma unroll
        for (int mi = 0; mi < 4; ++mi)
            #pragma unroll
            for (int ni = 0; ni < 4; ++ni)
                acc[mi][ni] = __builtin_amdgcn_mfma_f32_16x16x32_bf16(a[mi], b[ni], acc[mi][ni], 0, 0, 0);
        buf ^= 1;
    }
    const int colL = lane & 15, rq = lane >> 4;
    #pragma unroll
    for (int mi = 0; mi < 4; ++mi) {
        const int row0 = bm + wm * 64 + mi * 16 + rq * 4;
        #pragma unroll
        for (int ni = 0; ni < 4; ++ni) {
            const int col = bn + wn * 64 + ni * 16 + colL;
            float bv = 0.f;
            if (BIAS) bv = bias[col];
            #pragma unroll
            for (int r = 0; r < 4; ++r) {
                const size_t off = (size_t)(row0 + r) * N + col;
                float v = acc[mi][ni][r];
                if (BIAS) v += bv;
                if (OBF) Cb[off] = f2b(v); else Cf[off] = v;
            }
        }
    }
}

// ================= fused SAGE GEMM (swapped orientation, ROW bias) =================
__global__ __launch_bounds__(256)
void gemm_sage(const ushort_t* __restrict__ A0, const ushort_t* __restrict__ B0t,
               const ushort_t* __restrict__ A1, const ushort_t* __restrict__ B1t,
               const float* __restrict__ bias, ushort_t* __restrict__ Cb,
               int M, int N, int K) {
    __shared__ ushort_t lds[2][2][128 * 32];
    const int tid = threadIdx.x;
    const int lane = tid & 63, wv = tid >> 6;
    const int wm = wv >> 1, wn = wv & 1;
    const int swzid = xcd_swz_id();
    const int bm = (swzid / gridDim.x) << 7, bn = (swzid % gridDim.x) << 7;

    const ushort_t* gA0 = A0 + (size_t)bm * K;
    const ushort_t* gB0 = B0t + (size_t)bn * K;
    const ushort_t* gA1 = A1 + (size_t)bm * K;
    const ushort_t* gB1 = B1t + (size_t)bn * K;
    const int rsub = lane >> 2;
    const int qsw  = (lane & 3) ^ ((lane >> 3) & 3);
    const int KT = K >> 5;

    f32x4 acc[4][4];
    #pragma unroll
    for (int i = 0; i < 4; ++i)
        #pragma unroll
        for (int j = 0; j < 4; ++j) acc[i][j] = (f32x4){0.f, 0.f, 0.f, 0.f};

    auto stage = [&](int buf, int kt) {
        const int half = kt >= KT;
        const int k0 = (half ? (kt - KT) : kt) << 5;
        const ushort_t* sA = half ? gA1 : gA0;
        const ushort_t* sB = half ? gB1 : gB0;
        #pragma unroll
        for (int t = 0; t < 2; ++t) {
            const int br = (wv * 2 + t) * 16;
            GLOAD_LDS16(sA + (size_t)(br + rsub) * K + k0 + qsw * 8, &lds[buf][0][br * 32]);
            GLOAD_LDS16(sB + (size_t)(br + rsub) * K + k0 + qsw * 8, &lds[buf][1][br * 32]);
        }
    };
    const int rl = lane & 15, kg = lane >> 4;
    const int swr = (kg ^ ((rl >> 1) & 3)) * 8;

    stage(0, 0);
    int buf = 0;
    const int KT2 = KT * 2;
    for (int kt = 0; kt < KT2; ++kt) {
        __syncthreads();
        if (kt + 1 < KT2) stage(buf ^ 1, kt + 1);
        short8v a[4], b[4];
        #pragma unroll
        for (int mi = 0; mi < 4; ++mi)
            a[mi] = *(const short8v*)&lds[buf][0][(wm * 64 + mi * 16 + rl) * 32 + swr];
        #pragma unroll
        for (int ni = 0; ni < 4; ++ni)
            b[ni] = *(const short8v*)&lds[buf][1][(wn * 64 + ni * 16 + rl) * 32 + swr];
        #pragma unroll
        for (int mi = 0; mi < 4; ++mi)
            #pragma unroll
            for (int ni = 0; ni < 4; ++ni)
                acc[mi][ni] = __builtin_amdgcn_mfma_f32_16x16x32_bf16(a[mi], b[ni], acc[mi][ni], 0, 0, 0);
        buf ^= 1;
    }
    const int colL = lane & 15, rq = lane >> 4;
    #pragma unroll
    for (int mi = 0; mi < 4; ++mi) {
        const int row0 = bm + wm * 64 + mi * 16 + rq * 4;
        float bz[4];
        #pragma unroll
        for (int r = 0; r < 4; ++r) bz[r] = bias[row0 + r];
        #pragma unroll
        for (int ni = 0; ni < 4; ++ni) {
            const int col = bn + wn * 64 + ni * 16 + colL;
            #pragma unroll
            for (int r = 0; r < 4; ++r) {
                float v = acc[mi][ni][r] + bz[r];
                v = v > 0.f ? v : 0.01f * v;
                Cb[(size_t)(row0 + r) * N + col] = f2b(v);
            }
        }
    }
}

// ================= fused: SAGE gather + transpose-job tail =================
template<int NS>
__global__ __launch_bounds__(256)
void gather_tr(const int* __restrict__ rowptr, const int* __restrict__ srcs,
               const ushort_t* __restrict__ x, ushort_t* __restrict__ xout,
               TJobs jobs) {
    __shared__ ushort_t shm[64 * 65];
    const int tid = threadIdx.x;
    if ((int)blockIdx.x < jobs.nGather) {
        const int F = NS * 2048;
        const int node = blockIdx.x;
        int* snb = (int*)shm;
        const int beg = rowptr[node], end = rowptr[node + 1];
        float acc[NS][8];
        #pragma unroll
        for (int s = 0; s < NS; ++s)
            #pragma unroll
            for (int j = 0; j < 8; ++j) acc[s][j] = 0.f;
        for (int c = beg; c < end; c += 256) {
            const int m = min(256, end - c);
            __syncthreads();
            if (tid < m) snb[tid] = srcs[c + tid];
            __syncthreads();
            #pragma unroll 2
            for (int i = 0; i < m; ++i) {
                const uint4* row = (const uint4*)(x + (size_t)snb[i] * F);
                #pragma unroll
                for (int s = 0; s < NS; ++s) {
                    const uint4 v = row[tid + s * 256];
                    acc[s][0] += bl(v.x); acc[s][1] += bh(v.x);
                    acc[s][2] += bl(v.y); acc[s][3] += bh(v.y);
                    acc[s][4] += bl(v.z); acc[s][5] += bh(v.z);
                    acc[s][6] += bl(v.w); acc[s][7] += bh(v.w);
                }
            }
        }
        const float inv = 1.f / fmaxf((float)(end - beg), 1.f);
        uint4* orow = (uint4*)(xout + (size_t)node * F);
        #pragma unroll
        for (int s = 0; s < NS; ++s) {
            uint4 o;
            o.x = pk2(acc[s][0] * inv, acc[s][1] * inv);
            o.y = pk2(acc[s][2] * inv, acc[s][3] * inv);
            o.z = pk2(acc[s][4] * inv, acc[s][5] * inv);
            o.w = pk2(acc[s][6] * inv, acc[s][7] * inv);
            orow[tid + s * 256] = o;
        }
        return;
    }
    // ---- transpose jobs ----
    int b = blockIdx.x - jobs.nGather;
    int j = 0;
    while (j + 1 < jobs.n && b >= jobs.start[j + 1]) ++j;
    const int t = b - jobs.start[j];
    const int R = jobs.R[j], C = jobs.C[j];
    const int nx = C >> 6;
    const int bx = (t % nx) << 6, by = (t / nx) << 6;
    const int tr = tid >> 4, tc = (tid & 15) << 2;
    if (jobs.type[j] == 0) {
        const float* in = (const float*)jobs.in[j];
        #pragma unroll
        for (int i = 0; i < 4; ++i) {
            const int rr = tr + i * 16;
            const float4 v = *(const float4*)(in + (size_t)(by + rr) * C + bx + tc);
            shm[rr * 65 + tc + 0] = f2b(v.x); shm[rr * 65 + tc + 1] = f2b(v.y);
            shm[rr * 65 + tc + 2] = f2b(v.z); shm[rr * 65 + tc + 3] = f2b(v.w);
        }
    } else {
        const ushort_t* in = (const ushort_t*)jobs.in[j];
        #pragma unroll
        for (int i = 0; i < 4; ++i) {
            const int rr = tr + i * 16;
            const ushort4 v = *(const ushort4*)(in + (size_t)(by + rr) * C + bx + tc);
            shm[rr * 65 + tc + 0] = v.x; shm[rr * 65 + tc + 1] = v.y;
            shm[rr * 65 + tc + 2] = v.z; shm[rr * 65 + tc + 3] = v.w;
        }
    }
    __syncthreads();
    ushort_t* out = jobs.out[j];
    #pragma unroll
    for (int i = 0; i < 4; ++i) {
        const int cc = tr + i * 16;
        ushort4 o;
        o.x = shm[(tc + 0) * 65 + cc]; o.y = shm[(tc + 1) * 65 + cc];
        o.z = shm[(tc + 2) * 65 + cc]; o.w = shm[(tc + 3) * 65 + cc];
        *(ushort4*)(out + (size_t)(bx + cc) * R + by + tc) = o;
    }
}

// ---------------- standalone f32->bf16 transpose (x input) ----------------
__global__ __launch_bounds__(256)
void transpose_f2b(const float* __restrict__ in, ushort_t* __restrict__ out, int R, int C) {
    __shared__ ushort_t t[64][65];
    const int bx = blockIdx.x << 6, by = blockIdx.y << 6;
    const int tr = threadIdx.x >> 4;
    const int tc = (threadIdx.x & 15) << 2;
    #pragma unroll
    for (int i = 0; i < 4; ++i) {
        const int rr = tr + i * 16;
        const float4 v = *(const float4*)(in + (size_t)(by + rr) * C + bx + tc);
        t[rr][tc + 0] = f2b(v.x); t[rr][tc + 1] = f2b(v.y);
        t[rr][tc + 2] = f2b(v.z); t[rr][tc + 3] = f2b(v.w);
    }
    __syncthreads();
    #pragma unroll
    for (int i = 0; i < 4; ++i) {
        const int cc = tr + i * 16;
        ushort4 o;
        o.x = t[tc + 0][cc]; o.y = t[tc + 1][cc];
        o.z = t[tc + 2][cc]; o.w = t[tc + 3][cc];
        *(ushort4*)(out + (size_t)(bx + cc) * R + by + tc) = o;
    }
}

// ---------------- CSR build ----------------
__global__ void count_dst2(const int* __restrict__ pdst, float* __restrict__ cntp,
                           const int* __restrict__ kdst, float* __restrict__ cntk) {
    int e = blockIdx.x * blockDim.x + threadIdx.x;
    if (e < EPPI) atomicAdd(&cntp[pdst[e]], 1.0f);
    else if (e < EPPI + EKNN) atomicAdd(&cntk[kdst[e - EPPI]], 1.0f);
}

__global__ void make_dinv2(const float* __restrict__ cntp, float* __restrict__ dinvp,
                           const float* __restrict__ cntk, float* __restrict__ dinvk) {
    int i = blockIdx.x * blockDim.x + threadIdx.x;
    if (i < NG) dinvp[i] = rsqrtf(cntp[i] + 1.0f);
    else if (i < NG + NC) dinvk[i - NG] = rsqrtf(cntk[i - NG] + 1.0f);
}

__global__ __launch_bounds__(256)
void scan_rowptr2(const float* __restrict__ cntp, int* __restrict__ rpp,
                  const float* __restrict__ cntk, int* __restrict__ rpk) {
    const float* cnt = blockIdx.x ? cntk : cntp;
    int* rowptr = blockIdx.x ? rpk : rpp;
    const int n = blockIdx.x ? NC : NG;
    __shared__ int part[257];
    const int tid = threadIdx.x;
    const int per = n >> 8;
    const int base = tid * per;
    int s = 0;
    for (int i = 0; i < per; ++i) s += (int)cnt[base + i];
    part[tid + 1] = s;
    if (tid == 0) part[0] = 0;
    __syncthreads();
    if (tid == 0)
        for (int i = 1; i <= 256; ++i) part[i] += part[i - 1];
    __syncthreads();
    int run = part[tid];
    for (int i = 0; i < per; ++i) {
        rowptr[base + i] = run;
        run += (int)cnt[base + i];
    }
    if (tid == 255) rowptr[n] = run;
}

__global__ void fill_csr2(const int* __restrict__ psrc, const int* __restrict__ pdst,
                          const int* __restrict__ rpp, int* __restrict__ curp,
                          int* __restrict__ srcp, int* __restrict__ eidp,
                          const int* __restrict__ ksrc, const int* __restrict__ kdst,
                          const int* __restrict__ rpk, int* __restrict__ curk,
                          int* __restrict__ srck, int* __restrict__ eidk) {
    int e = blockIdx.x * blockDim.x + threadIdx.x;
    if (e < EPPI) {
        int d = pdst[e];
        int p = atomicAdd(&curp[d], 1);
        srcp[rpp[d] + p] = psrc[e];
        eidp[rpp[d] + p] = e;
    } else if (e < EPPI + EKNN) {
        int e2 = e - EPPI;
        int d = kdst[e2];
        int p = atomicAdd(&curk[d], 1);
        srck[rpk[d] + p] = ksrc[e2];
        eidk[rpk[d] + p] = e2;
    }
}

__global__ void concat8(const float* __restrict__ a, const float* __restrict__ b,
                        const float* __restrict__ c, const float* __restrict__ d,
                        const float* __restrict__ e, const float* __restrict__ f,
                        const float* __restrict__ g, const float* __restrict__ h,
                        float* __restrict__ o, double* __restrict__ stats) {
    int i = threadIdx.x + blockIdx.x * blockDim.x;
    if (i >= 1024) return;
    if (i < 4) ((unsigned int*)stats)[i] = 0u;
    const float* s;
    int j = i & 127;
    switch (i >> 7) {
        case 0: s = a; break; case 1: s = b; break; case 2: s = c; break; case 3: s = d; break;
        case 4: s = e; break; case 5: s = f; break; case 6: s = g; break; default: s = h; break;
    }
    o[i] = s[j];
}

// ---------------- graph kernels (batched pairs) ----------------
__global__ __launch_bounds__(128)
void gcn_gather2(const int* __restrict__ rpp, const int* __restrict__ srcp,
                 const ushort_t* __restrict__ hr, const float* __restrict__ dinvp,
                 const float* __restrict__ br, ushort_t* __restrict__ outr,
                 const int* __restrict__ rpk, const int* __restrict__ srck,
                 const ushort_t* __restrict__ hc, const float* __restrict__ dinvk,
                 const float* __restrict__ bc, ushort_t* __restrict__ outc) {
    const bool cols = blockIdx.x >= NG;
    const int node = cols ? blockIdx.x - NG : blockIdx.x;
    const int tid = threadIdx.x;
    const int* rowptr = cols ? rpk : rpp;
    const int* srcs = cols ? srck : srcp;
    const ushort_t* h = cols ? hc : hr;
    const float* dinv = cols ? dinvk : dinvp;
    const float* b = cols ? bc : br;
    ushort_t* out = cols ? outc : outr;

    const int beg = rowptr[node], end = rowptr[node + 1];
    __shared__ int snb[128];
    __shared__ float sdi[128];
    float ax = 0.f, ay = 0.f, az = 0.f, aw = 0.f;
    for (int c = beg; c < end; c += 128) {
        const int m = min(128, end - c);
        __syncthreads();
        if (tid < m) { int s = srcs[c + tid]; snb[tid] = s; sdi[tid] = dinv[s]; }
        __syncthreads();
        for (int i = 0; i < m; ++i) {
            const uint2 v = ((const uint2*)(h + (size_t)snb[i] * 512))[tid];
            const float w = sdi[i];
            ax += bl(v.x) * w; ay += bh(v.x) * w;
            az += bl(v.y) * w; aw += bh(v.y) * w;
        }
    }
    const float dd = dinv[node];
    const uint2 hv = ((const uint2*)(h + (size_t)node * 512))[tid];
    const float4 bv = ((const float4*)b)[tid];
    float4 o;
    o.x = ax * dd + bl(hv.x) * dd * dd + bv.x;
    o.y = ay * dd + bh(hv.x) * dd * dd + bv.y;
    o.z = az * dd + bl(hv.y) * dd * dd + bv.z;
    o.w = aw * dd + bh(hv.y) * dd * dd + bv.w;
    o.x = o.x > 0.f ? o.x : 0.01f * o.x;
    o.y = o.y > 0.f ? o.y : 0.01f * o.y;
    o.z = o.z > 0.f ? o.z : 0.01f * o.z;
    o.w = o.w > 0.f ? o.w : 0.01f * o.w;
    ((uint2*)(out + (size_t)node * 512))[tid] = make_uint2(pk2(o.x, o.y), pk2(o.z, o.w));
}

__global__ __launch_bounds__(256)
void edge_dot2(const int* __restrict__ psrc, const int* __restrict__ pdst,
               const float* __restrict__ qr, float* __restrict__ alphap,
               const int* __restrict__ ksrc, const int* __restrict__ kdst,
               const float* __restrict__ qc, float* __restrict__ alphak) {
    int wid = (blockIdx.x * blockDim.x + threadIdx.x) >> 6;
    int lane = threadIdx.x & 63;
    const float* q;
    float* out;
    int s, d, w;
    if (wid < EPPI) {
        w = wid; s = psrc[w]; d = pdst[w]; q = qr; out = alphap;
    } else if (wid < EPPI + EKNN) {
        w = wid - EPPI; s = ksrc[w]; d = kdst[w]; q = qc; out = alphak;
    } else return;
    const size_t qb = (size_t)d * 512;
    const size_t kb = (size_t)s * 512 + 128;
    float v = q[qb + lane] * q[kb + lane] + q[qb + 64 + lane] * q[kb + 64 + lane];
    #pragma unroll
    for (int off = 32; off; off >>= 1) v += __shfl_down(v, off);
    if (lane == 0) out[w] = v * 0.08838834764831845f;  // 1/sqrt(128)
}

__global__ __launch_bounds__(256)
void reduce_stats(const float* __restrict__ a, int E, double* __restrict__ stats) {
    double s = 0.0, s2 = 0.0;
    for (int i = blockIdx.x * blockDim.x + threadIdx.x; i < E; i += gridDim.x * blockDim.x) {
        double x = a[i];
        s += x; s2 += x * x;
    }
    #pragma unroll
    for (int off = 32; off; off >>= 1) {
        s += __shfl_down(s, off);
        s2 += __shfl_down(s2, off);
    }
    __shared__ double sh[4][2];
    int w = threadIdx.x >> 6;
    if ((threadIdx.x & 63) == 0) { sh[w][0] = s; sh[w][1] = s2; }
    __syncthreads();
    if (threadIdx.x == 0) {
        double t = sh[0][0] + sh[1][0] + sh[2][0] + sh[3][0];
        double t2 = sh[0][1] + sh[1][1] + sh[2][1] + sh[3][1];
        atomicAdd(&stats[0], t);
        atomicAdd(&stats[1], t2);
    }
}

__global__ __launch_bounds__(128)
void tconv2(const int* __restrict__ rpp, const int* __restrict__ srcp,
            const int* __restrict__ eidp, const float* __restrict__ alphap,
            const float* __restrict__ qr, float* __restrict__ outr,
            const int* __restrict__ rpk, const int* __restrict__ srck,
            const int* __restrict__ eidk, const float* __restrict__ alphak,
            const float* __restrict__ qc, const double* __restrict__ stats,
            float* __restrict__ outc, ushort_t* __restrict__ ob) {
    const int tid = threadIdx.x;
    __shared__ int snb[128];
    __shared__ float sa[128];
    if (blockIdx.x < NG) {
        const int node = blockIdx.x;
        const int beg = rpp[node], end = rpp[node + 1];
        float mx = -INFINITY;
        for (int c = beg; c < end; c += 128) {
            const int m = min(128, end - c);
            __syncthreads();
            if (tid < m) sa[tid] = alphap[eidp[c + tid]];
            __syncthreads();
            for (int i = 0; i < m; ++i) mx = fmaxf(mx, sa[i]);
        }
        float acc = 0.f, z = 0.f;
        for (int c = beg; c < end; c += 128) {
            const int m = min(128, end - c);
            __syncthreads();
            if (tid < m) { snb[tid] = srcp[c + tid]; sa[tid] = __expf(alphap[eidp[c + tid]] - mx); }
            __syncthreads();
            for (int i = 0; i < m; ++i) {
                z += sa[i];
                acc += sa[i] * qr[(size_t)snb[i] * 512 + 256 + tid];
            }
        }
        const float r = acc * (z > 0.f ? 1.f / z : 0.f) + qr[(size_t)node * 512 + 384 + tid];
        outr[(size_t)node * 128 + tid] = r;
    } else {
        const int node = blockIdx.x - NG;
        const int beg = rpk[node], end = rpk[node + 1];
        const double sum = stats[0], sumsq = stats[1];
        const double mu = sum / (double)EKNN;
        const double var = (sumsq - sum * sum / (double)EKNN) / (double)(EKNN - 1);
        const float sd = (float)sqrt(fmax(var, 0.0));
        const float kk = 3.0f / sd;
        const float fmu = (float)mu;
        float acc = 0.f;
        for (int c = beg; c < end; c += 128) {
            const int m = min(128, end - c);
            __syncthreads();
            if (tid < m) {
                snb[tid] = srck[c + tid];
                const float t = (alphak[eidk[c + tid]] - fmu) * kk;
                sa[tid] = 1.f / (1.f + __expf(-t));
            }
            __syncthreads();
            for (int i = 0; i < m; ++i)
                acc += sa[i] * qc[(size_t)snb[i] * 512 + 256 + tid];
        }
        const float r = acc + qc[(size_t)node * 512 + 384 + tid];
        outc[(size_t)node * 128 + tid] = r;
        ob[(size_t)node * 128 + tid] = f2b(r);
    }
}

// ---------------- workspace layout (float units) ----------------
static constexpr size_t NBIG = (size_t)NG * NC;
static constexpr size_t NBH = NBIG / 2;
static constexpr size_t OFF_B1 = 0;
static constexpr size_t OFF_B2 = NBH;
static constexpr size_t OFF_B3 = 2 * NBH;
static constexpr size_t OFF_WBF = 3 * NBH;                  // 2*NBIG floats (weight pair)
// overlay inside WBF region: all written AFTER the last SAGE GEMM
static constexpr size_t OFF_GRT   = OFF_WBF;                // bf16 512x4096 -> 1048576 fl
static constexpr size_t OFF_GCT   = OFF_GRT + 1048576;      // bf16 512x2048 -> 524288
static constexpr size_t OFF_WQR   = OFF_GCT + 524288;       // bf16 512x512  -> 131072
static constexpr size_t OFF_WQC   = OFF_WQR + 131072;
static constexpr size_t OFF_D1T   = OFF_WQC + 131072;       // bf16 512x128  -> 32768
static constexpr size_t OFF_D2T   = OFF_D1T + 32768;        // bf16 512x512  -> 131072
static constexpr size_t OFF_D3T   = OFF_D2T + 131072;       // bf16 2048x512 -> 524288
static constexpr size_t OFF_HRB   = OFF_D3T + 524288;       // bf16 2048x512
static constexpr size_t OFF_HCB   = OFF_HRB + 524288;       // bf16 4096x512
static constexpr size_t OFF_H2B   = OFF_HCB + 1048576;      // bf16 2048x512
static constexpr size_t OFF_H3B   = OFF_H2B + 524288;       // bf16 4096x512
static constexpr size_t OFF_QKVSR = OFF_H3B + 1048576;      // f32 2048x512
static constexpr size_t OFF_QKVSC = OFF_QKVSR + 1048576;    // f32 4096x512
static constexpr size_t OFF_CBF   = OFF_QKVSC + 2097152;    // bf16 4096x128
// tail after WBF region
static constexpr size_t OFF_TAIL = OFF_WBF + 2 * NBIG;
static constexpr size_t OFF_B4   = OFF_TAIL;                // f32 1024
static constexpr size_t OFF_ALPHAP = OFF_B4 + 1024;
static constexpr size_t OFF_ALPHAK = OFF_ALPHAP + EPPI;
static constexpr size_t OFF_CNT  = OFF_ALPHAK + EKNN;       // CNTP NG | CNTK NC | CURP NG | CURK NC
static constexpr size_t OFF_DINVP = OFF_CNT + 12288;
static constexpr size_t OFF_DINVK = OFF_DINVP + NG;
static constexpr size_t OFF_STATS = OFF_DINVK + NC;
static constexpr size_t OFF_RPP  = OFF_STATS + 16;
static constexpr size_t OFF_RPK  = OFF_RPP + 2064;
static constexpr size_t OFF_SRCP = OFF_RPK + 4112;
static constexpr size_t OFF_EIDP = OFF_SRCP + EPPI;
static constexpr size_t OFF_SRCK = OFF_EIDP + EPPI;
static constexpr size_t OFF_EIDK = OFF_SRCK + EKNN;

extern "C" void kernel_launch(void* const* d_in, const int* in_sizes, int n_in,
                              void* d_out, int out_size, void* d_ws, size_t ws_size,
                              hipStream_t stream) {
    const float* x      = (const float*)d_in[0];
    const int*   knn    = (const int*)d_in[1];
    const int*   ppi    = (const int*)d_in[2];
    const float* c0_wl = (const float*)d_in[3],  *c0_wr = (const float*)d_in[4],  *c0_b = (const float*)d_in[5];
    const float* r0_wl = (const float*)d_in[6],  *r0_wr = (const float*)d_in[7],  *r0_b = (const float*)d_in[8];
    const float* c1_wl = (const float*)d_in[9],  *c1_wr = (const float*)d_in[10], *c1_b = (const float*)d_in[11];
    const float* r1_wl = (const float*)d_in[12], *r1_wr = (const float*)d_in[13], *r1_b = (const float*)d_in[14];
    const float* gr_w  = (const float*)d_in[15], *gr_b  = (const float*)d_in[16];
    const float* tr_wq = (const float*)d_in[17], *tr_bq = (const float*)d_in[18];
    const float* tr_wk = (const float*)d_in[19], *tr_bk = (const float*)d_in[20];
    const float* tr_wv = (const float*)d_in[21], *tr_bv = (const float*)d_in[22];
    const float* tr_ws = (const float*)d_in[23], *tr_bs = (const float*)d_in[24];
    const float* gc_w  = (const float*)d_in[25], *gc_b  = (const float*)d_in[26];
    const float* tc_wq = (const float*)d_in[27], *tc_bq = (const float*)d_in[28];
    const float* tc_wk = (const float*)d_in[29], *tc_bk = (const float*)d_in[30];
    const float* tc_wv = (const float*)d_in[31], *tc_bv = (const float*)d_in[32];
    const float* tc_ws = (const float*)d_in[33], *tc_bs = (const float*)d_in[34];
    const float* d1_w  = (const float*)d_in[35], *d1_b  = (const float*)d_in[36];
    const float* d2_w  = (const float*)d_in[37], *d2_b  = (const float*)d_in[38];
    const float* d3_w  = (const float*)d_in[39], *d3_b  = (const float*)d_in[40];

    const int* knn_src = knn, *knn_dst = knn + EKNN;
    const int* ppi_src = ppi, *ppi_dst = ppi + EPPI;

    float* ws = (float*)d_ws;
    ushort_t* B1 = (ushort_t*)(ws + OFF_B1);
    ushort_t* B2 = (ushort_t*)(ws + OFF_B2);
    ushort_t* B3 = (ushort_t*)(ws + OFF_B3);
    ushort_t* WBF0 = (ushort_t*)(ws + OFF_WBF);
    ushort_t* WBF1 = WBF0 + 2 * NBIG;
    ushort_t* GRT = (ushort_t*)(ws + OFF_GRT);
    ushort_t* GCT = (ushort_t*)(ws + OFF_GCT);
    ushort_t* WQR = (ushort_t*)(ws + OFF_WQR);
    ushort_t* WQC = (ushort_t*)(ws + OFF_WQC);
    ushort_t* D1T = (ushort_t*)(ws + OFF_D1T);
    ushort_t* D2T = (ushort_t*)(ws + OFF_D2T);
    ushort_t* D3T = (ushort_t*)(ws + OFF_D3T);
    ushort_t* HRB = (ushort_t*)(ws + OFF_HRB);
    ushort_t* HCB = (ushort_t*)(ws + OFF_HCB);
    ushort_t* H2B = (ushort_t*)(ws + OFF_H2B);
    ushort_t* H3B = (ushort_t*)(ws + OFF_H3B);
    float* QKVSR = ws + OFF_QKVSR;
    float* QKVSC = ws + OFF_QKVSC;
    ushort_t* CBF = (ushort_t*)(ws + OFF_CBF);
    float* B4 = ws + OFF_B4;
    float* ALPHAP = ws + OFF_ALPHAP;
    float* ALPHAK = ws + OFF_ALPHAK;
    float* CNTP = ws + OFF_CNT;
    float* CNTK = CNTP + NG;
    float* DINVP = ws + OFF_DINVP;
    float* DINVK = ws + OFF_DINVK;
    double* STATS = (double*)(ws + OFF_STATS);
    int* CURP = (int*)(CNTK + NC);
    int* CURK = CURP + NG;
    int* RPP  = (int*)(ws + OFF_RPP);
    int* RPK  = (int*)(ws + OFF_RPK);
    int* SRCP = (int*)(ws + OFF_SRCP);
    int* EIDP = (int*)(ws + OFF_EIDP);
    int* SRCK = (int*)(ws + OFF_SRCK);
    int* EIDK = (int*)(ws + OFF_EIDK);

    float* out_rows = (float*)d_out;
    float* out_cols = out_rows + (size_t)NG * 128;
    float* out_feat = out_cols + (size_t)NC * 128;

    auto addJ = [](TJobs& J, const void* in, ushort_t* out, int R, int C, int type) {
        int k = J.n;
        int prevEnd = (k == 0) ? 0 : J.start[k - 1] + (J.C[k - 1] >> 6) * (J.R[k - 1] >> 6);
        J.in[k] = in; J.out[k] = out; J.R[k] = R; J.C[k] = C; J.type[k] = type;
        J.start[k] = prevEnd; J.n = k + 1;
    };
    auto jBlocks = [](const TJobs& J) {
        return (J.n == 0) ? 0 : J.start[J.n - 1] + (J.C[J.n - 1] >> 6) * (J.R[J.n - 1] >> 6);
    };
    auto gemm = [&](const ushort_t* Abf, const ushort_t* Wt, const float* bias,
                    float* Cf, ushort_t* Cb, int M, int N, int K, int mode) {
        dim3 g(N >> 7, M >> 7), blk(256);
        switch (mode) {
            case 2: gemm_bf16<0, true, false><<<g, blk, 0, stream>>>(Abf, Wt, bias, Cf, nullptr, M, N, K); break;
            case 3: gemm_bf16<2, true, true ><<<g, blk, 0, stream>>>(Abf, Wt, bias, nullptr, Cb, M, N, K); break;
        }
    };

    // ---- CSR build ----
    hipMemsetAsync(CNTP, 0, 12288 * 4, stream);
    count_dst2<<<cdiv(EPPI + EKNN, 256), 256, 0, stream>>>(ppi_dst, CNTP, knn_dst, CNTK);
    make_dinv2<<<cdiv(NG + NC, 256), 256, 0, stream>>>(CNTP, DINVP, CNTK, DINVK);
    scan_rowptr2<<<2, 256, 0, stream>>>(CNTP, RPP, CNTK, RPK);
    fill_csr2<<<cdiv(EPPI + EKNN, 256), 256, 0, stream>>>(ppi_src, ppi_dst, RPP, CURP, SRCP, EIDP,
                                                          knn_src, knn_dst, RPK, CURK, SRCK, EIDK);

    // ---- SAGE blocks (gather co-dispatched with that layer's weight transposes) ----
    transpose_f2b<<<dim3(NC >> 6, NG >> 6), 256, 0, stream>>>(x, B1, NG, NC);   // B1 [NC][NG]
    const float* cwl[2] = {c0_wl, c1_wl}; const float* cwr[2] = {c0_wr, c1_wr}; const float* cbb[2] = {c0_b, c1_b};
    const float* rwl[2] = {r0_wl, r1_wl}; const float* rwr[2] = {r0_wr, r1_wr}; const float* rbb[2] = {r0_b, r1_b};
    for (int l = 0; l < 2; ++l) {
        TJobs Jc{}; Jc.n = 0; Jc.nGather = NC;
        addJ(Jc, cwl[l], WBF0, NG, NG, 0);
        addJ(Jc, cwr[l], WBF1, NG, NG, 0);
        gather_tr<1><<<NC + jBlocks(Jc), 256, 0, stream>>>(RPK, SRCK, B1, B2, Jc);
        gemm_sage<<<dim3(NC >> 7, NG >> 7), 256, 0, stream>>>(WBF0, B2, WBF1, B1, cbb[l], B3, NG, NC, NG);
        TJobs Jr{}; Jr.n = 0; Jr.nGather = NG;
        addJ(Jr, rwl[l], WBF0, NC, NC, 0);
        addJ(Jr, rwr[l], WBF1, NC, NC, 0);
        gather_tr<2><<<NG + jBlocks(Jr), 256, 0, stream>>>(RPP, SRCP, B3, B2, Jr);
        gemm_sage<<<dim3(NG >> 7, NC >> 7), 256, 0, stream>>>(WBF0, B2, WBF1, B3, rbb[l], B1, NC, NG, NC);
    }

    // ---- prep dispatch: emb4 transpose + ALL encoder/decoder weight transposes ----
    {
        TJobs Jp{}; Jp.n = 0; Jp.nGather = 0;
        addJ(Jp, B1, B3, NC, NG, 1);                 // emb4 [NG][NC] from B1 [NC][NG]
        addJ(Jp, gr_w, GRT, NC, 512, 0);
        addJ(Jp, gc_w, GCT, NG, 512, 0);
        addJ(Jp, tr_wq, WQR + 0 * 65536, 512, 128, 0);
        addJ(Jp, tr_wk, WQR + 1 * 65536, 512, 128, 0);
        addJ(Jp, tr_wv, WQR + 2 * 65536, 512, 128, 0);
        addJ(Jp, tr_ws, WQR + 3 * 65536, 512, 128, 0);
        addJ(Jp, tc_wq, WQC + 0 * 65536, 512, 128, 0);
        addJ(Jp, tc_wk, WQC + 1 * 65536, 512, 128, 0);
        addJ(Jp, tc_wv, WQC + 2 * 65536, 512, 128, 0);
        addJ(Jp, tc_ws, WQC + 3 * 65536, 512, 128, 0);
        addJ(Jp, d1_w, D1T, 128, 512, 0);
        addJ(Jp, d2_w, D2T, 512, 512, 0);
        addJ(Jp, d3_w, D3T, 512, NG, 0);
        gather_tr<1><<<jBlocks(Jp), 256, 0, stream>>>(RPK, SRCK, B1, B2, Jp);
    }

    // ---- encoders (batched pairwise) ----
    gemm2_bf16<false, true><<<64 + 128, 256, 0, stream>>>(
        B3, GRT, nullptr, nullptr, HRB, 512, NC, 4, 64,
        B1, GCT, nullptr, nullptr, HCB, 512, NG, 4);
    gcn_gather2<<<NG + NC, 128, 0, stream>>>(RPP, SRCP, HRB, DINVP, gr_b, H2B,
                                             RPK, SRCK, HCB, DINVK, gc_b, H3B);
    concat8<<<4, 256, 0, stream>>>(tr_bq, tr_bk, tr_bv, tr_bs, tc_bq, tc_bk, tc_bv, tc_bs, B4, STATS);
    gemm2_bf16<true, false><<<64 + 128, 256, 0, stream>>>(
        H2B, WQR, B4, QKVSR, nullptr, 512, 512, 4, 64,
        H3B, WQC, B4 + 512, QKVSC, nullptr, 512, 512, 4);
    edge_dot2<<<cdiv((EPPI + EKNN) * 64, 256), 256, 0, stream>>>(
        ppi_src, ppi_dst, QKVSR, ALPHAP, knn_src, knn_dst, QKVSC, ALPHAK);
    reduce_stats<<<256, 256, 0, stream>>>(ALPHAK, EKNN, STATS);
    tconv2<<<NG + NC, 128, 0, stream>>>(RPP, SRCP, EIDP, ALPHAP, QKVSR, out_rows,
                                        RPK, SRCK, EIDK, ALPHAK, QKVSC, STATS, out_cols, CBF);

    // ---- decoder ----
    gemm(CBF, D1T, d1_b, nullptr, H2B, NC, 512, 128, 3);
    gemm(H2B, D2T, d2_b, nullptr, H3B, NC, 512, 512, 3);
    gemm(H3B, D3T, d3_b, out_feat, nullptr, NC, NG, 512, 2);

    (void)in_sizes; (void)n_in; (void)out_size; (void)ws_size;
}

// Round 10
// 915.210 us; speedup vs baseline: 19.9052x; 1.0311x over previous
//
#include <hip/hip_runtime.h>
#include <math.h>

#define NG 2048
#define NC 4096
#define EKNN 61440
#define EPPI 65536
#define NJMAX 14
#define NCH_P 256   // EPPI/256
#define NCH_K 240   // EKNN/256

typedef __attribute__((ext_vector_type(8))) short short8v;
typedef __attribute__((ext_vector_type(4))) float f32x4;
typedef unsigned short ushort_t;

static inline int cdiv(int a, int b) { return (a + b - 1) / b; }

__device__ __forceinline__ unsigned short f2b(float f) {
    union { float f; unsigned int i; } v; v.f = f;
    unsigned int r = v.i + 0x7FFFu + ((v.i >> 16) & 1u);
    return (unsigned short)(r >> 16);
}
__device__ __forceinline__ float bl(unsigned int u) { union { unsigned int i; float f; } v; v.i = u << 16; return v.f; }
__device__ __forceinline__ float bh(unsigned int u) { union { unsigned int i; float f; } v; v.i = u & 0xFFFF0000u; return v.f; }
__device__ __forceinline__ unsigned int pk2(float a, float b) { return (unsigned int)f2b(a) | ((unsigned int)f2b(b) << 16); }

__device__ __forceinline__ int xcd_swz_id() {
    const int nwg = gridDim.x * gridDim.y;
    const int orig = blockIdx.y * gridDim.x + blockIdx.x;
    const int q = nwg >> 3, r = nwg & 7;
    const int xcd = orig & 7, off = orig >> 3;
    return (xcd < r ? xcd * (q + 1) : r * (q + 1) + (xcd - r) * q) + off;
}

#define GLOAD_LDS16(gp, lp) __builtin_amdgcn_global_load_lds( \
    (const __attribute__((address_space(1))) void*)(gp),      \
    (__attribute__((address_space(3))) void*)(lp), 16, 0, 0)

// transpose job list (by-value kernel arg)
struct TJobs {
    const void* in[NJMAX];
    ushort_t* out[NJMAX];
    int R[NJMAX], C[NJMAX], start[NJMAX], type[NJMAX];  // 0=f32->bf16, 1=bf16->bf16
    int n;
    int nGather;
};

// ================= bf16 MFMA GEMM (single, XCD-swizzled) =================
template<int ACT, bool BIAS, bool OBF>
__global__ __launch_bounds__(256)
void gemm_bf16(const ushort_t* __restrict__ A,
               const ushort_t* __restrict__ Bt,
               const float* __restrict__ bias,
               float* __restrict__ Cf, ushort_t* __restrict__ Cb,
               int M, int N, int K) {
    __shared__ ushort_t lds[2][2][128 * 32];
    const int tid = threadIdx.x;
    const int lane = tid & 63, wv = tid >> 6;
    const int wm = wv >> 1, wn = wv & 1;
    const int swzid = xcd_swz_id();
    const int bm = (swzid / gridDim.x) << 7, bn = (swzid % gridDim.x) << 7;

    const ushort_t* gA = A + (size_t)bm * K;
    const ushort_t* gB = Bt + (size_t)bn * K;
    const int rsub = lane >> 2;
    const int qsw  = (lane & 3) ^ ((lane >> 3) & 3);
    const int KT = K >> 5;

    f32x4 acc[4][4];
    #pragma unroll
    for (int i = 0; i < 4; ++i)
        #pragma unroll
        for (int j = 0; j < 4; ++j) acc[i][j] = (f32x4){0.f, 0.f, 0.f, 0.f};

    auto stage = [&](int buf, int k0) {
        #pragma unroll
        for (int t = 0; t < 2; ++t) {
            const int br = (wv * 2 + t) * 16;
            GLOAD_LDS16(gA + (size_t)(br + rsub) * K + k0 + qsw * 8, &lds[buf][0][br * 32]);
            GLOAD_LDS16(gB + (size_t)(br + rsub) * K + k0 + qsw * 8, &lds[buf][1][br * 32]);
        }
    };
    const int rl = lane & 15, kg = lane >> 4;
    const int swr = (kg ^ ((rl >> 1) & 3)) * 8;

    stage(0, 0);
    int buf = 0;
    for (int kt = 0; kt < KT; ++kt) {
        __syncthreads();
        if (kt + 1 < KT) stage(buf ^ 1, (kt + 1) << 5);
        short8v a[4], b[4];
        #pragma unroll
        for (int mi = 0; mi < 4; ++mi)
            a[mi] = *(const short8v*)&lds[buf][0][(wm * 64 + mi * 16 + rl) * 32 + swr];
        #pragma unroll
        for (int ni = 0; ni < 4; ++ni)
            b[ni] = *(const short8v*)&lds[buf][1][(wn * 64 + ni * 16 + rl) * 32 + swr];
        #pragma unroll
        for (int mi = 0; mi < 4; ++mi)
            #pragma unroll
            for (int ni = 0; ni < 4; ++ni)
                acc[mi][ni] = __builtin_amdgcn_mfma_f32_16x16x32_bf16(a[mi], b[ni], acc[mi][ni], 0, 0, 0);
        buf ^= 1;
    }
    const int colL = lane & 15, rq = lane >> 4;
    #pragma unroll
    for (int mi = 0; mi < 4; ++mi) {
        const int row0 = bm + wm * 64 + mi * 16 + rq * 4;
        #pragma unroll
        for (int ni = 0; ni < 4; ++ni) {
            const int col = bn + wn * 64 + ni * 16 + colL;
            float bv = 0.f;
            if (BIAS) bv = bias[col];
            #pragma unroll
            for (int r = 0; r < 4; ++r) {
                const size_t off = (size_t)(row0 + r) * N + col;
                float v = acc[mi][ni][r];
                if (BIAS) v += bv;
                if (ACT == 2) v = fmaxf(v, 0.f);
                if (OBF) Cb[off] = f2b(v); else Cf[off] = v;
            }
        }
    }
}

// ================= batched dual GEMM =================
template<bool BIAS, bool OBF>
__global__ __launch_bounds__(256)
void gemm2_bf16(const ushort_t* __restrict__ A0, const ushort_t* __restrict__ Bt0,
                const float* __restrict__ bias0, float* __restrict__ Cf0, ushort_t* __restrict__ Cb0,
                int N0, int K0, int nx0, int nb0,
                const ushort_t* __restrict__ A1, const ushort_t* __restrict__ Bt1,
                const float* __restrict__ bias1, float* __restrict__ Cf1, ushort_t* __restrict__ Cb1,
                int N1, int K1, int nx1) {
    __shared__ ushort_t lds[2][2][128 * 32];
    const int bid = blockIdx.x;
    const bool p1 = bid >= nb0;
    const int lbid = p1 ? bid - nb0 : bid;
    const ushort_t* A = p1 ? A1 : A0;
    const ushort_t* Bt = p1 ? Bt1 : Bt0;
    const float* bias = p1 ? bias1 : bias0;
    float* Cf = p1 ? Cf1 : Cf0;
    ushort_t* Cb = p1 ? Cb1 : Cb0;
    const int N = p1 ? N1 : N0;
    const int K = p1 ? K1 : K0;
    const int nx = p1 ? nx1 : nx0;
    const int bn = (lbid % nx) << 7, bm = (lbid / nx) << 7;

    const int tid = threadIdx.x;
    const int lane = tid & 63, wv = tid >> 6;
    const int wm = wv >> 1, wn = wv & 1;
    const ushort_t* gA = A + (size_t)bm * K;
    const ushort_t* gB = Bt + (size_t)bn * K;
    const int rsub = lane >> 2;
    const int qsw  = (lane & 3) ^ ((lane >> 3) & 3);
    const int KT = K >> 5;

    f32x4 acc[4][4];
    #pragma unroll
    for (int i = 0; i < 4; ++i)
        #pragma unroll
        for (int j = 0; j < 4; ++j) acc[i][j] = (f32x4){0.f, 0.f, 0.f, 0.f};

    auto stage = [&](int buf, int k0) {
        #pragma unroll
        for (int t = 0; t < 2; ++t) {
            const int br = (wv * 2 + t) * 16;
            GLOAD_LDS16(gA + (size_t)(br + rsub) * K + k0 + qsw * 8, &lds[buf][0][br * 32]);
            GLOAD_LDS16(gB + (size_t)(br + rsub) * K + k0 + qsw * 8, &lds[buf][1][br * 32]);
        }
    };
    const int rl = lane & 15, kg = lane >> 4;
    const int swr = (kg ^ ((rl >> 1) & 3)) * 8;

    stage(0, 0);
    int buf = 0;
    for (int kt = 0; kt < KT; ++kt) {
        __syncthreads();
        if (kt + 1 < KT) stage(buf ^ 1, (kt + 1) << 5);
        short8v a[4], b[4];
        #pragma unroll
        for (int mi = 0; mi < 4; ++mi)
            a[mi] = *(const short8v*)&lds[buf][0][(wm * 64 + mi * 16 + rl) * 32 + swr];
        #pragma unroll
        for (int ni = 0; ni < 4; ++ni)
            b[ni] = *(const short8v*)&lds[buf][1][(wn * 64 + ni * 16 + rl) * 32 + swr];
        #pragma unroll
        for (int mi = 0; mi < 4; ++mi)
            #pragma unroll
            for (int ni = 0; ni < 4; ++ni)
                acc[mi][ni] = __builtin_amdgcn_mfma_f32_16x16x32_bf16(a[mi], b[ni], acc[mi][ni], 0, 0, 0);
        buf ^= 1;
    }
    const int colL = lane & 15, rq = lane >> 4;
    #pragma unroll
    for (int mi = 0; mi < 4; ++mi) {
        const int row0 = bm + wm * 64 + mi * 16 + rq * 4;
        #pragma unroll
        for (int ni = 0; ni < 4; ++ni) {
            const int col = bn + wn * 64 + ni * 16 + colL;
            float bv = 0.f;
            if (BIAS) bv = bias[col];
            #pragma unroll
            for (int r = 0; r < 4; ++r) {
                const size_t off = (size_t)(row0 + r) * N + col;
                float v = acc[mi][ni][r];
                if (BIAS) v += bv;
                if (OBF) Cb[off] = f2b(v); else Cf[off] = v;
            }
        }
    }
}

// ================= fused SAGE GEMM (swapped orientation, ROW bias) =================
__global__ __launch_bounds__(256)
void gemm_sage(const ushort_t* __restrict__ A0, const ushort_t* __restrict__ B0t,
               const ushort_t* __restrict__ A1, const ushort_t* __restrict__ B1t,
               const float* __restrict__ bias, ushort_t* __restrict__ Cb,
               int M, int N, int K) {
    __shared__ ushort_t lds[2][2][128 * 32];
    const int tid = threadIdx.x;
    const int lane = tid & 63, wv = tid >> 6;
    const int wm = wv >> 1, wn = wv & 1;
    const int swzid = xcd_swz_id();
    const int bm = (swzid / gridDim.x) << 7, bn = (swzid % gridDim.x) << 7;

    const ushort_t* gA0 = A0 + (size_t)bm * K;
    const ushort_t* gB0 = B0t + (size_t)bn * K;
    const ushort_t* gA1 = A1 + (size_t)bm * K;
    const ushort_t* gB1 = B1t + (size_t)bn * K;
    const int rsub = lane >> 2;
    const int qsw  = (lane & 3) ^ ((lane >> 3) & 3);
    const int KT = K >> 5;

    f32x4 acc[4][4];
    #pragma unroll
    for (int i = 0; i < 4; ++i)
        #pragma unroll
        for (int j = 0; j < 4; ++j) acc[i][j] = (f32x4){0.f, 0.f, 0.f, 0.f};

    auto stage = [&](int buf, int kt) {
        const int half = kt >= KT;
        const int k0 = (half ? (kt - KT) : kt) << 5;
        const ushort_t* sA = half ? gA1 : gA0;
        const ushort_t* sB = half ? gB1 : gB0;
        #pragma unroll
        for (int t = 0; t < 2; ++t) {
            const int br = (wv * 2 + t) * 16;
            GLOAD_LDS16(sA + (size_t)(br + rsub) * K + k0 + qsw * 8, &lds[buf][0][br * 32]);
            GLOAD_LDS16(sB + (size_t)(br + rsub) * K + k0 + qsw * 8, &lds[buf][1][br * 32]);
        }
    };
    const int rl = lane & 15, kg = lane >> 4;
    const int swr = (kg ^ ((rl >> 1) & 3)) * 8;

    stage(0, 0);
    int buf = 0;
    const int KT2 = KT * 2;
    for (int kt = 0; kt < KT2; ++kt) {
        __syncthreads();
        if (kt + 1 < KT2) stage(buf ^ 1, kt + 1);
        short8v a[4], b[4];
        #pragma unroll
        for (int mi = 0; mi < 4; ++mi)
            a[mi] = *(const short8v*)&lds[buf][0][(wm * 64 + mi * 16 + rl) * 32 + swr];
        #pragma unroll
        for (int ni = 0; ni < 4; ++ni)
            b[ni] = *(const short8v*)&lds[buf][1][(wn * 64 + ni * 16 + rl) * 32 + swr];
        #pragma unroll
        for (int mi = 0; mi < 4; ++mi)
            #pragma unroll
            for (int ni = 0; ni < 4; ++ni)
                acc[mi][ni] = __builtin_amdgcn_mfma_f32_16x16x32_bf16(a[mi], b[ni], acc[mi][ni], 0, 0, 0);
        buf ^= 1;
    }
    const int colL = lane & 15, rq = lane >> 4;
    #pragma unroll
    for (int mi = 0; mi < 4; ++mi) {
        const int row0 = bm + wm * 64 + mi * 16 + rq * 4;
        float bz[4];
        #pragma unroll
        for (int r = 0; r < 4; ++r) bz[r] = bias[row0 + r];
        #pragma unroll
        for (int ni = 0; ni < 4; ++ni) {
            const int col = bn + wn * 64 + ni * 16 + colL;
            #pragma unroll
            for (int r = 0; r < 4; ++r) {
                float v = acc[mi][ni][r] + bz[r];
                v = v > 0.f ? v : 0.01f * v;
                Cb[(size_t)(row0 + r) * N + col] = f2b(v);
            }
        }
    }
}

// ================= fused: SAGE gather + transpose-job tail =================
template<int NS>
__global__ __launch_bounds__(256)
void gather_tr(const int* __restrict__ rowptr, const int* __restrict__ srcs,
               const ushort_t* __restrict__ x, ushort_t* __restrict__ xout,
               TJobs jobs) {
    __shared__ ushort_t shm[64 * 65];
    const int tid = threadIdx.x;
    if ((int)blockIdx.x < jobs.nGather) {
        const int F = NS * 2048;
        const int node = blockIdx.x;
        int* snb = (int*)shm;
        const int beg = rowptr[node], end = rowptr[node + 1];
        float acc[NS][8];
        #pragma unroll
        for (int s = 0; s < NS; ++s)
            #pragma unroll
            for (int j = 0; j < 8; ++j) acc[s][j] = 0.f;
        for (int c = beg; c < end; c += 256) {
            const int m = min(256, end - c);
            __syncthreads();
            if (tid < m) snb[tid] = srcs[c + tid];
            __syncthreads();
            #pragma unroll 2
            for (int i = 0; i < m; ++i) {
                const uint4* row = (const uint4*)(x + (size_t)snb[i] * F);
                #pragma unroll
                for (int s = 0; s < NS; ++s) {
                    const uint4 v = row[tid + s * 256];
                    acc[s][0] += bl(v.x); acc[s][1] += bh(v.x);
                    acc[s][2] += bl(v.y); acc[s][3] += bh(v.y);
                    acc[s][4] += bl(v.z); acc[s][5] += bh(v.z);
                    acc[s][6] += bl(v.w); acc[s][7] += bh(v.w);
                }
            }
        }
        const float inv = 1.f / fmaxf((float)(end - beg), 1.f);
        uint4* orow = (uint4*)(xout + (size_t)node * F);
        #pragma unroll
        for (int s = 0; s < NS; ++s) {
            uint4 o;
            o.x = pk2(acc[s][0] * inv, acc[s][1] * inv);
            o.y = pk2(acc[s][2] * inv, acc[s][3] * inv);
            o.z = pk2(acc[s][4] * inv, acc[s][5] * inv);
            o.w = pk2(acc[s][6] * inv, acc[s][7] * inv);
            orow[tid + s * 256] = o;
        }
        return;
    }
    // ---- transpose jobs ----
    int b = blockIdx.x - jobs.nGather;
    int j = 0;
    while (j + 1 < jobs.n && b >= jobs.start[j + 1]) ++j;
    const int t = b - jobs.start[j];
    const int R = jobs.R[j], C = jobs.C[j];
    const int nx = C >> 6;
    const int bx = (t % nx) << 6, by = (t / nx) << 6;
    const int tr = tid >> 4, tc = (tid & 15) << 2;
    if (jobs.type[j] == 0) {
        const float* in = (const float*)jobs.in[j];
        #pragma unroll
        for (int i = 0; i < 4; ++i) {
            const int rr = tr + i * 16;
            const float4 v = *(const float4*)(in + (size_t)(by + rr) * C + bx + tc);
            shm[rr * 65 + tc + 0] = f2b(v.x); shm[rr * 65 + tc + 1] = f2b(v.y);
            shm[rr * 65 + tc + 2] = f2b(v.z); shm[rr * 65 + tc + 3] = f2b(v.w);
        }
    } else {
        const ushort_t* in = (const ushort_t*)jobs.in[j];
        #pragma unroll
        for (int i = 0; i < 4; ++i) {
            const int rr = tr + i * 16;
            const ushort4 v = *(const ushort4*)(in + (size_t)(by + rr) * C + bx + tc);
            shm[rr * 65 + tc + 0] = v.x; shm[rr * 65 + tc + 1] = v.y;
            shm[rr * 65 + tc + 2] = v.z; shm[rr * 65 + tc + 3] = v.w;
        }
    }
    __syncthreads();
    ushort_t* out = jobs.out[j];
    #pragma unroll
    for (int i = 0; i < 4; ++i) {
        const int cc = tr + i * 16;
        ushort4 o;
        o.x = shm[(tc + 0) * 65 + cc]; o.y = shm[(tc + 1) * 65 + cc];
        o.z = shm[(tc + 2) * 65 + cc]; o.w = shm[(tc + 3) * 65 + cc];
        *(ushort4*)(out + (size_t)(bx + cc) * R + by + tc) = o;
    }
}

// ---------------- deterministic CSR build ----------------
// pass 1: per-chunk per-dst histogram (atomic counts are order-independent)
__global__ void cnt_chunks(const int* __restrict__ pdst, int* __restrict__ chp,
                           const int* __restrict__ kdst, int* __restrict__ chk) {
    const int bid = blockIdx.x, tid = threadIdx.x;
    if (bid < NCH_P) {
        atomicAdd(&chp[bid * NG + pdst[bid * 256 + tid]], 1);
    } else {
        const int c = bid - NCH_P;
        atomicAdd(&chk[c * NC + kdst[c * 256 + tid]], 1);
    }
}

// pass 2: exclusive prefix over chunks per dst; also emits counts + dinv
__global__ __launch_bounds__(256)
void pref_chunks(int* __restrict__ chp, int* __restrict__ chk,
                 float* __restrict__ cntp, float* __restrict__ cntk,
                 float* __restrict__ dinvp, float* __restrict__ dinvk) {
    const int bid = blockIdx.x, tid = threadIdx.x;
    if (bid < 8) {
        const int d = bid * 256 + tid;
        int run = 0;
        for (int c = 0; c < NCH_P; ++c) {
            const int t = chp[c * NG + d];
            chp[c * NG + d] = run;
            run += t;
        }
        cntp[d] = (float)run;
        dinvp[d] = rsqrtf((float)run + 1.0f);
    } else {
        const int d = (bid - 8) * 256 + tid;
        int run = 0;
        for (int c = 0; c < NCH_K; ++c) {
            const int t = chk[c * NC + d];
            chk[c * NC + d] = run;
            run += t;
        }
        cntk[d] = (float)run;
        dinvk[d] = rsqrtf((float)run + 1.0f);
    }
}

__global__ __launch_bounds__(256)
void scan_rowptr2(const float* __restrict__ cntp, int* __restrict__ rpp,
                  const float* __restrict__ cntk, int* __restrict__ rpk) {
    const float* cnt = blockIdx.x ? cntk : cntp;
    int* rowptr = blockIdx.x ? rpk : rpp;
    const int n = blockIdx.x ? NC : NG;
    __shared__ int part[257];
    const int tid = threadIdx.x;
    const int per = n >> 8;
    const int base = tid * per;
    int s = 0;
    for (int i = 0; i < per; ++i) s += (int)cnt[base + i];
    part[tid + 1] = s;
    if (tid == 0) part[0] = 0;
    __syncthreads();
    if (tid == 0)
        for (int i = 1; i <= 256; ++i) part[i] += part[i - 1];
    __syncthreads();
    int run = part[tid];
    for (int i = 0; i < per; ++i) {
        rowptr[base + i] = run;
        run += (int)cnt[base + i];
    }
    if (tid == 255) rowptr[n] = run;
}

// pass 3: deterministic slot fill (eid order within node) + x transpose tiles co-dispatched
__global__ __launch_bounds__(256)
void fill_det_xt(const int* __restrict__ psrc, const int* __restrict__ pdst,
                 const int* __restrict__ rpp, const int* __restrict__ chp,
                 int* __restrict__ srcp, int* __restrict__ eidp,
                 const int* __restrict__ ksrc, const int* __restrict__ kdst,
                 const int* __restrict__ rpk, const int* __restrict__ chk,
                 int* __restrict__ srck, int* __restrict__ eidk,
                 const float* __restrict__ x, ushort_t* __restrict__ xt) {
    __shared__ ushort_t shm[64 * 65];
    const int bid = blockIdx.x, tid = threadIdx.x;
    if (bid < NCH_P + NCH_K) {
        int* sd = (int*)shm;
        const bool knn = bid >= NCH_P;
        const int c = knn ? bid - NCH_P : bid;
        const int e = c * 256 + tid;
        const int d = knn ? kdst[e] : pdst[e];
        sd[tid] = d;
        __syncthreads();
        int rank = 0;
        for (int j = 0; j < 256; ++j)
            rank += (j < tid && sd[j] == d) ? 1 : 0;
        const int slot = (knn ? rpk : rpp)[d] + (knn ? chk + c * NC : chp + c * NG)[d] + rank;
        if (knn) { srck[slot] = ksrc[e]; eidk[slot] = e; }
        else     { srcp[slot] = psrc[e]; eidp[slot] = e; }
        return;
    }
    // x [NG][NC] -> xt [NC][NG], 64x64 tiles (NC/64=64 cols, NG/64=32 rows)
    const int t = bid - (NCH_P + NCH_K);
    const int bx = (t & 63) << 6;
    const int by = (t >> 6) << 6;
    const int tr = tid >> 4, tc = (tid & 15) << 2;
    #pragma unroll
    for (int i = 0; i < 4; ++i) {
        const int rr = tr + i * 16;
        const float4 v = *(const float4*)(x + (size_t)(by + rr) * NC + bx + tc);
        shm[rr * 65 + tc + 0] = f2b(v.x); shm[rr * 65 + tc + 1] = f2b(v.y);
        shm[rr * 65 + tc + 2] = f2b(v.z); shm[rr * 65 + tc + 3] = f2b(v.w);
    }
    __syncthreads();
    #pragma unroll
    for (int i = 0; i < 4; ++i) {
        const int cc = tr + i * 16;
        ushort4 o;
        o.x = shm[(tc + 0) * 65 + cc]; o.y = shm[(tc + 1) * 65 + cc];
        o.z = shm[(tc + 2) * 65 + cc]; o.w = shm[(tc + 3) * 65 + cc];
        *(ushort4*)(xt + (size_t)(bx + cc) * NG + by + tc) = o;
    }
}

__global__ void concat8(const float* __restrict__ a, const float* __restrict__ b,
                        const float* __restrict__ c, const float* __restrict__ d,
                        const float* __restrict__ e, const float* __restrict__ f,
                        const float* __restrict__ g, const float* __restrict__ h,
                        float* __restrict__ o) {
    int i = threadIdx.x + blockIdx.x * blockDim.x;
    if (i >= 1024) return;
    const float* s;
    int j = i & 127;
    switch (i >> 7) {
        case 0: s = a; break; case 1: s = b; break; case 2: s = c; break; case 3: s = d; break;
        case 4: s = e; break; case 5: s = f; break; case 6: s = g; break; default: s = h; break;
    }
    o[i] = s[j];
}

// ---------------- graph kernels (batched pairs) ----------------
__global__ __launch_bounds__(128)
void gcn_gather2(const int* __restrict__ rpp, const int* __restrict__ srcp,
                 const ushort_t* __restrict__ hr, const float* __restrict__ dinvp,
                 const float* __restrict__ br, ushort_t* __restrict__ outr,
                 const int* __restrict__ rpk, const int* __restrict__ srck,
                 const ushort_t* __restrict__ hc, const float* __restrict__ dinvk,
                 const float* __restrict__ bc, ushort_t* __restrict__ outc) {
    const bool cols = blockIdx.x >= NG;
    const int node = cols ? blockIdx.x - NG : blockIdx.x;
    const int tid = threadIdx.x;
    const int* rowptr = cols ? rpk : rpp;
    const int* srcs = cols ? srck : srcp;
    const ushort_t* h = cols ? hc : hr;
    const float* dinv = cols ? dinvk : dinvp;
    const float* b = cols ? bc : br;
    ushort_t* out = cols ? outc : outr;

    const int beg = rowptr[node], end = rowptr[node + 1];
    __shared__ int snb[128];
    __shared__ float sdi[128];
    float ax = 0.f, ay = 0.f, az = 0.f, aw = 0.f;
    for (int c = beg; c < end; c += 128) {
        const int m = min(128, end - c);
        __syncthreads();
        if (tid < m) { int s = srcs[c + tid]; snb[tid] = s; sdi[tid] = dinv[s]; }
        __syncthreads();
        for (int i = 0; i < m; ++i) {
            const uint2 v = ((const uint2*)(h + (size_t)snb[i] * 512))[tid];
            const float w = sdi[i];
            ax += bl(v.x) * w; ay += bh(v.x) * w;
            az += bl(v.y) * w; aw += bh(v.y) * w;
        }
    }
    const float dd = dinv[node];
    const uint2 hv = ((const uint2*)(h + (size_t)node * 512))[tid];
    const float4 bv = ((const float4*)b)[tid];
    float4 o;
    o.x = ax * dd + bl(hv.x) * dd * dd + bv.x;
    o.y = ay * dd + bh(hv.x) * dd * dd + bv.y;
    o.z = az * dd + bl(hv.y) * dd * dd + bv.z;
    o.w = aw * dd + bh(hv.y) * dd * dd + bv.w;
    o.x = o.x > 0.f ? o.x : 0.01f * o.x;
    o.y = o.y > 0.f ? o.y : 0.01f * o.y;
    o.z = o.z > 0.f ? o.z : 0.01f * o.z;
    o.w = o.w > 0.f ? o.w : 0.01f * o.w;
    ((uint2*)(out + (size_t)node * 512))[tid] = make_uint2(pk2(o.x, o.y), pk2(o.z, o.w));
}

// 16 lanes per edge, 4 edges per wave
__global__ __launch_bounds__(256)
void edge_dot2(const int* __restrict__ psrc, const int* __restrict__ pdst,
               const float* __restrict__ qr, float* __restrict__ alphap,
               const int* __restrict__ ksrc, const int* __restrict__ kdst,
               const float* __restrict__ qc, float* __restrict__ alphak) {
    const int gid = blockIdx.x * blockDim.x + threadIdx.x;
    const int wid = gid >> 6;
    const int lane = threadIdx.x & 63;
    const int e = wid * 4 + (lane >> 4);
    const int sub = lane & 15;
    const float* q;
    float* out;
    int s, d, w;
    if (e < EPPI) {
        w = e; s = psrc[w]; d = pdst[w]; q = qr; out = alphap;
    } else if (e < EPPI + EKNN) {
        w = e - EPPI; s = ksrc[w]; d = kdst[w]; q = qc; out = alphak;
    } else return;
    const float4* qa = (const float4*)(q + (size_t)d * 512 + sub * 8);
    const float4* ka = (const float4*)(q + (size_t)s * 512 + 128 + sub * 8);
    const float4 a0 = qa[0], a1 = qa[1], b0 = ka[0], b1 = ka[1];
    float v = a0.x * b0.x + a0.y * b0.y + a0.z * b0.z + a0.w * b0.w
            + a1.x * b1.x + a1.y * b1.y + a1.z * b1.z + a1.w * b1.w;
    v += __shfl_down(v, 8); v += __shfl_down(v, 4);
    v += __shfl_down(v, 2); v += __shfl_down(v, 1);
    if (sub == 0) out[w] = v * 0.08838834764831845f;  // 1/sqrt(128)
}

// deterministic: 64 block partials, no atomics
__global__ __launch_bounds__(256)
void reduce_stats2(const float* __restrict__ a, double* __restrict__ part) {
    double s = 0.0, s2 = 0.0;
    for (int i = blockIdx.x * blockDim.x + threadIdx.x; i < EKNN; i += gridDim.x * blockDim.x) {
        double xx = a[i];
        s += xx; s2 += xx * xx;
    }
    #pragma unroll
    for (int off = 32; off; off >>= 1) {
        s += __shfl_down(s, off);
        s2 += __shfl_down(s2, off);
    }
    __shared__ double sh[4][2];
    int w = threadIdx.x >> 6;
    if ((threadIdx.x & 63) == 0) { sh[w][0] = s; sh[w][1] = s2; }
    __syncthreads();
    if (threadIdx.x == 0) {
        part[2 * blockIdx.x]     = sh[0][0] + sh[1][0] + sh[2][0] + sh[3][0];
        part[2 * blockIdx.x + 1] = sh[0][1] + sh[1][1] + sh[2][1] + sh[3][1];
    }
}

__global__ __launch_bounds__(128)
void tconv2(const int* __restrict__ rpp, const int* __restrict__ srcp,
            const int* __restrict__ eidp, const float* __restrict__ alphap,
            const float* __restrict__ qr, float* __restrict__ outr,
            const int* __restrict__ rpk, const int* __restrict__ srck,
            const int* __restrict__ eidk, const float* __restrict__ alphak,
            const float* __restrict__ qc, const double* __restrict__ part,
            float* __restrict__ outc, ushort_t* __restrict__ ob) {
    const int tid = threadIdx.x;
    __shared__ int snb[128];
    __shared__ float sa[128];
    if (blockIdx.x < NG) {
        const int node = blockIdx.x;
        const int beg = rpp[node], end = rpp[node + 1];
        float mx = -INFINITY;
        for (int c = beg; c < end; c += 128) {
            const int m = min(128, end - c);
            __syncthreads();
            if (tid < m) sa[tid] = alphap[eidp[c + tid]];
            __syncthreads();
            for (int i = 0; i < m; ++i) mx = fmaxf(mx, sa[i]);
        }
        float acc = 0.f, z = 0.f;
        for (int c = beg; c < end; c += 128) {
            const int m = min(128, end - c);
            __syncthreads();
            if (tid < m) { snb[tid] = srcp[c + tid]; sa[tid] = __expf(alphap[eidp[c + tid]] - mx); }
            __syncthreads();
            for (int i = 0; i < m; ++i) {
                z += sa[i];
                acc += sa[i] * qr[(size_t)snb[i] * 512 + 256 + tid];
            }
        }
        const float r = acc * (z > 0.f ? 1.f / z : 0.f) + qr[(size_t)node * 512 + 384 + tid];
        outr[(size_t)node * 128 + tid] = r;
    } else {
        const int node = blockIdx.x - NG;
        const int beg = rpk[node], end = rpk[node + 1];
        double sum = 0.0, sumsq = 0.0;
        for (int i = 0; i < 64; ++i) { sum += part[2 * i]; sumsq += part[2 * i + 1]; }
        const double mu = sum / (double)EKNN;
        const double var = (sumsq - sum * sum / (double)EKNN) / (double)(EKNN - 1);
        const float sd = (float)sqrt(fmax(var, 0.0));
        const float kk = 3.0f / sd;
        const float fmu = (float)mu;
        float acc = 0.f;
        for (int c = beg; c < end; c += 128) {
            const int m = min(128, end - c);
            __syncthreads();
            if (tid < m) {
                snb[tid] = srck[c + tid];
                const float t = (alphak[eidk[c + tid]] - fmu) * kk;
                sa[tid] = 1.f / (1.f + __expf(-t));
            }
            __syncthreads();
            for (int i = 0; i < m; ++i)
                acc += sa[i] * qc[(size_t)snb[i] * 512 + 256 + tid];
        }
        const float r = acc + qc[(size_t)node * 512 + 384 + tid];
        outc[(size_t)node * 128 + tid] = r;
        ob[(size_t)node * 128 + tid] = f2b(r);
    }
}

// ---------------- workspace layout (float units) ----------------
static constexpr size_t NBIG = (size_t)NG * NC;
static constexpr size_t NBH = NBIG / 2;
static constexpr size_t OFF_B1 = 0;
static constexpr size_t OFF_B2 = NBH;
static constexpr size_t OFF_B3 = 2 * NBH;
static constexpr size_t OFF_WBF = 3 * NBH;                  // 2*NBIG floats (weight pair)
// overlay inside WBF region: all written AFTER the last SAGE GEMM
static constexpr size_t OFF_GRT   = OFF_WBF;
static constexpr size_t OFF_GCT   = OFF_GRT + 1048576;
static constexpr size_t OFF_WQR   = OFF_GCT + 524288;
static constexpr size_t OFF_WQC   = OFF_WQR + 131072;
static constexpr size_t OFF_D1T   = OFF_WQC + 131072;
static constexpr size_t OFF_D2T   = OFF_D1T + 32768;
static constexpr size_t OFF_D3T   = OFF_D2T + 131072;
static constexpr size_t OFF_HRB   = OFF_D3T + 524288;
static constexpr size_t OFF_HCB   = OFF_HRB + 524288;
static constexpr size_t OFF_H2B   = OFF_HCB + 1048576;
static constexpr size_t OFF_H3B   = OFF_H2B + 524288;
static constexpr size_t OFF_QKVSR = OFF_H3B + 1048576;
static constexpr size_t OFF_QKVSC = OFF_QKVSR + 1048576;
static constexpr size_t OFF_CBF   = OFF_QKVSC + 2097152;
// tail after WBF region
static constexpr size_t OFF_TAIL = OFF_WBF + 2 * NBIG;
static constexpr size_t OFF_B4   = OFF_TAIL;
static constexpr size_t OFF_ALPHAP = OFF_B4 + 1024;
static constexpr size_t OFF_ALPHAK = OFF_ALPHAP + EPPI;
static constexpr size_t OFF_CNT  = OFF_ALPHAK + EKNN;       // CNTP NG | CNTK NC
static constexpr size_t OFF_DINVP = OFF_CNT + 12288;
static constexpr size_t OFF_DINVK = OFF_DINVP + NG;
static constexpr size_t OFF_PART = OFF_DINVK + NC;          // double[128]
static constexpr size_t OFF_RPP  = OFF_PART + 256;
static constexpr size_t OFF_RPK  = OFF_RPP + 2064;
static constexpr size_t OFF_SRCP = OFF_RPK + 4112;
static constexpr size_t OFF_EIDP = OFF_SRCP + EPPI;
static constexpr size_t OFF_SRCK = OFF_EIDP + EPPI;
static constexpr size_t OFF_EIDK = OFF_SRCK + EKNN;
static constexpr size_t OFF_CHP  = OFF_EIDK + EKNN;         // int[NCH_P*NG]
static constexpr size_t OFF_CHK  = OFF_CHP + (size_t)NCH_P * NG;  // int[NCH_K*NC]

extern "C" void kernel_launch(void* const* d_in, const int* in_sizes, int n_in,
                              void* d_out, int out_size, void* d_ws, size_t ws_size,
                              hipStream_t stream) {
    const float* x      = (const float*)d_in[0];
    const int*   knn    = (const int*)d_in[1];
    const int*   ppi    = (const int*)d_in[2];
    const float* c0_wl = (const float*)d_in[3],  *c0_wr = (const float*)d_in[4],  *c0_b = (const float*)d_in[5];
    const float* r0_wl = (const float*)d_in[6],  *r0_wr = (const float*)d_in[7],  *r0_b = (const float*)d_in[8];
    const float* c1_wl = (const float*)d_in[9],  *c1_wr = (const float*)d_in[10], *c1_b = (const float*)d_in[11];
    const float* r1_wl = (const float*)d_in[12], *r1_wr = (const float*)d_in[13], *r1_b = (const float*)d_in[14];
    const float* gr_w  = (const float*)d_in[15], *gr_b  = (const float*)d_in[16];
    const float* tr_wq = (const float*)d_in[17], *tr_bq = (const float*)d_in[18];
    const float* tr_wk = (const float*)d_in[19], *tr_bk = (const float*)d_in[20];
    const float* tr_wv = (const float*)d_in[21], *tr_bv = (const float*)d_in[22];
    const float* tr_ws = (const float*)d_in[23], *tr_bs = (const float*)d_in[24];
    const float* gc_w  = (const float*)d_in[25], *gc_b  = (const float*)d_in[26];
    const float* tc_wq = (const float*)d_in[27], *tc_bq = (const float*)d_in[28];
    const float* tc_wk = (const float*)d_in[29], *tc_bk = (const float*)d_in[30];
    const float* tc_wv = (const float*)d_in[31], *tc_bv = (const float*)d_in[32];
    const float* tc_ws = (const float*)d_in[33], *tc_bs = (const float*)d_in[34];
    const float* d1_w  = (const float*)d_in[35], *d1_b  = (const float*)d_in[36];
    const float* d2_w  = (const float*)d_in[37], *d2_b  = (const float*)d_in[38];
    const float* d3_w  = (const float*)d_in[39], *d3_b  = (const float*)d_in[40];

    const int* knn_src = knn, *knn_dst = knn + EKNN;
    const int* ppi_src = ppi, *ppi_dst = ppi + EPPI;

    float* ws = (float*)d_ws;
    ushort_t* B1 = (ushort_t*)(ws + OFF_B1);
    ushort_t* B2 = (ushort_t*)(ws + OFF_B2);
    ushort_t* B3 = (ushort_t*)(ws + OFF_B3);
    ushort_t* WBF0 = (ushort_t*)(ws + OFF_WBF);
    ushort_t* WBF1 = WBF0 + 2 * NBIG;
    ushort_t* GRT = (ushort_t*)(ws + OFF_GRT);
    ushort_t* GCT = (ushort_t*)(ws + OFF_GCT);
    ushort_t* WQR = (ushort_t*)(ws + OFF_WQR);
    ushort_t* WQC = (ushort_t*)(ws + OFF_WQC);
    ushort_t* D1T = (ushort_t*)(ws + OFF_D1T);
    ushort_t* D2T = (ushort_t*)(ws + OFF_D2T);
    ushort_t* D3T = (ushort_t*)(ws + OFF_D3T);
    ushort_t* HRB = (ushort_t*)(ws + OFF_HRB);
    ushort_t* HCB = (ushort_t*)(ws + OFF_HCB);
    ushort_t* H2B = (ushort_t*)(ws + OFF_H2B);
    ushort_t* H3B = (ushort_t*)(ws + OFF_H3B);
    float* QKVSR = ws + OFF_QKVSR;
    float* QKVSC = ws + OFF_QKVSC;
    ushort_t* CBF = (ushort_t*)(ws + OFF_CBF);
    float* B4 = ws + OFF_B4;
    float* ALPHAP = ws + OFF_ALPHAP;
    float* ALPHAK = ws + OFF_ALPHAK;
    float* CNTP = ws + OFF_CNT;
    float* CNTK = CNTP + NG;
    float* DINVP = ws + OFF_DINVP;
    float* DINVK = ws + OFF_DINVK;
    double* PART = (double*)(ws + OFF_PART);
    int* RPP  = (int*)(ws + OFF_RPP);
    int* RPK  = (int*)(ws + OFF_RPK);
    int* SRCP = (int*)(ws + OFF_SRCP);
    int* EIDP = (int*)(ws + OFF_EIDP);
    int* SRCK = (int*)(ws + OFF_SRCK);
    int* EIDK = (int*)(ws + OFF_EIDK);
    int* CHP  = (int*)(ws + OFF_CHP);
    int* CHK  = (int*)(ws + OFF_CHK);

    float* out_rows = (float*)d_out;
    float* out_cols = out_rows + (size_t)NG * 128;
    float* out_feat = out_cols + (size_t)NC * 128;

    auto addJ = [](TJobs& J, const void* in, ushort_t* out, int R, int C, int type) {
        int k = J.n;
        int prevEnd = (k == 0) ? 0 : J.start[k - 1] + (J.C[k - 1] >> 6) * (J.R[k - 1] >> 6);
        J.in[k] = in; J.out[k] = out; J.R[k] = R; J.C[k] = C; J.type[k] = type;
        J.start[k] = prevEnd; J.n = k + 1;
    };
    auto jBlocks = [](const TJobs& J) {
        return (J.n == 0) ? 0 : J.start[J.n - 1] + (J.C[J.n - 1] >> 6) * (J.R[J.n - 1] >> 6);
    };
    auto gemm = [&](const ushort_t* Abf, const ushort_t* Wt, const float* bias,
                    float* Cf, ushort_t* Cb, int M, int N, int K, int mode) {
        dim3 g(N >> 7, M >> 7), blk(256);
        switch (mode) {
            case 2: gemm_bf16<0, true, false><<<g, blk, 0, stream>>>(Abf, Wt, bias, Cf, nullptr, M, N, K); break;
            case 3: gemm_bf16<2, true, true ><<<g, blk, 0, stream>>>(Abf, Wt, bias, nullptr, Cb, M, N, K); break;
        }
    };

    // ---- deterministic CSR build + x transpose ----
    hipMemsetAsync(CHP, 0, ((size_t)NCH_P * NG + (size_t)NCH_K * NC) * 4, stream);
    cnt_chunks<<<NCH_P + NCH_K, 256, 0, stream>>>(ppi_dst, CHP, knn_dst, CHK);
    pref_chunks<<<24, 256, 0, stream>>>(CHP, CHK, CNTP, CNTK, DINVP, DINVK);
    scan_rowptr2<<<2, 256, 0, stream>>>(CNTP, RPP, CNTK, RPK);
    fill_det_xt<<<NCH_P + NCH_K + 2048, 256, 0, stream>>>(
        ppi_src, ppi_dst, RPP, CHP, SRCP, EIDP,
        knn_src, knn_dst, RPK, CHK, SRCK, EIDK, x, B1);     // B1 = x^T bf16 [NC][NG]

    // ---- SAGE blocks (gather co-dispatched with that layer's weight transposes) ----
    const float* cwl[2] = {c0_wl, c1_wl}; const float* cwr[2] = {c0_wr, c1_wr}; const float* cbb[2] = {c0_b, c1_b};
    const float* rwl[2] = {r0_wl, r1_wl}; const float* rwr[2] = {r0_wr, r1_wr}; const float* rbb[2] = {r0_b, r1_b};
    for (int l = 0; l < 2; ++l) {
        TJobs Jc{}; Jc.n = 0; Jc.nGather = NC;
        addJ(Jc, cwl[l], WBF0, NG, NG, 0);
        addJ(Jc, cwr[l], WBF1, NG, NG, 0);
        gather_tr<1><<<NC + jBlocks(Jc), 256, 0, stream>>>(RPK, SRCK, B1, B2, Jc);
        gemm_sage<<<dim3(NC >> 7, NG >> 7), 256, 0, stream>>>(WBF0, B2, WBF1, B1, cbb[l], B3, NG, NC, NG);
        TJobs Jr{}; Jr.n = 0; Jr.nGather = NG;
        addJ(Jr, rwl[l], WBF0, NC, NC, 0);
        addJ(Jr, rwr[l], WBF1, NC, NC, 0);
        gather_tr<2><<<NG + jBlocks(Jr), 256, 0, stream>>>(RPP, SRCP, B3, B2, Jr);
        gemm_sage<<<dim3(NG >> 7, NC >> 7), 256, 0, stream>>>(WBF0, B2, WBF1, B3, rbb[l], B1, NC, NG, NC);
    }

    // ---- prep dispatch: emb4 transpose + ALL encoder/decoder weight transposes ----
    {
        TJobs Jp{}; Jp.n = 0; Jp.nGather = 0;
        addJ(Jp, B1, B3, NC, NG, 1);                 // emb4 [NG][NC] from B1 [NC][NG]
        addJ(Jp, gr_w, GRT, NC, 512, 0);
        addJ(Jp, gc_w, GCT, NG, 512, 0);
        addJ(Jp, tr_wq, WQR + 0 * 65536, 512, 128, 0);
        addJ(Jp, tr_wk, WQR + 1 * 65536, 512, 128, 0);
        addJ(Jp, tr_wv, WQR + 2 * 65536, 512, 128, 0);
        addJ(Jp, tr_ws, WQR + 3 * 65536, 512, 128, 0);
        addJ(Jp, tc_wq, WQC + 0 * 65536, 512, 128, 0);
        addJ(Jp, tc_wk, WQC + 1 * 65536, 512, 128, 0);
        addJ(Jp, tc_wv, WQC + 2 * 65536, 512, 128, 0);
        addJ(Jp, tc_ws, WQC + 3 * 65536, 512, 128, 0);
        addJ(Jp, d1_w, D1T, 128, 512, 0);
        addJ(Jp, d2_w, D2T, 512, 512, 0);
        addJ(Jp, d3_w, D3T, 512, NG, 0);
        gather_tr<1><<<jBlocks(Jp), 256, 0, stream>>>(RPK, SRCK, B1, B2, Jp);
    }

    // ---- encoders (batched pairwise) ----
    gemm2_bf16<false, true><<<64 + 128, 256, 0, stream>>>(
        B3, GRT, nullptr, nullptr, HRB, 512, NC, 4, 64,
        B1, GCT, nullptr, nullptr, HCB, 512, NG, 4);
    gcn_gather2<<<NG + NC, 128, 0, stream>>>(RPP, SRCP, HRB, DINVP, gr_b, H2B,
                                             RPK, SRCK, HCB, DINVK, gc_b, H3B);
    concat8<<<4, 256, 0, stream>>>(tr_bq, tr_bk, tr_bv, tr_bs, tc_bq, tc_bk, tc_bv, tc_bs, B4);
    gemm2_bf16<true, false><<<64 + 128, 256, 0, stream>>>(
        H2B, WQR, B4, QKVSR, nullptr, 512, 512, 4, 64,
        H3B, WQC, B4 + 512, QKVSC, nullptr, 512, 512, 4);
    edge_dot2<<<cdiv((EPPI + EKNN) * 16, 256), 256, 0, stream>>>(
        ppi_src, ppi_dst, QKVSR, ALPHAP, knn_src, knn_dst, QKVSC, ALPHAK);
    reduce_stats2<<<64, 256, 0, stream>>>(ALPHAK, PART);
    tconv2<<<NG + NC, 128, 0, stream>>>(RPP, SRCP, EIDP, ALPHAP, QKVSR, out_rows,
                                        RPK, SRCK, EIDK, ALPHAK, QKVSC, PART, out_cols, CBF);

    // ---- decoder ----
    gemm(CBF, D1T, d1_b, nullptr, H2B, NC, 512, 128, 3);
    gemm(H2B, D2T, d2_b, nullptr, H3B, NC, 512, 512, 3);
    gemm(H3B, D3T, d3_b, out_feat, nullptr, NC, NG, 512, 2);

    (void)in_sizes; (void)n_in; (void)out_size; (void)ws_size;
}

// Round 11
// 883.874 us; speedup vs baseline: 20.6109x; 1.0355x over previous
//
#include <hip/hip_runtime.h>
#include <math.h>

#define NG 2048
#define NC 4096
#define EKNN 61440
#define EPPI 65536
#define NJMAX 14
#define NCH_P 256   // EPPI/256
#define NCH_K 240   // EKNN/256

typedef __attribute__((ext_vector_type(8))) short short8v;
typedef __attribute__((ext_vector_type(4))) float f32x4;
typedef unsigned short ushort_t;

static inline int cdiv(int a, int b) { return (a + b - 1) / b; }

__device__ __forceinline__ unsigned short f2b(float f) {
    union { float f; unsigned int i; } v; v.f = f;
    unsigned int r = v.i + 0x7FFFu + ((v.i >> 16) & 1u);
    return (unsigned short)(r >> 16);
}
__device__ __forceinline__ float bl(unsigned int u) { union { unsigned int i; float f; } v; v.i = u << 16; return v.f; }
__device__ __forceinline__ float bh(unsigned int u) { union { unsigned int i; float f; } v; v.i = u & 0xFFFF0000u; return v.f; }
__device__ __forceinline__ unsigned int pk2(float a, float b) { return (unsigned int)f2b(a) | ((unsigned int)f2b(b) << 16); }

__device__ __forceinline__ int xcd_swz_id() {
    const int nwg = gridDim.x * gridDim.y;
    const int orig = blockIdx.y * gridDim.x + blockIdx.x;
    const int q = nwg >> 3, r = nwg & 7;
    const int xcd = orig & 7, off = orig >> 3;
    return (xcd < r ? xcd * (q + 1) : r * (q + 1) + (xcd - r) * q) + off;
}

#define GLOAD_LDS16(gp, lp) __builtin_amdgcn_global_load_lds( \
    (const __attribute__((address_space(1))) void*)(gp),      \
    (__attribute__((address_space(3))) void*)(lp), 16, 0, 0)

// transpose job list (by-value kernel arg)
struct TJobs {
    const void* in[NJMAX];
    ushort_t* out[NJMAX];
    int R[NJMAX], C[NJMAX], start[NJMAX], type[NJMAX];  // 0=f32->bf16, 1=bf16->bf16
    int n;
    int nGather;
};

// ================= bf16 MFMA GEMM (single, XCD-swizzled) =================
template<int ACT, bool BIAS, bool OBF>
__global__ __launch_bounds__(256)
void gemm_bf16(const ushort_t* __restrict__ A,
               const ushort_t* __restrict__ Bt,
               const float* __restrict__ bias,
               float* __restrict__ Cf, ushort_t* __restrict__ Cb,
               int M, int N, int K) {
    __shared__ ushort_t lds[2][2][128 * 32];
    const int tid = threadIdx.x;
    const int lane = tid & 63, wv = tid >> 6;
    const int wm = wv >> 1, wn = wv & 1;
    const int swzid = xcd_swz_id();
    const int bm = (swzid / gridDim.x) << 7, bn = (swzid % gridDim.x) << 7;

    const ushort_t* gA = A + (size_t)bm * K;
    const ushort_t* gB = Bt + (size_t)bn * K;
    const int rsub = lane >> 2;
    const int qsw  = (lane & 3) ^ ((lane >> 3) & 3);
    const int KT = K >> 5;

    f32x4 acc[4][4];
    #pragma unroll
    for (int i = 0; i < 4; ++i)
        #pragma unroll
        for (int j = 0; j < 4; ++j) acc[i][j] = (f32x4){0.f, 0.f, 0.f, 0.f};

    auto stage = [&](int buf, int k0) {
        #pragma unroll
        for (int t = 0; t < 2; ++t) {
            const int br = (wv * 2 + t) * 16;
            GLOAD_LDS16(gA + (size_t)(br + rsub) * K + k0 + qsw * 8, &lds[buf][0][br * 32]);
            GLOAD_LDS16(gB + (size_t)(br + rsub) * K + k0 + qsw * 8, &lds[buf][1][br * 32]);
        }
    };
    const int rl = lane & 15, kg = lane >> 4;
    const int swr = (kg ^ ((rl >> 1) & 3)) * 8;

    stage(0, 0);
    int buf = 0;
    for (int kt = 0; kt < KT; ++kt) {
        __syncthreads();
        if (kt + 1 < KT) stage(buf ^ 1, (kt + 1) << 5);
        short8v a[4], b[4];
        #pragma unroll
        for (int mi = 0; mi < 4; ++mi)
            a[mi] = *(const short8v*)&lds[buf][0][(wm * 64 + mi * 16 + rl) * 32 + swr];
        #pragma unroll
        for (int ni = 0; ni < 4; ++ni)
            b[ni] = *(const short8v*)&lds[buf][1][(wn * 64 + ni * 16 + rl) * 32 + swr];
        #pragma unroll
        for (int mi = 0; mi < 4; ++mi)
            #pragma unroll
            for (int ni = 0; ni < 4; ++ni)
                acc[mi][ni] = __builtin_amdgcn_mfma_f32_16x16x32_bf16(a[mi], b[ni], acc[mi][ni], 0, 0, 0);
        buf ^= 1;
    }
    const int colL = lane & 15, rq = lane >> 4;
    #pragma unroll
    for (int mi = 0; mi < 4; ++mi) {
        const int row0 = bm + wm * 64 + mi * 16 + rq * 4;
        #pragma unroll
        for (int ni = 0; ni < 4; ++ni) {
            const int col = bn + wn * 64 + ni * 16 + colL;
            float bv = 0.f;
            if (BIAS) bv = bias[col];
            #pragma unroll
            for (int r = 0; r < 4; ++r) {
                const size_t off = (size_t)(row0 + r) * N + col;
                float v = acc[mi][ni][r];
                if (BIAS) v += bv;
                if (ACT == 2) v = fmaxf(v, 0.f);
                if (OBF) Cb[off] = f2b(v); else Cf[off] = v;
            }
        }
    }
}

// ================= batched dual GEMM =================
template<bool BIAS, bool OBF>
__global__ __launch_bounds__(256)
void gemm2_bf16(const ushort_t* __restrict__ A0, const ushort_t* __restrict__ Bt0,
                const float* __restrict__ bias0, float* __restrict__ Cf0, ushort_t* __restrict__ Cb0,
                int N0, int K0, int nx0, int nb0,
                const ushort_t* __restrict__ A1, const ushort_t* __restrict__ Bt1,
                const float* __restrict__ bias1, float* __restrict__ Cf1, ushort_t* __restrict__ Cb1,
                int N1, int K1, int nx1) {
    __shared__ ushort_t lds[2][2][128 * 32];
    const int bid = blockIdx.x;
    const bool p1 = bid >= nb0;
    const int lbid = p1 ? bid - nb0 : bid;
    const ushort_t* A = p1 ? A1 : A0;
    const ushort_t* Bt = p1 ? Bt1 : Bt0;
    const float* bias = p1 ? bias1 : bias0;
    float* Cf = p1 ? Cf1 : Cf0;
    ushort_t* Cb = p1 ? Cb1 : Cb0;
    const int N = p1 ? N1 : N0;
    const int K = p1 ? K1 : K0;
    const int nx = p1 ? nx1 : nx0;
    const int bn = (lbid % nx) << 7, bm = (lbid / nx) << 7;

    const int tid = threadIdx.x;
    const int lane = tid & 63, wv = tid >> 6;
    const int wm = wv >> 1, wn = wv & 1;
    const ushort_t* gA = A + (size_t)bm * K;
    const ushort_t* gB = Bt + (size_t)bn * K;
    const int rsub = lane >> 2;
    const int qsw  = (lane & 3) ^ ((lane >> 3) & 3);
    const int KT = K >> 5;

    f32x4 acc[4][4];
    #pragma unroll
    for (int i = 0; i < 4; ++i)
        #pragma unroll
        for (int j = 0; j < 4; ++j) acc[i][j] = (f32x4){0.f, 0.f, 0.f, 0.f};

    auto stage = [&](int buf, int k0) {
        #pragma unroll
        for (int t = 0; t < 2; ++t) {
            const int br = (wv * 2 + t) * 16;
            GLOAD_LDS16(gA + (size_t)(br + rsub) * K + k0 + qsw * 8, &lds[buf][0][br * 32]);
            GLOAD_LDS16(gB + (size_t)(br + rsub) * K + k0 + qsw * 8, &lds[buf][1][br * 32]);
        }
    };
    const int rl = lane & 15, kg = lane >> 4;
    const int swr = (kg ^ ((rl >> 1) & 3)) * 8;

    stage(0, 0);
    int buf = 0;
    for (int kt = 0; kt < KT; ++kt) {
        __syncthreads();
        if (kt + 1 < KT) stage(buf ^ 1, (kt + 1) << 5);
        short8v a[4], b[4];
        #pragma unroll
        for (int mi = 0; mi < 4; ++mi)
            a[mi] = *(const short8v*)&lds[buf][0][(wm * 64 + mi * 16 + rl) * 32 + swr];
        #pragma unroll
        for (int ni = 0; ni < 4; ++ni)
            b[ni] = *(const short8v*)&lds[buf][1][(wn * 64 + ni * 16 + rl) * 32 + swr];
        #pragma unroll
        for (int mi = 0; mi < 4; ++mi)
            #pragma unroll
            for (int ni = 0; ni < 4; ++ni)
                acc[mi][ni] = __builtin_amdgcn_mfma_f32_16x16x32_bf16(a[mi], b[ni], acc[mi][ni], 0, 0, 0);
        buf ^= 1;
    }
    const int colL = lane & 15, rq = lane >> 4;
    #pragma unroll
    for (int mi = 0; mi < 4; ++mi) {
        const int row0 = bm + wm * 64 + mi * 16 + rq * 4;
        #pragma unroll
        for (int ni = 0; ni < 4; ++ni) {
            const int col = bn + wn * 64 + ni * 16 + colL;
            float bv = 0.f;
            if (BIAS) bv = bias[col];
            #pragma unroll
            for (int r = 0; r < 4; ++r) {
                const size_t off = (size_t)(row0 + r) * N + col;
                float v = acc[mi][ni][r];
                if (BIAS) v += bv;
                if (OBF) Cb[off] = f2b(v); else Cf[off] = v;
            }
        }
    }
}

// ================= fused SAGE GEMM (swapped orientation, ROW bias) =================
__global__ __launch_bounds__(256)
void gemm_sage(const ushort_t* __restrict__ A0, const ushort_t* __restrict__ B0t,
               const ushort_t* __restrict__ A1, const ushort_t* __restrict__ B1t,
               const float* __restrict__ bias, ushort_t* __restrict__ Cb,
               int M, int N, int K) {
    __shared__ ushort_t lds[2][2][128 * 32];
    const int tid = threadIdx.x;
    const int lane = tid & 63, wv = tid >> 6;
    const int wm = wv >> 1, wn = wv & 1;
    const int swzid = xcd_swz_id();
    const int bm = (swzid / gridDim.x) << 7, bn = (swzid % gridDim.x) << 7;

    const ushort_t* gA0 = A0 + (size_t)bm * K;
    const ushort_t* gB0 = B0t + (size_t)bn * K;
    const ushort_t* gA1 = A1 + (size_t)bm * K;
    const ushort_t* gB1 = B1t + (size_t)bn * K;
    const int rsub = lane >> 2;
    const int qsw  = (lane & 3) ^ ((lane >> 3) & 3);
    const int KT = K >> 5;

    f32x4 acc[4][4];
    #pragma unroll
    for (int i = 0; i < 4; ++i)
        #pragma unroll
        for (int j = 0; j < 4; ++j) acc[i][j] = (f32x4){0.f, 0.f, 0.f, 0.f};

    auto stage = [&](int buf, int kt) {
        const int half = kt >= KT;
        const int k0 = (half ? (kt - KT) : kt) << 5;
        const ushort_t* sA = half ? gA1 : gA0;
        const ushort_t* sB = half ? gB1 : gB0;
        #pragma unroll
        for (int t = 0; t < 2; ++t) {
            const int br = (wv * 2 + t) * 16;
            GLOAD_LDS16(sA + (size_t)(br + rsub) * K + k0 + qsw * 8, &lds[buf][0][br * 32]);
            GLOAD_LDS16(sB + (size_t)(br + rsub) * K + k0 + qsw * 8, &lds[buf][1][br * 32]);
        }
    };
    const int rl = lane & 15, kg = lane >> 4;
    const int swr = (kg ^ ((rl >> 1) & 3)) * 8;

    stage(0, 0);
    int buf = 0;
    const int KT2 = KT * 2;
    for (int kt = 0; kt < KT2; ++kt) {
        __syncthreads();
        if (kt + 1 < KT2) stage(buf ^ 1, kt + 1);
        short8v a[4], b[4];
        #pragma unroll
        for (int mi = 0; mi < 4; ++mi)
            a[mi] = *(const short8v*)&lds[buf][0][(wm * 64 + mi * 16 + rl) * 32 + swr];
        #pragma unroll
        for (int ni = 0; ni < 4; ++ni)
            b[ni] = *(const short8v*)&lds[buf][1][(wn * 64 + ni * 16 + rl) * 32 + swr];
        #pragma unroll
        for (int mi = 0; mi < 4; ++mi)
            #pragma unroll
            for (int ni = 0; ni < 4; ++ni)
                acc[mi][ni] = __builtin_amdgcn_mfma_f32_16x16x32_bf16(a[mi], b[ni], acc[mi][ni], 0, 0, 0);
        buf ^= 1;
    }
    const int colL = lane & 15, rq = lane >> 4;
    #pragma unroll
    for (int mi = 0; mi < 4; ++mi) {
        const int row0 = bm + wm * 64 + mi * 16 + rq * 4;
        float bz[4];
        #pragma unroll
        for (int r = 0; r < 4; ++r) bz[r] = bias[row0 + r];
        #pragma unroll
        for (int ni = 0; ni < 4; ++ni) {
            const int col = bn + wn * 64 + ni * 16 + colL;
            #pragma unroll
            for (int r = 0; r < 4; ++r) {
                float v = acc[mi][ni][r] + bz[r];
                v = v > 0.f ? v : 0.01f * v;
                Cb[(size_t)(row0 + r) * N + col] = f2b(v);
            }
        }
    }
}

// ================= fused: SAGE gather (feature-split) + transpose-job tail =================
// SPLIT blocks per node; each block handles 2048 features (256 uint4, 1/thread).
template<int SPLIT>
__global__ __launch_bounds__(256)
void gather_tr(const int* __restrict__ rowptr, const int* __restrict__ srcs,
               const ushort_t* __restrict__ x, ushort_t* __restrict__ xout,
               TJobs jobs) {
    __shared__ ushort_t shm[64 * 65];
    const int tid = threadIdx.x;
    if ((int)blockIdx.x < jobs.nGather) {
        const int F = SPLIT * 2048;
        const int node = (int)blockIdx.x / SPLIT;
        const int part = (int)blockIdx.x % SPLIT;
        const int fo = part * 256 + tid;            // uint4 index within row
        int* snb = (int*)shm;
        const int beg = rowptr[node], end = rowptr[node + 1];
        float acc[8];
        #pragma unroll
        for (int j = 0; j < 8; ++j) acc[j] = 0.f;
        for (int c = beg; c < end; c += 256) {
            const int m = min(256, end - c);
            __syncthreads();
            if (tid < m) snb[tid] = srcs[c + tid];
            __syncthreads();
            #pragma unroll 4
            for (int i = 0; i < m; ++i) {
                const uint4 v = ((const uint4*)(x + (size_t)snb[i] * F))[fo];
                acc[0] += bl(v.x); acc[1] += bh(v.x);
                acc[2] += bl(v.y); acc[3] += bh(v.y);
                acc[4] += bl(v.z); acc[5] += bh(v.z);
                acc[6] += bl(v.w); acc[7] += bh(v.w);
            }
        }
        const float inv = 1.f / fmaxf((float)(end - beg), 1.f);
        uint4 o;
        o.x = pk2(acc[0] * inv, acc[1] * inv);
        o.y = pk2(acc[2] * inv, acc[3] * inv);
        o.z = pk2(acc[4] * inv, acc[5] * inv);
        o.w = pk2(acc[6] * inv, acc[7] * inv);
        ((uint4*)(xout + (size_t)node * F))[fo] = o;
        return;
    }
    // ---- transpose jobs ----
    int b = blockIdx.x - jobs.nGather;
    int j = 0;
    while (j + 1 < jobs.n && b >= jobs.start[j + 1]) ++j;
    const int t = b - jobs.start[j];
    const int R = jobs.R[j], C = jobs.C[j];
    const int nx = C >> 6;
    const int bx = (t % nx) << 6, by = (t / nx) << 6;
    const int tr = tid >> 4, tc = (tid & 15) << 2;
    if (jobs.type[j] == 0) {
        const float* in = (const float*)jobs.in[j];
        #pragma unroll
        for (int i = 0; i < 4; ++i) {
            const int rr = tr + i * 16;
            const float4 v = *(const float4*)(in + (size_t)(by + rr) * C + bx + tc);
            shm[rr * 65 + tc + 0] = f2b(v.x); shm[rr * 65 + tc + 1] = f2b(v.y);
            shm[rr * 65 + tc + 2] = f2b(v.z); shm[rr * 65 + tc + 3] = f2b(v.w);
        }
    } else {
        const ushort_t* in = (const ushort_t*)jobs.in[j];
        #pragma unroll
        for (int i = 0; i < 4; ++i) {
            const int rr = tr + i * 16;
            const ushort4 v = *(const ushort4*)(in + (size_t)(by + rr) * C + bx + tc);
            shm[rr * 65 + tc + 0] = v.x; shm[rr * 65 + tc + 1] = v.y;
            shm[rr * 65 + tc + 2] = v.z; shm[rr * 65 + tc + 3] = v.w;
        }
    }
    __syncthreads();
    ushort_t* out = jobs.out[j];
    #pragma unroll
    for (int i = 0; i < 4; ++i) {
        const int cc = tr + i * 16;
        ushort4 o;
        o.x = shm[(tc + 0) * 65 + cc]; o.y = shm[(tc + 1) * 65 + cc];
        o.z = shm[(tc + 2) * 65 + cc]; o.w = shm[(tc + 3) * 65 + cc];
        *(ushort4*)(out + (size_t)(bx + cc) * R + by + tc) = o;
    }
}

// ---------------- deterministic CSR build ----------------
__global__ void cnt_chunks(const int* __restrict__ pdst, int* __restrict__ chp,
                           const int* __restrict__ kdst, int* __restrict__ chk) {
    const int bid = blockIdx.x, tid = threadIdx.x;
    if (bid < NCH_P) {
        atomicAdd(&chp[bid * NG + pdst[bid * 256 + tid]], 1);
    } else {
        const int c = bid - NCH_P;
        atomicAdd(&chk[c * NC + kdst[c * 256 + tid]], 1);
    }
}

__global__ __launch_bounds__(256)
void pref_chunks(int* __restrict__ chp, int* __restrict__ chk,
                 float* __restrict__ cntp, float* __restrict__ cntk,
                 float* __restrict__ dinvp, float* __restrict__ dinvk) {
    const int bid = blockIdx.x, tid = threadIdx.x;
    if (bid < 8) {
        const int d = bid * 256 + tid;
        int run = 0;
        for (int c = 0; c < NCH_P; ++c) {
            const int t = chp[c * NG + d];
            chp[c * NG + d] = run;
            run += t;
        }
        cntp[d] = (float)run;
        dinvp[d] = rsqrtf((float)run + 1.0f);
    } else {
        const int d = (bid - 8) * 256 + tid;
        int run = 0;
        for (int c = 0; c < NCH_K; ++c) {
            const int t = chk[c * NC + d];
            chk[c * NC + d] = run;
            run += t;
        }
        cntk[d] = (float)run;
        dinvk[d] = rsqrtf((float)run + 1.0f);
    }
}

__global__ __launch_bounds__(256)
void scan_rowptr2(const float* __restrict__ cntp, int* __restrict__ rpp,
                  const float* __restrict__ cntk, int* __restrict__ rpk) {
    const float* cnt = blockIdx.x ? cntk : cntp;
    int* rowptr = blockIdx.x ? rpk : rpp;
    const int n = blockIdx.x ? NC : NG;
    __shared__ int part[257];
    const int tid = threadIdx.x;
    const int per = n >> 8;
    const int base = tid * per;
    int s = 0;
    for (int i = 0; i < per; ++i) s += (int)cnt[base + i];
    part[tid + 1] = s;
    if (tid == 0) part[0] = 0;
    __syncthreads();
    if (tid == 0)
        for (int i = 1; i <= 256; ++i) part[i] += part[i - 1];
    __syncthreads();
    int run = part[tid];
    for (int i = 0; i < per; ++i) {
        rowptr[base + i] = run;
        run += (int)cnt[base + i];
    }
    if (tid == 255) rowptr[n] = run;
}

__global__ __launch_bounds__(256)
void fill_det_xt(const int* __restrict__ psrc, const int* __restrict__ pdst,
                 const int* __restrict__ rpp, const int* __restrict__ chp,
                 int* __restrict__ srcp, int* __restrict__ eidp,
                 const int* __restrict__ ksrc, const int* __restrict__ kdst,
                 const int* __restrict__ rpk, const int* __restrict__ chk,
                 int* __restrict__ srck, int* __restrict__ eidk,
                 const float* __restrict__ x, ushort_t* __restrict__ xt) {
    __shared__ ushort_t shm[64 * 65];
    const int bid = blockIdx.x, tid = threadIdx.x;
    if (bid < NCH_P + NCH_K) {
        int* sd = (int*)shm;
        const bool knn = bid >= NCH_P;
        const int c = knn ? bid - NCH_P : bid;
        const int e = c * 256 + tid;
        const int d = knn ? kdst[e] : pdst[e];
        sd[tid] = d;
        __syncthreads();
        int rank = 0;
        for (int j = 0; j < 256; ++j)
            rank += (j < tid && sd[j] == d) ? 1 : 0;
        const int slot = (knn ? rpk : rpp)[d] + (knn ? chk + c * NC : chp + c * NG)[d] + rank;
        if (knn) { srck[slot] = ksrc[e]; eidk[slot] = e; }
        else     { srcp[slot] = psrc[e]; eidp[slot] = e; }
        return;
    }
    const int t = bid - (NCH_P + NCH_K);
    const int bx = (t & 63) << 6;
    const int by = (t >> 6) << 6;
    const int tr = tid >> 4, tc = (tid & 15) << 2;
    #pragma unroll
    for (int i = 0; i < 4; ++i) {
        const int rr = tr + i * 16;
        const float4 v = *(const float4*)(x + (size_t)(by + rr) * NC + bx + tc);
        shm[rr * 65 + tc + 0] = f2b(v.x); shm[rr * 65 + tc + 1] = f2b(v.y);
        shm[rr * 65 + tc + 2] = f2b(v.z); shm[rr * 65 + tc + 3] = f2b(v.w);
    }
    __syncthreads();
    #pragma unroll
    for (int i = 0; i < 4; ++i) {
        const int cc = tr + i * 16;
        ushort4 o;
        o.x = shm[(tc + 0) * 65 + cc]; o.y = shm[(tc + 1) * 65 + cc];
        o.z = shm[(tc + 2) * 65 + cc]; o.w = shm[(tc + 3) * 65 + cc];
        *(ushort4*)(xt + (size_t)(bx + cc) * NG + by + tc) = o;
    }
}

__global__ void concat8(const float* __restrict__ a, const float* __restrict__ b,
                        const float* __restrict__ c, const float* __restrict__ d,
                        const float* __restrict__ e, const float* __restrict__ f,
                        const float* __restrict__ g, const float* __restrict__ h,
                        float* __restrict__ o) {
    int i = threadIdx.x + blockIdx.x * blockDim.x;
    if (i >= 1024) return;
    const float* s;
    int j = i & 127;
    switch (i >> 7) {
        case 0: s = a; break; case 1: s = b; break; case 2: s = c; break; case 3: s = d; break;
        case 4: s = e; break; case 5: s = f; break; case 6: s = g; break; default: s = h; break;
    }
    o[i] = s[j];
}

// ---------------- graph kernels (batched pairs) ----------------
__global__ __launch_bounds__(128)
void gcn_gather2(const int* __restrict__ rpp, const int* __restrict__ srcp,
                 const ushort_t* __restrict__ hr, const float* __restrict__ dinvp,
                 const float* __restrict__ br, ushort_t* __restrict__ outr,
                 const int* __restrict__ rpk, const int* __restrict__ srck,
                 const ushort_t* __restrict__ hc, const float* __restrict__ dinvk,
                 const float* __restrict__ bc, ushort_t* __restrict__ outc) {
    const bool cols = blockIdx.x >= NG;
    const int node = cols ? blockIdx.x - NG : blockIdx.x;
    const int tid = threadIdx.x;
    const int* rowptr = cols ? rpk : rpp;
    const int* srcs = cols ? srck : srcp;
    const ushort_t* h = cols ? hc : hr;
    const float* dinv = cols ? dinvk : dinvp;
    const float* b = cols ? bc : br;
    ushort_t* out = cols ? outc : outr;

    const int beg = rowptr[node], end = rowptr[node + 1];
    __shared__ int snb[128];
    __shared__ float sdi[128];
    float ax = 0.f, ay = 0.f, az = 0.f, aw = 0.f;
    for (int c = beg; c < end; c += 128) {
        const int m = min(128, end - c);
        __syncthreads();
        if (tid < m) { int s = srcs[c + tid]; snb[tid] = s; sdi[tid] = dinv[s]; }
        __syncthreads();
        for (int i = 0; i < m; ++i) {
            const uint2 v = ((const uint2*)(h + (size_t)snb[i] * 512))[tid];
            const float w = sdi[i];
            ax += bl(v.x) * w; ay += bh(v.x) * w;
            az += bl(v.y) * w; aw += bh(v.y) * w;
        }
    }
    const float dd = dinv[node];
    const uint2 hv = ((const uint2*)(h + (size_t)node * 512))[tid];
    const float4 bv = ((const float4*)b)[tid];
    float4 o;
    o.x = ax * dd + bl(hv.x) * dd * dd + bv.x;
    o.y = ay * dd + bh(hv.x) * dd * dd + bv.y;
    o.z = az * dd + bl(hv.y) * dd * dd + bv.z;
    o.w = aw * dd + bh(hv.y) * dd * dd + bv.w;
    o.x = o.x > 0.f ? o.x : 0.01f * o.x;
    o.y = o.y > 0.f ? o.y : 0.01f * o.y;
    o.z = o.z > 0.f ? o.z : 0.01f * o.z;
    o.w = o.w > 0.f ? o.w : 0.01f * o.w;
    ((uint2*)(out + (size_t)node * 512))[tid] = make_uint2(pk2(o.x, o.y), pk2(o.z, o.w));
}

// 16 lanes per edge, 4 edges per wave
__global__ __launch_bounds__(256)
void edge_dot2(const int* __restrict__ psrc, const int* __restrict__ pdst,
               const float* __restrict__ qr, float* __restrict__ alphap,
               const int* __restrict__ ksrc, const int* __restrict__ kdst,
               const float* __restrict__ qc, float* __restrict__ alphak) {
    const int gid = blockIdx.x * blockDim.x + threadIdx.x;
    const int wid = gid >> 6;
    const int lane = threadIdx.x & 63;
    const int e = wid * 4 + (lane >> 4);
    const int sub = lane & 15;
    const float* q;
    float* out;
    int s, d, w;
    if (e < EPPI) {
        w = e; s = psrc[w]; d = pdst[w]; q = qr; out = alphap;
    } else if (e < EPPI + EKNN) {
        w = e - EPPI; s = ksrc[w]; d = kdst[w]; q = qc; out = alphak;
    } else return;
    const float4* qa = (const float4*)(q + (size_t)d * 512 + sub * 8);
    const float4* ka = (const float4*)(q + (size_t)s * 512 + 128 + sub * 8);
    const float4 a0 = qa[0], a1 = qa[1], b0 = ka[0], b1 = ka[1];
    float v = a0.x * b0.x + a0.y * b0.y + a0.z * b0.z + a0.w * b0.w
            + a1.x * b1.x + a1.y * b1.y + a1.z * b1.z + a1.w * b1.w;
    v += __shfl_down(v, 8); v += __shfl_down(v, 4);
    v += __shfl_down(v, 2); v += __shfl_down(v, 1);
    if (sub == 0) out[w] = v * 0.08838834764831845f;  // 1/sqrt(128)
}

// deterministic: 64 block partials, no atomics
__global__ __launch_bounds__(256)
void reduce_stats2(const float* __restrict__ a, double* __restrict__ part) {
    double s = 0.0, s2 = 0.0;
    for (int i = blockIdx.x * blockDim.x + threadIdx.x; i < EKNN; i += gridDim.x * blockDim.x) {
        double xx = a[i];
        s += xx; s2 += xx * xx;
    }
    #pragma unroll
    for (int off = 32; off; off >>= 1) {
        s += __shfl_down(s, off);
        s2 += __shfl_down(s2, off);
    }
    __shared__ double sh[4][2];
    int w = threadIdx.x >> 6;
    if ((threadIdx.x & 63) == 0) { sh[w][0] = s; sh[w][1] = s2; }
    __syncthreads();
    if (threadIdx.x == 0) {
        part[2 * blockIdx.x]     = sh[0][0] + sh[1][0] + sh[2][0] + sh[3][0];
        part[2 * blockIdx.x + 1] = sh[0][1] + sh[1][1] + sh[2][1] + sh[3][1];
    }
}

__global__ __launch_bounds__(128)
void tconv2(const int* __restrict__ rpp, const int* __restrict__ srcp,
            const int* __restrict__ eidp, const float* __restrict__ alphap,
            const float* __restrict__ qr, float* __restrict__ outr,
            const int* __restrict__ rpk, const int* __restrict__ srck,
            const int* __restrict__ eidk, const float* __restrict__ alphak,
            const float* __restrict__ qc, const double* __restrict__ part,
            float* __restrict__ outc, ushort_t* __restrict__ ob) {
    const int tid = threadIdx.x;
    __shared__ int snb[128];
    __shared__ float sa[128];
    if (blockIdx.x < NG) {
        const int node = blockIdx.x;
        const int beg = rpp[node], end = rpp[node + 1];
        float mx = -INFINITY;
        for (int c = beg; c < end; c += 128) {
            const int m = min(128, end - c);
            __syncthreads();
            if (tid < m) sa[tid] = alphap[eidp[c + tid]];
            __syncthreads();
            for (int i = 0; i < m; ++i) mx = fmaxf(mx, sa[i]);
        }
        float acc = 0.f, z = 0.f;
        for (int c = beg; c < end; c += 128) {
            const int m = min(128, end - c);
            __syncthreads();
            if (tid < m) { snb[tid] = srcp[c + tid]; sa[tid] = __expf(alphap[eidp[c + tid]] - mx); }
            __syncthreads();
            for (int i = 0; i < m; ++i) {
                z += sa[i];
                acc += sa[i] * qr[(size_t)snb[i] * 512 + 256 + tid];
            }
        }
        const float r = acc * (z > 0.f ? 1.f / z : 0.f) + qr[(size_t)node * 512 + 384 + tid];
        outr[(size_t)node * 128 + tid] = r;
    } else {
        const int node = blockIdx.x - NG;
        const int beg = rpk[node], end = rpk[node + 1];
        double sum = 0.0, sumsq = 0.0;
        for (int i = 0; i < 64; ++i) { sum += part[2 * i]; sumsq += part[2 * i + 1]; }
        const double mu = sum / (double)EKNN;
        const double var = (sumsq - sum * sum / (double)EKNN) / (double)(EKNN - 1);
        const float sd = (float)sqrt(fmax(var, 0.0));
        const float kk = 3.0f / sd;
        const float fmu = (float)mu;
        float acc = 0.f;
        for (int c = beg; c < end; c += 128) {
            const int m = min(128, end - c);
            __syncthreads();
            if (tid < m) {
                snb[tid] = srck[c + tid];
                const float t = (alphak[eidk[c + tid]] - fmu) * kk;
                sa[tid] = 1.f / (1.f + __expf(-t));
            }
            __syncthreads();
            for (int i = 0; i < m; ++i)
                acc += sa[i] * qc[(size_t)snb[i] * 512 + 256 + tid];
        }
        const float r = acc + qc[(size_t)node * 512 + 384 + tid];
        outc[(size_t)node * 128 + tid] = r;
        ob[(size_t)node * 128 + tid] = f2b(r);
    }
}

// ---------------- workspace layout (float units) ----------------
static constexpr size_t NBIG = (size_t)NG * NC;
static constexpr size_t NBH = NBIG / 2;
static constexpr size_t OFF_B1 = 0;
static constexpr size_t OFF_B2 = NBH;
static constexpr size_t OFF_B3 = 2 * NBH;
static constexpr size_t OFF_WBF = 3 * NBH;                  // 2*NBIG floats (weight pair)
// overlay inside WBF region (written only AFTER the last SAGE GEMM)
static constexpr size_t OFF_GRT   = OFF_WBF;
static constexpr size_t OFF_GCT   = OFF_GRT + 1048576;
static constexpr size_t OFF_HRB   = OFF_GCT + 524288;
static constexpr size_t OFF_HCB   = OFF_HRB + 524288;
static constexpr size_t OFF_H2B   = OFF_HCB + 1048576;
static constexpr size_t OFF_H3B   = OFF_H2B + 524288;
static constexpr size_t OFF_QKVSR = OFF_H3B + 1048576;
static constexpr size_t OFF_QKVSC = OFF_QKVSR + 1048576;
static constexpr size_t OFF_CBF   = OFF_QKVSC + 2097152;
// tail after WBF region
static constexpr size_t OFF_TAIL = OFF_WBF + 2 * NBIG;
static constexpr size_t OFF_B4   = OFF_TAIL;
static constexpr size_t OFF_ALPHAP = OFF_B4 + 1024;
static constexpr size_t OFF_ALPHAK = OFF_ALPHAP + EPPI;
static constexpr size_t OFF_CNT  = OFF_ALPHAK + EKNN;       // CNTP NG | CNTK NC
static constexpr size_t OFF_DINVP = OFF_CNT + 12288;
static constexpr size_t OFF_DINVK = OFF_DINVP + NG;
static constexpr size_t OFF_PART = OFF_DINVK + NC;          // double[128]
static constexpr size_t OFF_RPP  = OFF_PART + 256;
static constexpr size_t OFF_RPK  = OFF_RPP + 2064;
static constexpr size_t OFF_SRCP = OFF_RPK + 4112;
static constexpr size_t OFF_EIDP = OFF_SRCP + EPPI;
static constexpr size_t OFF_SRCK = OFF_EIDP + EPPI;
static constexpr size_t OFF_EIDK = OFF_SRCK + EKNN;
static constexpr size_t OFF_CHP  = OFF_EIDK + EKNN;
static constexpr size_t OFF_CHK  = OFF_CHP + (size_t)NCH_P * NG;
// small weights (bf16) — written during l=1 r-gather, live through decoder
static constexpr size_t OFF_WQR  = OFF_CHK + (size_t)NCH_K * NC;
static constexpr size_t OFF_WQC  = OFF_WQR + 131072;
static constexpr size_t OFF_D1T  = OFF_WQC + 131072;
static constexpr size_t OFF_D2T  = OFF_D1T + 32768;
static constexpr size_t OFF_D3T  = OFF_D2T + 131072;        // + 524288 end

extern "C" void kernel_launch(void* const* d_in, const int* in_sizes, int n_in,
                              void* d_out, int out_size, void* d_ws, size_t ws_size,
                              hipStream_t stream) {
    const float* x      = (const float*)d_in[0];
    const int*   knn    = (const int*)d_in[1];
    const int*   ppi    = (const int*)d_in[2];
    const float* c0_wl = (const float*)d_in[3],  *c0_wr = (const float*)d_in[4],  *c0_b = (const float*)d_in[5];
    const float* r0_wl = (const float*)d_in[6],  *r0_wr = (const float*)d_in[7],  *r0_b = (const float*)d_in[8];
    const float* c1_wl = (const float*)d_in[9],  *c1_wr = (const float*)d_in[10], *c1_b = (const float*)d_in[11];
    const float* r1_wl = (const float*)d_in[12], *r1_wr = (const float*)d_in[13], *r1_b = (const float*)d_in[14];
    const float* gr_w  = (const float*)d_in[15], *gr_b  = (const float*)d_in[16];
    const float* tr_wq = (const float*)d_in[17], *tr_bq = (const float*)d_in[18];
    const float* tr_wk = (const float*)d_in[19], *tr_bk = (const float*)d_in[20];
    const float* tr_wv = (const float*)d_in[21], *tr_bv = (const float*)d_in[22];
    const float* tr_ws = (const float*)d_in[23], *tr_bs = (const float*)d_in[24];
    const float* gc_w  = (const float*)d_in[25], *gc_b  = (const float*)d_in[26];
    const float* tc_wq = (const float*)d_in[27], *tc_bq = (const float*)d_in[28];
    const float* tc_wk = (const float*)d_in[29], *tc_bk = (const float*)d_in[30];
    const float* tc_wv = (const float*)d_in[31], *tc_bv = (const float*)d_in[32];
    const float* tc_ws = (const float*)d_in[33], *tc_bs = (const float*)d_in[34];
    const float* d1_w  = (const float*)d_in[35], *d1_b  = (const float*)d_in[36];
    const float* d2_w  = (const float*)d_in[37], *d2_b  = (const float*)d_in[38];
    const float* d3_w  = (const float*)d_in[39], *d3_b  = (const float*)d_in[40];

    const int* knn_src = knn, *knn_dst = knn + EKNN;
    const int* ppi_src = ppi, *ppi_dst = ppi + EPPI;

    float* ws = (float*)d_ws;
    ushort_t* B1 = (ushort_t*)(ws + OFF_B1);
    ushort_t* B2 = (ushort_t*)(ws + OFF_B2);
    ushort_t* B3 = (ushort_t*)(ws + OFF_B3);
    ushort_t* WBF0 = (ushort_t*)(ws + OFF_WBF);
    ushort_t* WBF1 = WBF0 + 2 * NBIG;
    ushort_t* GRT = (ushort_t*)(ws + OFF_GRT);
    ushort_t* GCT = (ushort_t*)(ws + OFF_GCT);
    ushort_t* WQR = (ushort_t*)(ws + OFF_WQR);
    ushort_t* WQC = (ushort_t*)(ws + OFF_WQC);
    ushort_t* D1T = (ushort_t*)(ws + OFF_D1T);
    ushort_t* D2T = (ushort_t*)(ws + OFF_D2T);
    ushort_t* D3T = (ushort_t*)(ws + OFF_D3T);
    ushort_t* HRB = (ushort_t*)(ws + OFF_HRB);
    ushort_t* HCB = (ushort_t*)(ws + OFF_HCB);
    ushort_t* H2B = (ushort_t*)(ws + OFF_H2B);
    ushort_t* H3B = (ushort_t*)(ws + OFF_H3B);
    float* QKVSR = ws + OFF_QKVSR;
    float* QKVSC = ws + OFF_QKVSC;
    ushort_t* CBF = (ushort_t*)(ws + OFF_CBF);
    float* B4 = ws + OFF_B4;
    float* ALPHAP = ws + OFF_ALPHAP;
    float* ALPHAK = ws + OFF_ALPHAK;
    float* CNTP = ws + OFF_CNT;
    float* CNTK = CNTP + NG;
    float* DINVP = ws + OFF_DINVP;
    float* DINVK = ws + OFF_DINVK;
    double* PART = (double*)(ws + OFF_PART);
    int* RPP  = (int*)(ws + OFF_RPP);
    int* RPK  = (int*)(ws + OFF_RPK);
    int* SRCP = (int*)(ws + OFF_SRCP);
    int* EIDP = (int*)(ws + OFF_EIDP);
    int* SRCK = (int*)(ws + OFF_SRCK);
    int* EIDK = (int*)(ws + OFF_EIDK);
    int* CHP  = (int*)(ws + OFF_CHP);
    int* CHK  = (int*)(ws + OFF_CHK);

    float* out_rows = (float*)d_out;
    float* out_cols = out_rows + (size_t)NG * 128;
    float* out_feat = out_cols + (size_t)NC * 128;

    auto addJ = [](TJobs& J, const void* in, ushort_t* out, int R, int C, int type) {
        int k = J.n;
        int prevEnd = (k == 0) ? 0 : J.start[k - 1] + (J.C[k - 1] >> 6) * (J.R[k - 1] >> 6);
        J.in[k] = in; J.out[k] = out; J.R[k] = R; J.C[k] = C; J.type[k] = type;
        J.start[k] = prevEnd; J.n = k + 1;
    };
    auto jBlocks = [](const TJobs& J) {
        return (J.n == 0) ? 0 : J.start[J.n - 1] + (J.C[J.n - 1] >> 6) * (J.R[J.n - 1] >> 6);
    };
    auto gemm = [&](const ushort_t* Abf, const ushort_t* Wt, const float* bias,
                    float* Cf, ushort_t* Cb, int M, int N, int K, int mode) {
        dim3 g(N >> 7, M >> 7), blk(256);
        switch (mode) {
            case 2: gemm_bf16<0, true, false><<<g, blk, 0, stream>>>(Abf, Wt, bias, Cf, nullptr, M, N, K); break;
            case 3: gemm_bf16<2, true, true ><<<g, blk, 0, stream>>>(Abf, Wt, bias, nullptr, Cb, M, N, K); break;
        }
    };

    // ---- deterministic CSR build + x transpose ----
    hipMemsetAsync(CHP, 0, ((size_t)NCH_P * NG + (size_t)NCH_K * NC) * 4, stream);
    cnt_chunks<<<NCH_P + NCH_K, 256, 0, stream>>>(ppi_dst, CHP, knn_dst, CHK);
    pref_chunks<<<24, 256, 0, stream>>>(CHP, CHK, CNTP, CNTK, DINVP, DINVK);
    scan_rowptr2<<<2, 256, 0, stream>>>(CNTP, RPP, CNTK, RPK);
    fill_det_xt<<<NCH_P + NCH_K + 2048, 256, 0, stream>>>(
        ppi_src, ppi_dst, RPP, CHP, SRCP, EIDP,
        knn_src, knn_dst, RPK, CHK, SRCK, EIDK, x, B1);     // B1 = x^T bf16 [NC][NG]

    // ---- SAGE blocks ----
    const float* cwl[2] = {c0_wl, c1_wl}; const float* cwr[2] = {c0_wr, c1_wr}; const float* cbb[2] = {c0_b, c1_b};
    const float* rwl[2] = {r0_wl, r1_wl}; const float* rwr[2] = {r0_wr, r1_wr}; const float* rbb[2] = {r0_b, r1_b};
    for (int l = 0; l < 2; ++l) {
        // cells graph: KNN gather (SPLIT=1) + c-weight transposes
        TJobs Jc{}; Jc.n = 0; Jc.nGather = NC;
        addJ(Jc, cwl[l], WBF0, NG, NG, 0);
        addJ(Jc, cwr[l], WBF1, NG, NG, 0);
        gather_tr<1><<<NC + jBlocks(Jc), 256, 0, stream>>>(RPK, SRCK, B1, B2, Jc);
        gemm_sage<<<dim3(NC >> 7, NG >> 7), 256, 0, stream>>>(WBF0, B2, WBF1, B1, cbb[l], B3, NG, NC, NG);
        // genes graph: PPI gather (SPLIT=2, feature-halved blocks) + r-weight transposes
        TJobs Jr{}; Jr.n = 0; Jr.nGather = 2 * NG;
        addJ(Jr, rwl[l], WBF0, NC, NC, 0);
        addJ(Jr, rwr[l], WBF1, NC, NC, 0);
        if (l == 1) {   // small encoder/decoder weights ride along (deps: none)
            addJ(Jr, tr_wq, WQR + 0 * 65536, 512, 128, 0);
            addJ(Jr, tr_wk, WQR + 1 * 65536, 512, 128, 0);
            addJ(Jr, tr_wv, WQR + 2 * 65536, 512, 128, 0);
            addJ(Jr, tr_ws, WQR + 3 * 65536, 512, 128, 0);
            addJ(Jr, tc_wq, WQC + 0 * 65536, 512, 128, 0);
            addJ(Jr, tc_wk, WQC + 1 * 65536, 512, 128, 0);
            addJ(Jr, tc_wv, WQC + 2 * 65536, 512, 128, 0);
            addJ(Jr, tc_ws, WQC + 3 * 65536, 512, 128, 0);
            addJ(Jr, d1_w, D1T, 128, 512, 0);
            addJ(Jr, d2_w, D2T, 512, 512, 0);
            addJ(Jr, d3_w, D3T, 512, NG, 0);
        }
        gather_tr<2><<<2 * NG + jBlocks(Jr), 256, 0, stream>>>(RPP, SRCP, B3, B2, Jr);
        gemm_sage<<<dim3(NG >> 7, NC >> 7), 256, 0, stream>>>(WBF0, B2, WBF1, B3, rbb[l], B1, NC, NG, NC);
    }

    // ---- prep dispatch: emb4 transpose + gr/gc weight transposes (WBF overlay now free) ----
    {
        TJobs Jp{}; Jp.n = 0; Jp.nGather = 0;
        addJ(Jp, B1, B3, NC, NG, 1);                 // emb4 [NG][NC] from B1 [NC][NG]
        addJ(Jp, gr_w, GRT, NC, 512, 0);
        addJ(Jp, gc_w, GCT, NG, 512, 0);
        gather_tr<1><<<jBlocks(Jp), 256, 0, stream>>>(RPK, SRCK, B1, B2, Jp);
    }

    // ---- encoders (batched pairwise) ----
    gemm2_bf16<false, true><<<64 + 128, 256, 0, stream>>>(
        B3, GRT, nullptr, nullptr, HRB, 512, NC, 4, 64,
        B1, GCT, nullptr, nullptr, HCB, 512, NG, 4);
    gcn_gather2<<<NG + NC, 128, 0, stream>>>(RPP, SRCP, HRB, DINVP, gr_b, H2B,
                                             RPK, SRCK, HCB, DINVK, gc_b, H3B);
    concat8<<<4, 256, 0, stream>>>(tr_bq, tr_bk, tr_bv, tr_bs, tc_bq, tc_bk, tc_bv, tc_bs, B4);
    gemm2_bf16<true, false><<<64 + 128, 256, 0, stream>>>(
        H2B, WQR, B4, QKVSR, nullptr, 512, 512, 4, 64,
        H3B, WQC, B4 + 512, QKVSC, nullptr, 512, 512, 4);
    edge_dot2<<<cdiv((EPPI + EKNN) * 16, 256), 256, 0, stream>>>(
        ppi_src, ppi_dst, QKVSR, ALPHAP, knn_src, knn_dst, QKVSC, ALPHAK);
    reduce_stats2<<<64, 256, 0, stream>>>(ALPHAK, PART);
    tconv2<<<NG + NC, 128, 0, stream>>>(RPP, SRCP, EIDP, ALPHAP, QKVSR, out_rows,
                                        RPK, SRCK, EIDK, ALPHAK, QKVSC, PART, out_cols, CBF);

    // ---- decoder ----
    gemm(CBF, D1T, d1_b, nullptr, H2B, NC, 512, 128, 3);
    gemm(H2B, D2T, d2_b, nullptr, H3B, NC, 512, 512, 3);
    gemm(H3B, D3T, d3_b, out_feat, nullptr, NC, NG, 512, 2);

    (void)in_sizes; (void)n_in; (void)out_size; (void)ws_size;
}